// Round 1
// baseline (6057.303 us; speedup 1.0000x reference)
//
#include <hip/hip_runtime.h>
#include <math.h>

#define NN 100000
#define NE 500000
#define NG 128
#define ND 91
#define ED 20
#define H  128
#define NL 3
#define EPSF 1e-5f

// ---------------------------------------------------------------------------
// h = node_feats @ ne_W + ne_b     (one node per 128-thread block)
// ---------------------------------------------------------------------------
__global__ void encode_nodes(const float* __restrict__ nf,
                             const float* __restrict__ W,
                             const float* __restrict__ b,
                             float* __restrict__ h) {
    int n = blockIdx.x;
    int c = threadIdx.x;                       // 0..127
    __shared__ float row[ND];
    if (c < ND) row[c] = nf[(size_t)n * ND + c];
    __syncthreads();
    float acc = b[c];
    for (int k = 0; k < ND; ++k) acc += row[k] * W[k * H + c];
    h[(size_t)n * H + c] = acc;
}

// ---------------------------------------------------------------------------
// Fold the (linear) edge-feature path:  Wec[l] = ee_W @ msg_W1[l][2H:3H,:]
//                                       bec[l] = ee_b @ msg_W1[l][2H:3H,:] + msg_b1[l]
// grid (ED+1, NL) x 128
// ---------------------------------------------------------------------------
__global__ void fold_edge_weights(const float* __restrict__ eeW,
                                  const float* __restrict__ eeb,
                                  const float* __restrict__ msgW1,
                                  const float* __restrict__ msgb1,
                                  float* __restrict__ Wec,
                                  float* __restrict__ bec) {
    int l = blockIdx.y;
    int k = blockIdx.x;                        // 0..ED (ED => bias row)
    int c = threadIdx.x;                       // 0..127
    const float* W1e = msgW1 + (size_t)l * 3 * H * H + (size_t)2 * H * H;
    if (k < ED) {
        float acc = 0.f;
        for (int m = 0; m < H; ++m) acc += eeW[k * H + m] * W1e[m * H + c];
        Wec[((size_t)l * ED + k) * H + c] = acc;
    } else {
        float acc = msgb1[l * H + c];
        for (int m = 0; m < H; ++m) acc += eeb[m] * W1e[m * H + c];
        bec[(size_t)l * H + c] = acc;
    }
}

// ---------------------------------------------------------------------------
// hs = h @ W1[0:H,:],  hd = h @ W1[H:2H,:]   ; also zero agg for this layer
// one node per 256-thread block (threads 0..127 -> hs, 128..255 -> hd)
// ---------------------------------------------------------------------------
__global__ void node_msg_pre(const float* __restrict__ h,
                             const float* __restrict__ W1l,
                             float* __restrict__ hs,
                             float* __restrict__ hd,
                             float* __restrict__ agg) {
    int n = blockIdx.x;
    int t = threadIdx.x;                       // 0..255
    int c = t & 127;
    const float* W = W1l + (t < 128 ? 0 : H * H);
    __shared__ float row[H];
    if (t < H) {
        row[t] = h[(size_t)n * H + t];
        agg[(size_t)n * H + t] = 0.f;          // zero-init aggregation buffer
    }
    __syncthreads();
    float acc = 0.f;
    #pragma unroll 8
    for (int k = 0; k < H; ++k) acc += row[k] * W[k * H + c];
    float* out = (t < 128) ? hs : hd;
    out[(size_t)n * H + c] = acc;
}

// ---------------------------------------------------------------------------
// per edge: hid = relu(hs[src] + hd[dst] + ef@Wec + bec)
//           msg = hid @ W2 + b2 ;  atomicAdd(agg[dst], msg)
// 2 edges per 256-thread block
// ---------------------------------------------------------------------------
__global__ void edge_msg(const int* __restrict__ src,
                         const int* __restrict__ dst,
                         const float* __restrict__ ef,
                         const float* __restrict__ hs,
                         const float* __restrict__ hd,
                         const float* __restrict__ Wec_l,
                         const float* __restrict__ bec_l,
                         const float* __restrict__ W2,
                         const float* __restrict__ b2,
                         float* __restrict__ agg) {
    int t  = threadIdx.x;
    int le = t >> 7;                           // 0 or 1
    int c  = t & 127;
    int e  = blockIdx.x * 2 + le;
    __shared__ float hid[2][H];
    __shared__ float efs[2][ED];
    if (c < ED) efs[le][c] = ef[(size_t)e * ED + c];
    __syncthreads();
    int s = src[e], d = dst[e];
    float acc = bec_l[c];
    #pragma unroll
    for (int k = 0; k < ED; ++k) acc += efs[le][k] * Wec_l[k * H + c];
    acc += hs[(size_t)s * H + c] + hd[(size_t)d * H + c];
    hid[le][c] = fmaxf(acc, 0.f);
    __syncthreads();
    float m = b2[c];
    #pragma unroll 8
    for (int k = 0; k < H; ++k) m += hid[le][k] * W2[k * H + c];
    atomicAdd(&agg[(size_t)d * H + c], m);
}

// ---------------------------------------------------------------------------
// h_new = relu([h, agg] @ updW + updb) ; h = LN(h + h_new)*g + b
// one node per 128-thread block (2 waves)
// ---------------------------------------------------------------------------
__global__ void node_update(const float* __restrict__ agg,
                            const float* __restrict__ updWl,
                            const float* __restrict__ updbl,
                            const float* __restrict__ lng,
                            const float* __restrict__ lnb,
                            float* __restrict__ h) {
    int n = blockIdx.x;
    int c = threadIdx.x;                       // 0..127
    __shared__ float in[2 * H];
    __shared__ float rs[2][2];
    float hv = h[(size_t)n * H + c];
    in[c]     = hv;
    in[H + c] = agg[(size_t)n * H + c];
    __syncthreads();
    float acc = updbl[c];
    #pragma unroll 8
    for (int k = 0; k < 2 * H; ++k) acc += in[k] * updWl[k * H + c];
    float x = hv + fmaxf(acc, 0.f);
    float s1 = x, s2 = x * x;
    #pragma unroll
    for (int off = 32; off >= 1; off >>= 1) {
        s1 += __shfl_xor(s1, off, 64);
        s2 += __shfl_xor(s2, off, 64);
    }
    int w = c >> 6;
    if ((c & 63) == 0) { rs[w][0] = s1; rs[w][1] = s2; }
    __syncthreads();
    float S1 = rs[0][0] + rs[1][0];
    float S2 = rs[0][1] + rs[1][1];
    float mu  = S1 * (1.0f / H);
    float var = S2 * (1.0f / H) - mu * mu;
    float inv = rsqrtf(var + EPSF);
    h[(size_t)n * H + c] = (x - mu) * inv * lng[c] + lnb[c];
}

// ---------------------------------------------------------------------------
// per-graph mean (denom = count+1) and max pooling; batch is sorted.
// one graph per 128-thread block, boundaries by binary search
// ---------------------------------------------------------------------------
__global__ void pool(const float* __restrict__ h,
                     const int* __restrict__ batch,
                     float* __restrict__ hg) {
    int g = blockIdx.x;
    int c = threadIdx.x;
    int lo = 0, hi = NN;
    while (lo < hi) { int mid = (lo + hi) >> 1; if (batch[mid] < g) lo = mid + 1; else hi = mid; }
    int start = lo;
    hi = NN;
    while (lo < hi) { int mid = (lo + hi) >> 1; if (batch[mid] < g + 1) lo = mid + 1; else hi = mid; }
    int end = lo;
    float s = 0.f, mx = -INFINITY;
    for (int n = start; n < end; ++n) {
        float v = h[(size_t)n * H + c];
        s += v;
        mx = fmaxf(mx, v);
    }
    float denom = (float)(end - start) + 1.0f;
    hg[(size_t)g * 2 * H + c]     = s / denom;
    hg[(size_t)g * 2 * H + H + c] = mx;
}

// ---------------------------------------------------------------------------
// readout MLP: relu(hg@W1+b1) -> relu(@W2+b2) -> @W3+b3 ; one graph per block
// ---------------------------------------------------------------------------
__global__ void readout(const float* __restrict__ hg,
                        const float* __restrict__ W1, const float* __restrict__ b1,
                        const float* __restrict__ W2, const float* __restrict__ b2,
                        const float* __restrict__ W3, const float* __restrict__ b3,
                        float* __restrict__ out) {
    int g = blockIdx.x, t = threadIdx.x;       // 128 threads
    __shared__ float xin[2 * H];
    __shared__ float x1[H];
    __shared__ float x2[H / 2];
    xin[t]     = hg[(size_t)g * 2 * H + t];
    xin[H + t] = hg[(size_t)g * 2 * H + H + t];
    __syncthreads();
    float acc = b1[t];
    for (int k = 0; k < 2 * H; ++k) acc += xin[k] * W1[k * H + t];
    x1[t] = fmaxf(acc, 0.f);
    __syncthreads();
    if (t < 64) {
        float a2 = b2[t];
        for (int k = 0; k < H; ++k) a2 += x1[k] * W2[k * 64 + t];
        x2[t] = fmaxf(a2, 0.f);
    }
    __syncthreads();
    if (t < 64) {
        float v = x2[t] * W3[t];
        #pragma unroll
        for (int off = 32; off >= 1; off >>= 1) v += __shfl_xor(v, off, 64);
        if (t == 0) out[g] = v + b3[0];
    }
}

// ---------------------------------------------------------------------------
extern "C" void kernel_launch(void* const* d_in, const int* in_sizes, int n_in,
                              void* d_out, int out_size, void* d_ws, size_t ws_size,
                              hipStream_t stream) {
    const float* node_feats = (const float*)d_in[0];
    const int*   edge_index = (const int*)d_in[1];
    const float* edge_feats = (const float*)d_in[2];
    const int*   batch      = (const int*)d_in[3];
    const float* ne_W  = (const float*)d_in[4];
    const float* ne_b  = (const float*)d_in[5];
    const float* ee_W  = (const float*)d_in[6];
    const float* ee_b  = (const float*)d_in[7];
    const float* msgW1 = (const float*)d_in[8];
    const float* msgb1 = (const float*)d_in[9];
    const float* msgW2 = (const float*)d_in[10];
    const float* msgb2 = (const float*)d_in[11];
    const float* updW  = (const float*)d_in[12];
    const float* updb  = (const float*)d_in[13];
    const float* lng   = (const float*)d_in[14];
    const float* lnb   = (const float*)d_in[15];
    const float* roW1  = (const float*)d_in[16];
    const float* rob1  = (const float*)d_in[17];
    const float* roW2  = (const float*)d_in[18];
    const float* rob2  = (const float*)d_in[19];
    const float* roW3  = (const float*)d_in[20];
    const float* rob3  = (const float*)d_in[21];

    const int* src = edge_index;            // row 0
    const int* dst = edge_index + NE;       // row 1

    char* ws = (char*)d_ws;
    float* h   = (float*)ws; ws += (size_t)NN * H * 4;
    float* hs  = (float*)ws; ws += (size_t)NN * H * 4;
    float* hd  = (float*)ws; ws += (size_t)NN * H * 4;
    float* agg = (float*)ws; ws += (size_t)NN * H * 4;
    float* Wec = (float*)ws; ws += (size_t)NL * ED * H * 4;
    float* bec = (float*)ws; ws += (size_t)NL * H * 4;
    float* hg  = (float*)ws; ws += (size_t)NG * 2 * H * 4;

    encode_nodes<<<NN, H, 0, stream>>>(node_feats, ne_W, ne_b, h);
    fold_edge_weights<<<dim3(ED + 1, NL), H, 0, stream>>>(ee_W, ee_b, msgW1, msgb1, Wec, bec);

    for (int l = 0; l < NL; ++l) {
        node_msg_pre<<<NN, 256, 0, stream>>>(h, msgW1 + (size_t)l * 3 * H * H, hs, hd, agg);
        edge_msg<<<NE / 2, 256, 0, stream>>>(src, dst, edge_feats, hs, hd,
                                             Wec + (size_t)l * ED * H,
                                             bec + (size_t)l * H,
                                             msgW2 + (size_t)l * H * H,
                                             msgb2 + (size_t)l * H, agg);
        node_update<<<NN, H, 0, stream>>>(agg, updW + (size_t)l * 2 * H * H,
                                          updb + (size_t)l * H,
                                          lng + (size_t)l * H, lnb + (size_t)l * H, h);
    }

    pool<<<NG, H, 0, stream>>>(h, batch, hg);
    readout<<<NG, H, 0, stream>>>(hg, roW1, rob1, roW2, rob2, roW3, rob3, (float*)d_out);
}

// Round 2
// 1550.638 us; speedup vs baseline: 3.9063x; 3.9063x over previous
//
#include <hip/hip_runtime.h>
#include <math.h>

#define NN 100000
#define NE 500000
#define NG 128
#define ND 91
#define ED 20
#define H  128
#define NL 3
#define EPSF 1e-5f
#define NT 8            // nodes per block in tiled GEMV kernels

// ---------------------------------------------------------------------------
// h = node_feats @ ne_W + ne_b     (NT nodes per 128-thread block)
// ---------------------------------------------------------------------------
__global__ void encode_nodes_t(const float* __restrict__ nf,
                               const float* __restrict__ W,
                               const float* __restrict__ b,
                               float* __restrict__ h) {
    int c = threadIdx.x;                       // 0..127
    int n0 = blockIdx.x * NT;
    __shared__ float rows[NT][ND];
    #pragma unroll
    for (int nt = 0; nt < NT; ++nt)
        if (c < ND) rows[nt][c] = nf[(size_t)(n0 + nt) * ND + c];
    __syncthreads();
    float bb = b[c];
    float acc[NT];
    #pragma unroll
    for (int nt = 0; nt < NT; ++nt) acc[nt] = bb;
    for (int k = 0; k < ND; ++k) {
        float w = W[k * H + c];
        #pragma unroll
        for (int nt = 0; nt < NT; ++nt) acc[nt] += rows[nt][k] * w;
    }
    #pragma unroll
    for (int nt = 0; nt < NT; ++nt) h[(size_t)(n0 + nt) * H + c] = acc[nt];
}

// ---------------------------------------------------------------------------
// Fold edge-feature path: Wec[l] = ee_W @ msg_W1[l][2H:3H,:]
//                         bec[l] = ee_b @ msg_W1[l][2H:3H,:] + msg_b1[l]
// ---------------------------------------------------------------------------
__global__ void fold_edge_weights(const float* __restrict__ eeW,
                                  const float* __restrict__ eeb,
                                  const float* __restrict__ msgW1,
                                  const float* __restrict__ msgb1,
                                  float* __restrict__ Wec,
                                  float* __restrict__ bec) {
    int l = blockIdx.y;
    int k = blockIdx.x;                        // 0..ED (ED => bias row)
    int c = threadIdx.x;
    const float* W1e = msgW1 + (size_t)l * 3 * H * H + (size_t)2 * H * H;
    if (k < ED) {
        float acc = 0.f;
        for (int m = 0; m < H; ++m) acc += eeW[k * H + m] * W1e[m * H + c];
        Wec[((size_t)l * ED + k) * H + c] = acc;
    } else {
        float acc = msgb1[l * H + c];
        for (int m = 0; m < H; ++m) acc += eeb[m] * W1e[m * H + c];
        bec[(size_t)l * H + c] = acc;
    }
}

// ---------------------------------------------------------------------------
// Fold msg_W2 into the update weights:
//   W2u[l] = msg_W2[l] @ updW[l][H:2H,:]   (H x H)
//   b2u[l] = msg_b2[l] @ updW[l][H:2H,:]   (H)
// grid (H+1, NL) x 128
// ---------------------------------------------------------------------------
__global__ void fold_W2u(const float* __restrict__ msgW2,
                         const float* __restrict__ msgb2,
                         const float* __restrict__ updW,
                         float* __restrict__ W2u,
                         float* __restrict__ b2u) {
    int l = blockIdx.y;
    int k = blockIdx.x;                        // 0..H (H => bias row)
    int c = threadIdx.x;
    const float* Wbot = updW + (size_t)l * 2 * H * H + (size_t)H * H;
    if (k < H) {
        const float* w2row = msgW2 + (size_t)l * H * H + (size_t)k * H;
        float acc = 0.f;
        for (int m = 0; m < H; ++m) acc += w2row[m] * Wbot[m * H + c];
        W2u[((size_t)l * H + k) * H + c] = acc;
    } else {
        const float* b2 = msgb2 + (size_t)l * H;
        float acc = 0.f;
        for (int m = 0; m < H; ++m) acc += b2[m] * Wbot[m * H + c];
        b2u[(size_t)l * H + c] = acc;
    }
}

// ---------------------------------------------------------------------------
// CSR build over dst
// ---------------------------------------------------------------------------
__global__ void csr_count(const int* __restrict__ dst, int* __restrict__ deg) {
    int e = blockIdx.x * blockDim.x + threadIdx.x;
    if (e < NE) atomicAdd(&deg[dst[e]], 1);
}

// single block, 1024 threads: exclusive scan deg -> rowstart, rowstart[NN]=NE
__global__ void scan_deg(const int* __restrict__ deg, int* __restrict__ rowstart) {
    __shared__ int wsum[16];
    __shared__ int carry_s;
    int t = threadIdx.x, lane = t & 63, w = t >> 6;
    if (t == 0) carry_s = 0;
    __syncthreads();
    for (int base = 0; base < NN; base += 1024) {
        int i = base + t;
        int v = (i < NN) ? deg[i] : 0;
        int inc = v;
        #pragma unroll
        for (int off = 1; off < 64; off <<= 1) {
            int u = __shfl_up(inc, off, 64);
            if (lane >= off) inc += u;
        }
        if (lane == 63) wsum[w] = inc;
        __syncthreads();
        if (t == 0) {
            int run = carry_s;
            #pragma unroll
            for (int q = 0; q < 16; ++q) { int tmp = wsum[q]; wsum[q] = run; run += tmp; }
            carry_s = run;
        }
        __syncthreads();
        if (i < NN) rowstart[i] = wsum[w] + inc - v;
        __syncthreads();
    }
    if (t == 0) rowstart[NN] = NE;
}

__global__ void csr_scatter(const int* __restrict__ dst,
                            const int* __restrict__ rowstart,
                            int* __restrict__ cursor,
                            int* __restrict__ ecsr) {
    int e = blockIdx.x * blockDim.x + threadIdx.x;
    if (e < NE) {
        int d = dst[e];
        int pos = atomicAdd(&cursor[d], 1);
        ecsr[rowstart[d] + pos] = e;
    }
}

// ---------------------------------------------------------------------------
// hs = h @ W1[0:H,:],  hd = h @ W1[H:2H,:]   (NT nodes per 256-thread block)
// ---------------------------------------------------------------------------
__global__ void node_msg_pre_t(const float* __restrict__ h,
                               const float* __restrict__ W1l,
                               float* __restrict__ hs,
                               float* __restrict__ hd) {
    int t = threadIdx.x;                       // 0..255
    int c = t & 127;
    int half = t >> 7;
    int n0 = blockIdx.x * NT;
    __shared__ float rows[NT][H];
    for (int idx = t; idx < NT * H; idx += 256)
        rows[idx >> 7][idx & 127] = h[(size_t)n0 * H + idx];
    __syncthreads();
    const float* W = W1l + (size_t)half * H * H;
    float acc[NT];
    #pragma unroll
    for (int nt = 0; nt < NT; ++nt) acc[nt] = 0.f;
    for (int k = 0; k < H; ++k) {
        float w = W[k * H + c];
        #pragma unroll
        for (int nt = 0; nt < NT; ++nt) acc[nt] += rows[nt][k] * w;
    }
    float* out = half ? hd : hs;
    #pragma unroll
    for (int nt = 0; nt < NT; ++nt) out[(size_t)(n0 + nt) * H + c] = acc[nt];
}

// ---------------------------------------------------------------------------
// hidsum[n] = sum_{e in in(n)} relu(hs[src_e] + hd[n] + ef[e]@Wec + bec)
// one node per 128-thread block, CSR edges, zero atomics
// ---------------------------------------------------------------------------
__global__ void node_aggregate(const int* __restrict__ src,
                               const int* __restrict__ ecsr,
                               const int* __restrict__ rowstart,
                               const float* __restrict__ ef,
                               const float* __restrict__ hs,
                               const float* __restrict__ hd,
                               const float* __restrict__ Wec_l,
                               const float* __restrict__ bec_l,
                               float* __restrict__ hidsum) {
    int n = blockIdx.x, c = threadIdx.x;
    int beg = rowstart[n], end = rowstart[n + 1];
    float wec[ED];
    #pragma unroll
    for (int k = 0; k < ED; ++k) wec[k] = Wec_l[k * H + c];
    float hdv = hd[(size_t)n * H + c] + bec_l[c];
    float acc = 0.f;
    for (int j = beg; j < end; ++j) {
        int e = ecsr[j];                       // uniform per block
        int s = src[e];                        // uniform
        const float* efp = ef + (size_t)e * ED;
        float v = hdv + hs[(size_t)s * H + c];
        #pragma unroll
        for (int k = 0; k < ED; ++k) v = fmaf(efp[k], wec[k], v);
        acc += fmaxf(v, 0.f);
    }
    hidsum[(size_t)n * H + c] = acc;
}

// ---------------------------------------------------------------------------
// x = h + relu(h@updW_top + hidsum@W2u + deg*b2u + updb); h = LN(x)*g + b
// NT nodes per 128-thread block
// ---------------------------------------------------------------------------
__global__ void node_update_t(const float* __restrict__ hidsum,
                              const int* __restrict__ rowstart,
                              const float* __restrict__ updWl,   // top H x H
                              const float* __restrict__ W2u_l,
                              const float* __restrict__ b2u_l,
                              const float* __restrict__ updbl,
                              const float* __restrict__ lng,
                              const float* __restrict__ lnb,
                              float* __restrict__ h) {
    int c = threadIdx.x;                       // 0..127
    int n0 = blockIdx.x * NT;
    __shared__ float rh[NT][H];
    __shared__ float rs[NT][H];
    __shared__ float red[NT][2][2];
    #pragma unroll
    for (int nt = 0; nt < NT; ++nt) {
        rh[nt][c] = h[(size_t)(n0 + nt) * H + c];
        rs[nt][c] = hidsum[(size_t)(n0 + nt) * H + c];
    }
    __syncthreads();
    float ub = updbl[c], b2 = b2u_l[c];
    float acc[NT];
    #pragma unroll
    for (int nt = 0; nt < NT; ++nt) {
        float deg = (float)(rowstart[n0 + nt + 1] - rowstart[n0 + nt]);
        acc[nt] = ub + b2 * deg;
    }
    for (int k = 0; k < H; ++k) {
        float w = updWl[k * H + c];
        #pragma unroll
        for (int nt = 0; nt < NT; ++nt) acc[nt] += rh[nt][k] * w;
    }
    for (int k = 0; k < H; ++k) {
        float w = W2u_l[k * H + c];
        #pragma unroll
        for (int nt = 0; nt < NT; ++nt) acc[nt] += rs[nt][k] * w;
    }
    float x[NT];
    #pragma unroll
    for (int nt = 0; nt < NT; ++nt) x[nt] = rh[nt][c] + fmaxf(acc[nt], 0.f);
    // layernorm per node
    int w64 = c >> 6;
    #pragma unroll
    for (int nt = 0; nt < NT; ++nt) {
        float s1 = x[nt], s2 = x[nt] * x[nt];
        #pragma unroll
        for (int off = 32; off >= 1; off >>= 1) {
            s1 += __shfl_xor(s1, off, 64);
            s2 += __shfl_xor(s2, off, 64);
        }
        if ((c & 63) == 0) { red[nt][w64][0] = s1; red[nt][w64][1] = s2; }
    }
    __syncthreads();
    #pragma unroll
    for (int nt = 0; nt < NT; ++nt) {
        float S1 = red[nt][0][0] + red[nt][1][0];
        float S2 = red[nt][0][1] + red[nt][1][1];
        float mu  = S1 * (1.0f / H);
        float var = S2 * (1.0f / H) - mu * mu;
        float inv = rsqrtf(var + EPSF);
        h[(size_t)(n0 + nt) * H + c] = (x[nt] - mu) * inv * lng[c] + lnb[c];
    }
}

// ---------------------------------------------------------------------------
// per-graph mean (denom = count+1) and max pooling; batch sorted.
// one graph per 512-thread block (4-way node parallel)
// ---------------------------------------------------------------------------
__global__ void pool(const float* __restrict__ h,
                     const int* __restrict__ batch,
                     float* __restrict__ hg) {
    int g = blockIdx.x;
    int t = threadIdx.x;
    int c = t & 127, q = t >> 7;               // q = 0..3
    int lo = 0, hi = NN;
    while (lo < hi) { int mid = (lo + hi) >> 1; if (batch[mid] < g) lo = mid + 1; else hi = mid; }
    int start = lo;
    hi = NN;
    while (lo < hi) { int mid = (lo + hi) >> 1; if (batch[mid] < g + 1) lo = mid + 1; else hi = mid; }
    int end = lo;
    float s = 0.f, mx = -INFINITY;
    for (int n = start + q; n < end; n += 4) {
        float v = h[(size_t)n * H + c];
        s += v;
        mx = fmaxf(mx, v);
    }
    __shared__ float shs[4][H];
    __shared__ float shm[4][H];
    shs[q][c] = s; shm[q][c] = mx;
    __syncthreads();
    if (q == 0) {
        float S = shs[0][c] + shs[1][c] + shs[2][c] + shs[3][c];
        float M = fmaxf(fmaxf(shm[0][c], shm[1][c]), fmaxf(shm[2][c], shm[3][c]));
        float denom = (float)(end - start) + 1.0f;
        hg[(size_t)g * 2 * H + c]     = S / denom;
        hg[(size_t)g * 2 * H + H + c] = M;
    }
}

// ---------------------------------------------------------------------------
// readout MLP
// ---------------------------------------------------------------------------
__global__ void readout(const float* __restrict__ hg,
                        const float* __restrict__ W1, const float* __restrict__ b1,
                        const float* __restrict__ W2, const float* __restrict__ b2,
                        const float* __restrict__ W3, const float* __restrict__ b3,
                        float* __restrict__ out) {
    int g = blockIdx.x, t = threadIdx.x;       // 128 threads
    __shared__ float xin[2 * H];
    __shared__ float x1[H];
    __shared__ float x2[H / 2];
    xin[t]     = hg[(size_t)g * 2 * H + t];
    xin[H + t] = hg[(size_t)g * 2 * H + H + t];
    __syncthreads();
    float acc = b1[t];
    for (int k = 0; k < 2 * H; ++k) acc += xin[k] * W1[k * H + t];
    x1[t] = fmaxf(acc, 0.f);
    __syncthreads();
    if (t < 64) {
        float a2 = b2[t];
        for (int k = 0; k < H; ++k) a2 += x1[k] * W2[k * 64 + t];
        x2[t] = fmaxf(a2, 0.f);
    }
    __syncthreads();
    if (t < 64) {
        float v = x2[t] * W3[t];
        #pragma unroll
        for (int off = 32; off >= 1; off >>= 1) v += __shfl_xor(v, off, 64);
        if (t == 0) out[g] = v + b3[0];
    }
}

// ---------------------------------------------------------------------------
extern "C" void kernel_launch(void* const* d_in, const int* in_sizes, int n_in,
                              void* d_out, int out_size, void* d_ws, size_t ws_size,
                              hipStream_t stream) {
    const float* node_feats = (const float*)d_in[0];
    const int*   edge_index = (const int*)d_in[1];
    const float* edge_feats = (const float*)d_in[2];
    const int*   batch      = (const int*)d_in[3];
    const float* ne_W  = (const float*)d_in[4];
    const float* ne_b  = (const float*)d_in[5];
    const float* ee_W  = (const float*)d_in[6];
    const float* ee_b  = (const float*)d_in[7];
    const float* msgW1 = (const float*)d_in[8];
    const float* msgb1 = (const float*)d_in[9];
    const float* msgW2 = (const float*)d_in[10];
    const float* msgb2 = (const float*)d_in[11];
    const float* updW  = (const float*)d_in[12];
    const float* updb  = (const float*)d_in[13];
    const float* lng   = (const float*)d_in[14];
    const float* lnb   = (const float*)d_in[15];
    const float* roW1  = (const float*)d_in[16];
    const float* rob1  = (const float*)d_in[17];
    const float* roW2  = (const float*)d_in[18];
    const float* rob2  = (const float*)d_in[19];
    const float* roW3  = (const float*)d_in[20];
    const float* rob3  = (const float*)d_in[21];

    const int* src = edge_index;            // row 0
    const int* dst = edge_index + NE;       // row 1

    char* ws = (char*)d_ws;
    float* h      = (float*)ws; ws += (size_t)NN * H * 4;
    float* hs     = (float*)ws; ws += (size_t)NN * H * 4;
    float* hd     = (float*)ws; ws += (size_t)NN * H * 4;
    float* hidsum = (float*)ws; ws += (size_t)NN * H * 4;
    float* Wec = (float*)ws; ws += (size_t)NL * ED * H * 4;
    float* bec = (float*)ws; ws += (size_t)NL * H * 4;
    float* W2u = (float*)ws; ws += (size_t)NL * H * H * 4;
    float* b2u = (float*)ws; ws += (size_t)NL * H * 4;
    float* hg  = (float*)ws; ws += (size_t)NG * 2 * H * 4;
    int* rowstart = (int*)ws; ws += (size_t)(NN + 4) * 4;
    int* deg      = (int*)ws; ws += (size_t)NN * 4;     // also reused as cursor
    int* ecsr     = (int*)ws; ws += (size_t)NE * 4;

    // --- precompute (topology + folded weights) ---
    encode_nodes_t<<<NN / NT, H, 0, stream>>>(node_feats, ne_W, ne_b, h);
    fold_edge_weights<<<dim3(ED + 1, NL), H, 0, stream>>>(ee_W, ee_b, msgW1, msgb1, Wec, bec);
    fold_W2u<<<dim3(H + 1, NL), H, 0, stream>>>(msgW2, msgb2, updW, W2u, b2u);

    hipMemsetAsync(deg, 0, (size_t)NN * 4, stream);
    csr_count<<<(NE + 255) / 256, 256, 0, stream>>>(dst, deg);
    scan_deg<<<1, 1024, 0, stream>>>(deg, rowstart);
    hipMemsetAsync(deg, 0, (size_t)NN * 4, stream);
    csr_scatter<<<(NE + 255) / 256, 256, 0, stream>>>(dst, rowstart, deg, ecsr);

    // --- layers ---
    for (int l = 0; l < NL; ++l) {
        node_msg_pre_t<<<NN / NT, 256, 0, stream>>>(h, msgW1 + (size_t)l * 3 * H * H, hs, hd);
        node_aggregate<<<NN, H, 0, stream>>>(src, ecsr, rowstart, edge_feats, hs, hd,
                                             Wec + (size_t)l * ED * H,
                                             bec + (size_t)l * H, hidsum);
        node_update_t<<<NN / NT, H, 0, stream>>>(hidsum, rowstart,
                                                 updW + (size_t)l * 2 * H * H,
                                                 W2u + (size_t)l * H * H,
                                                 b2u + (size_t)l * H,
                                                 updb + (size_t)l * H,
                                                 lng + (size_t)l * H, lnb + (size_t)l * H, h);
    }

    pool<<<NG, 512, 0, stream>>>(h, batch, hg);
    readout<<<NG, H, 0, stream>>>(hg, roW1, rob1, roW2, rob2, roW3, rob3, (float*)d_out);
}

// Round 3
// 1419.936 us; speedup vs baseline: 4.2659x; 1.0920x over previous
//
#include <hip/hip_runtime.h>
#include <hip/hip_fp16.h>
#include <math.h>

#define NN 100000
#define NE 500000
#define NG 128
#define ND 91
#define ED 20
#define H  128
#define NL 3
#define EPSF 1e-5f
#define NT 16           // nodes per block in fused GEMV kernels
#define EPB 32          // edges per block in aggregation

// ---------------------------------------------------------------------------
// Fold edge-feature path: Wec[l] = ee_W @ msg_W1[l][2H:3H,:]
//                         bec[l] = ee_b @ msg_W1[l][2H:3H,:] + msg_b1[l]
// ---------------------------------------------------------------------------
__global__ void fold_edge_weights(const float* __restrict__ eeW,
                                  const float* __restrict__ eeb,
                                  const float* __restrict__ msgW1,
                                  const float* __restrict__ msgb1,
                                  float* __restrict__ Wec,
                                  float* __restrict__ bec) {
    int l = blockIdx.y;
    int k = blockIdx.x;                        // 0..ED (ED => bias row)
    int c = threadIdx.x;
    const float* W1e = msgW1 + (size_t)l * 3 * H * H + (size_t)2 * H * H;
    if (k < ED) {
        float acc = 0.f;
        for (int m = 0; m < H; ++m) acc += eeW[k * H + m] * W1e[m * H + c];
        Wec[((size_t)l * ED + k) * H + c] = acc;
    } else {
        float acc = msgb1[l * H + c];
        for (int m = 0; m < H; ++m) acc += eeb[m] * W1e[m * H + c];
        bec[(size_t)l * H + c] = acc;
    }
}

// ---------------------------------------------------------------------------
// Fold msg_W2 into update weights: W2u[l] = msg_W2[l] @ updW[l][H:2H,:]
//                                  b2u[l] = msg_b2[l] @ updW[l][H:2H,:]
// ---------------------------------------------------------------------------
__global__ void fold_W2u(const float* __restrict__ msgW2,
                         const float* __restrict__ msgb2,
                         const float* __restrict__ updW,
                         float* __restrict__ W2u,
                         float* __restrict__ b2u) {
    int l = blockIdx.y;
    int k = blockIdx.x;                        // 0..H (H => bias row)
    int c = threadIdx.x;
    const float* Wbot = updW + (size_t)l * 2 * H * H + (size_t)H * H;
    if (k < H) {
        const float* w2row = msgW2 + (size_t)l * H * H + (size_t)k * H;
        float acc = 0.f;
        for (int m = 0; m < H; ++m) acc += w2row[m] * Wbot[m * H + c];
        W2u[((size_t)l * H + k) * H + c] = acc;
    } else {
        const float* b2 = msgb2 + (size_t)l * H;
        float acc = 0.f;
        for (int m = 0; m < H; ++m) acc += b2[m] * Wbot[m * H + c];
        b2u[(size_t)l * H + c] = acc;
    }
}

// ---------------------------------------------------------------------------
// CSR build over dst (+ reorder src/dst/edge_feats into CSR order)
// ---------------------------------------------------------------------------
__global__ void csr_count(const int* __restrict__ dst, int* __restrict__ deg) {
    int e = blockIdx.x * blockDim.x + threadIdx.x;
    if (e < NE) atomicAdd(&deg[dst[e]], 1);
}

__global__ void scan_deg(const int* __restrict__ deg, int* __restrict__ rowstart) {
    __shared__ int wsum[16];
    __shared__ int carry_s;
    int t = threadIdx.x, lane = t & 63, w = t >> 6;
    if (t == 0) carry_s = 0;
    __syncthreads();
    for (int base = 0; base < NN; base += 1024) {
        int i = base + t;
        int v = (i < NN) ? deg[i] : 0;
        int inc = v;
        #pragma unroll
        for (int off = 1; off < 64; off <<= 1) {
            int u = __shfl_up(inc, off, 64);
            if (lane >= off) inc += u;
        }
        if (lane == 63) wsum[w] = inc;
        __syncthreads();
        if (t == 0) {
            int run = carry_s;
            #pragma unroll
            for (int q = 0; q < 16; ++q) { int tmp = wsum[q]; wsum[q] = run; run += tmp; }
            carry_s = run;
        }
        __syncthreads();
        if (i < NN) rowstart[i] = wsum[w] + inc - v;
        __syncthreads();
    }
    if (t == 0) rowstart[NN] = NE;
}

__global__ void csr_scatter(const int* __restrict__ src,
                            const int* __restrict__ dst,
                            const float* __restrict__ ef,
                            const int* __restrict__ rowstart,
                            int* __restrict__ cursor,
                            int* __restrict__ srcs,
                            int* __restrict__ dsts,
                            float* __restrict__ efs) {
    int e = blockIdx.x * blockDim.x + threadIdx.x;
    if (e < NE) {
        int d = dst[e];
        int pos = atomicAdd(&cursor[d], 1);
        int j = rowstart[d] + pos;
        srcs[j] = src[e];
        dsts[j] = d;
        const float* efp = ef + (size_t)e * ED;
        float* out = efs + (size_t)j * ED;
        #pragma unroll
        for (int k = 0; k < ED; ++k) out[k] = efp[k];
    }
}

// ---------------------------------------------------------------------------
// Fused: h = nf@neW + neb ; hs/hd = h @ W1[0:H]/W1[H:2H] (fp16) ; hidsum = 0
// NT nodes per 128-thread block
// ---------------------------------------------------------------------------
__global__ void __launch_bounds__(128)
encode_pre(const float* __restrict__ nf,
           const float* __restrict__ neW, const float* __restrict__ neb,
           const float* __restrict__ W1l,
           float* __restrict__ h, __half* __restrict__ hs, __half* __restrict__ hd,
           float* __restrict__ hidsum) {
    int c = threadIdx.x;
    int n0 = blockIdx.x * NT;
    __shared__ float rows[NT][92];             // padded: 92*4 = 368 B, 16B-aligned rows
    __shared__ float hrow[NT][H];
    for (int i = c; i < NT * ND; i += 128) rows[i / ND][i % ND] = nf[(size_t)n0 * ND + i];
    __syncthreads();
    float bb = neb[c];
    float acc[NT];
    #pragma unroll
    for (int nt = 0; nt < NT; ++nt) acc[nt] = bb;
    for (int k0 = 0; k0 + 4 <= ND; k0 += 4) {
        float w0 = neW[(k0 + 0) * H + c];
        float w1 = neW[(k0 + 1) * H + c];
        float w2 = neW[(k0 + 2) * H + c];
        float w3 = neW[(k0 + 3) * H + c];
        #pragma unroll
        for (int nt = 0; nt < NT; ++nt) {
            float4 r = *(const float4*)&rows[nt][k0];
            acc[nt] += r.x * w0 + r.y * w1 + r.z * w2 + r.w * w3;
        }
    }
    for (int k = ND & ~3; k < ND; ++k) {
        float w = neW[k * H + c];
        #pragma unroll
        for (int nt = 0; nt < NT; ++nt) acc[nt] += rows[nt][k] * w;
    }
    #pragma unroll
    for (int nt = 0; nt < NT; ++nt) {
        h[(size_t)(n0 + nt) * H + c] = acc[nt];
        hrow[nt][c] = acc[nt];
        hidsum[(size_t)(n0 + nt) * H + c] = 0.f;
    }
    __syncthreads();
    float a1[NT], a2[NT];
    #pragma unroll
    for (int nt = 0; nt < NT; ++nt) { a1[nt] = 0.f; a2[nt] = 0.f; }
    for (int k0 = 0; k0 < H; k0 += 4) {
        float u0 = W1l[(k0 + 0) * H + c], v0 = W1l[(H + k0 + 0) * H + c];
        float u1 = W1l[(k0 + 1) * H + c], v1 = W1l[(H + k0 + 1) * H + c];
        float u2 = W1l[(k0 + 2) * H + c], v2 = W1l[(H + k0 + 2) * H + c];
        float u3 = W1l[(k0 + 3) * H + c], v3 = W1l[(H + k0 + 3) * H + c];
        #pragma unroll
        for (int nt = 0; nt < NT; ++nt) {
            float4 r = *(const float4*)&hrow[nt][k0];
            a1[nt] += r.x * u0 + r.y * u1 + r.z * u2 + r.w * u3;
            a2[nt] += r.x * v0 + r.y * v1 + r.z * v2 + r.w * v3;
        }
    }
    #pragma unroll
    for (int nt = 0; nt < NT; ++nt) {
        hs[(size_t)(n0 + nt) * H + c] = __float2half(a1[nt]);
        hd[(size_t)(n0 + nt) * H + c] = __float2half(a2[nt]);
    }
}

// ---------------------------------------------------------------------------
// Edge-parallel segmented aggregation over CSR-sorted edges, EPB per block.
// hidsum[d] += relu(hs[s] + hd[d] + ef@Wec + bec) ; interior segs: plain store
// ---------------------------------------------------------------------------
__global__ void __launch_bounds__(128)
aggregate_edges(const int* __restrict__ srcs,
                const int* __restrict__ dsts,
                const float* __restrict__ efs,
                const __half* __restrict__ hs,
                const __half* __restrict__ hd,
                const float* __restrict__ Wec_l,
                const float* __restrict__ bec_l,
                float* __restrict__ hidsum) {
    int c = threadIdx.x;
    size_t j0 = (size_t)blockIdx.x * EPB;
    __shared__ float efs_lds[EPB][ED];
    __shared__ int sd[2 * EPB];
    const float* efsrc = efs + j0 * ED;
    for (int i = c; i < EPB * ED; i += 128) ((float*)efs_lds)[i] = efsrc[i];
    if (c < EPB) { sd[c] = srcs[j0 + c]; sd[EPB + c] = dsts[j0 + c]; }
    __syncthreads();
    float wec[ED];
    #pragma unroll
    for (int k = 0; k < ED; ++k) wec[k] = Wec_l[k * H + c];
    float becc = bec_l[c];
    // independent gather batch (deep MLP)
    float hv[EPB];
    #pragma unroll
    for (int jj = 0; jj < EPB; ++jj) {
        hv[jj] = __half2float(hs[(size_t)sd[jj] * H + c])
               + __half2float(hd[(size_t)sd[EPB + jj] * H + c]);
    }
    int dcur = sd[EPB];
    float acc = 0.f;
    int nflush = 0;
    #pragma unroll
    for (int jj = 0; jj < EPB; ++jj) {
        int d = sd[EPB + jj];
        if (d != dcur) {                       // uniform branch
            if (nflush == 0) atomicAdd(&hidsum[(size_t)dcur * H + c], acc);
            else             hidsum[(size_t)dcur * H + c] = acc;   // interior
            dcur = d; acc = 0.f; ++nflush;
        }
        float v = hv[jj] + becc;
        #pragma unroll
        for (int k = 0; k < ED; ++k) v = fmaf(efs_lds[jj][k], wec[k], v);
        acc += fmaxf(v, 0.f);
    }
    atomicAdd(&hidsum[(size_t)dcur * H + c], acc);  // last segment may continue
}

// ---------------------------------------------------------------------------
// Fused: x = h + relu(h@updW_top + hidsum@W2u + deg*b2u + updb); h=LN(x)*g+b
// then (if !last): hs/hd for next layer, hidsum=0.  NT nodes / 128 threads.
// ---------------------------------------------------------------------------
__global__ void __launch_bounds__(128)
update_pre(const float* __restrict__ hidsum,
           const int* __restrict__ rowstart,
           const float* __restrict__ updWl,    // [2H][H], top H rows used
           const float* __restrict__ W2u_l,
           const float* __restrict__ b2u_l,
           const float* __restrict__ updbl,
           const float* __restrict__ lng,
           const float* __restrict__ lnb,
           const float* __restrict__ W1next,   // next layer msg_W1 (if !last)
           float* __restrict__ h,
           __half* __restrict__ hs, __half* __restrict__ hd,
           float* __restrict__ hidsum_out,
           int last) {
    int c = threadIdx.x;
    int n0 = blockIdx.x * NT;
    __shared__ float rh[NT][H];
    __shared__ float rs[NT][H];
    __shared__ float red[NT][2][2];
    for (int i = c; i < NT * H; i += 128) {
        rh[i >> 7][i & 127] = h[(size_t)n0 * H + i];
        rs[i >> 7][i & 127] = hidsum[(size_t)n0 * H + i];
    }
    __syncthreads();
    float ub = updbl[c], b2 = b2u_l[c];
    float acc[NT];
    #pragma unroll
    for (int nt = 0; nt < NT; ++nt) {
        float deg = (float)(rowstart[n0 + nt + 1] - rowstart[n0 + nt]);
        acc[nt] = ub + b2 * deg;
    }
    for (int k0 = 0; k0 < H; k0 += 4) {
        float u0 = updWl[(k0 + 0) * H + c], v0 = W2u_l[(k0 + 0) * H + c];
        float u1 = updWl[(k0 + 1) * H + c], v1 = W2u_l[(k0 + 1) * H + c];
        float u2 = updWl[(k0 + 2) * H + c], v2 = W2u_l[(k0 + 2) * H + c];
        float u3 = updWl[(k0 + 3) * H + c], v3 = W2u_l[(k0 + 3) * H + c];
        #pragma unroll
        for (int nt = 0; nt < NT; ++nt) {
            float4 a = *(const float4*)&rh[nt][k0];
            float4 b = *(const float4*)&rs[nt][k0];
            acc[nt] += a.x * u0 + a.y * u1 + a.z * u2 + a.w * u3
                     + b.x * v0 + b.y * v1 + b.z * v2 + b.w * v3;
        }
    }
    float x[NT];
    #pragma unroll
    for (int nt = 0; nt < NT; ++nt) x[nt] = rh[nt][c] + fmaxf(acc[nt], 0.f);
    int w64 = c >> 6;
    #pragma unroll
    for (int nt = 0; nt < NT; ++nt) {
        float s1 = x[nt], s2 = x[nt] * x[nt];
        #pragma unroll
        for (int off = 32; off >= 1; off >>= 1) {
            s1 += __shfl_xor(s1, off, 64);
            s2 += __shfl_xor(s2, off, 64);
        }
        if ((c & 63) == 0) { red[nt][w64][0] = s1; red[nt][w64][1] = s2; }
    }
    __syncthreads();
    float g = lng[c], bb = lnb[c];
    float hn[NT];
    #pragma unroll
    for (int nt = 0; nt < NT; ++nt) {
        float S1 = red[nt][0][0] + red[nt][1][0];
        float S2 = red[nt][0][1] + red[nt][1][1];
        float mu  = S1 * (1.0f / H);
        float var = S2 * (1.0f / H) - mu * mu;
        float inv = rsqrtf(var + EPSF);
        hn[nt] = (x[nt] - mu) * inv * g + bb;
        h[(size_t)(n0 + nt) * H + c] = hn[nt];
    }
    if (last) return;
    __syncthreads();                           // rh reads (GEMV above) done
    #pragma unroll
    for (int nt = 0; nt < NT; ++nt) {
        rh[nt][c] = hn[nt];
        hidsum_out[(size_t)(n0 + nt) * H + c] = 0.f;
    }
    __syncthreads();
    float a1[NT], a2[NT];
    #pragma unroll
    for (int nt = 0; nt < NT; ++nt) { a1[nt] = 0.f; a2[nt] = 0.f; }
    for (int k0 = 0; k0 < H; k0 += 4) {
        float u0 = W1next[(k0 + 0) * H + c], v0 = W1next[(H + k0 + 0) * H + c];
        float u1 = W1next[(k0 + 1) * H + c], v1 = W1next[(H + k0 + 1) * H + c];
        float u2 = W1next[(k0 + 2) * H + c], v2 = W1next[(H + k0 + 2) * H + c];
        float u3 = W1next[(k0 + 3) * H + c], v3 = W1next[(H + k0 + 3) * H + c];
        #pragma unroll
        for (int nt = 0; nt < NT; ++nt) {
            float4 r = *(const float4*)&rh[nt][k0];
            a1[nt] += r.x * u0 + r.y * u1 + r.z * u2 + r.w * u3;
            a2[nt] += r.x * v0 + r.y * v1 + r.z * v2 + r.w * v3;
        }
    }
    #pragma unroll
    for (int nt = 0; nt < NT; ++nt) {
        hs[(size_t)(n0 + nt) * H + c] = __float2half(a1[nt]);
        hd[(size_t)(n0 + nt) * H + c] = __float2half(a2[nt]);
    }
}

// ---------------------------------------------------------------------------
// per-graph mean (denom = count+1) and max pooling; batch sorted.
// ---------------------------------------------------------------------------
__global__ void __launch_bounds__(512)
pool(const float* __restrict__ h,
     const int* __restrict__ batch,
     float* __restrict__ hg) {
    int g = blockIdx.x;
    int t = threadIdx.x;
    int c = t & 127, q = t >> 7;               // q = 0..3
    int lo = 0, hi = NN;
    while (lo < hi) { int mid = (lo + hi) >> 1; if (batch[mid] < g) lo = mid + 1; else hi = mid; }
    int start = lo;
    hi = NN;
    while (lo < hi) { int mid = (lo + hi) >> 1; if (batch[mid] < g + 1) lo = mid + 1; else hi = mid; }
    int end = lo;
    float s = 0.f, mx = -INFINITY;
    for (int n = start + q; n < end; n += 4) {
        float v = h[(size_t)n * H + c];
        s += v;
        mx = fmaxf(mx, v);
    }
    __shared__ float shs[4][H];
    __shared__ float shm[4][H];
    shs[q][c] = s; shm[q][c] = mx;
    __syncthreads();
    if (q == 0) {
        float S = shs[0][c] + shs[1][c] + shs[2][c] + shs[3][c];
        float M = fmaxf(fmaxf(shm[0][c], shm[1][c]), fmaxf(shm[2][c], shm[3][c]));
        float denom = (float)(end - start) + 1.0f;
        hg[(size_t)g * 2 * H + c]     = S / denom;
        hg[(size_t)g * 2 * H + H + c] = M;
    }
}

// ---------------------------------------------------------------------------
// readout MLP
// ---------------------------------------------------------------------------
__global__ void __launch_bounds__(128)
readout(const float* __restrict__ hg,
        const float* __restrict__ W1, const float* __restrict__ b1,
        const float* __restrict__ W2, const float* __restrict__ b2,
        const float* __restrict__ W3, const float* __restrict__ b3,
        float* __restrict__ out) {
    int g = blockIdx.x, t = threadIdx.x;
    __shared__ float xin[2 * H];
    __shared__ float x1[H];
    __shared__ float x2[H / 2];
    xin[t]     = hg[(size_t)g * 2 * H + t];
    xin[H + t] = hg[(size_t)g * 2 * H + H + t];
    __syncthreads();
    float acc = b1[t];
    for (int k = 0; k < 2 * H; ++k) acc += xin[k] * W1[k * H + t];
    x1[t] = fmaxf(acc, 0.f);
    __syncthreads();
    if (t < 64) {
        float a2 = b2[t];
        for (int k = 0; k < H; ++k) a2 += x1[k] * W2[k * 64 + t];
        x2[t] = fmaxf(a2, 0.f);
    }
    __syncthreads();
    if (t < 64) {
        float v = x2[t] * W3[t];
        #pragma unroll
        for (int off = 32; off >= 1; off >>= 1) v += __shfl_xor(v, off, 64);
        if (t == 0) out[g] = v + b3[0];
    }
}

// ---------------------------------------------------------------------------
extern "C" void kernel_launch(void* const* d_in, const int* in_sizes, int n_in,
                              void* d_out, int out_size, void* d_ws, size_t ws_size,
                              hipStream_t stream) {
    const float* node_feats = (const float*)d_in[0];
    const int*   edge_index = (const int*)d_in[1];
    const float* edge_feats = (const float*)d_in[2];
    const int*   batch      = (const int*)d_in[3];
    const float* ne_W  = (const float*)d_in[4];
    const float* ne_b  = (const float*)d_in[5];
    const float* ee_W  = (const float*)d_in[6];
    const float* ee_b  = (const float*)d_in[7];
    const float* msgW1 = (const float*)d_in[8];
    const float* msgb1 = (const float*)d_in[9];
    const float* msgW2 = (const float*)d_in[10];
    const float* msgb2 = (const float*)d_in[11];
    const float* updW  = (const float*)d_in[12];
    const float* updb  = (const float*)d_in[13];
    const float* lng   = (const float*)d_in[14];
    const float* lnb   = (const float*)d_in[15];
    const float* roW1  = (const float*)d_in[16];
    const float* rob1  = (const float*)d_in[17];
    const float* roW2  = (const float*)d_in[18];
    const float* rob2  = (const float*)d_in[19];
    const float* roW3  = (const float*)d_in[20];
    const float* rob3  = (const float*)d_in[21];

    const int* src = edge_index;            // row 0
    const int* dst = edge_index + NE;       // row 1

    char* ws = (char*)d_ws;
    float*  h      = (float*)ws;  ws += (size_t)NN * H * 4;
    float*  hidsum = (float*)ws;  ws += (size_t)NN * H * 4;
    __half* hs     = (__half*)ws; ws += (size_t)NN * H * 2;
    __half* hd     = (__half*)ws; ws += (size_t)NN * H * 2;
    float*  efs    = (float*)ws;  ws += (size_t)NE * ED * 4;
    int* srcs     = (int*)ws; ws += (size_t)NE * 4;
    int* dsts     = (int*)ws; ws += (size_t)NE * 4;
    int* rowstart = (int*)ws; ws += (size_t)(NN + 4) * 4;
    int* deg      = (int*)ws; ws += (size_t)NN * 4;     // reused as cursor
    float* Wec = (float*)ws; ws += (size_t)NL * ED * H * 4;
    float* bec = (float*)ws; ws += (size_t)NL * H * 4;
    float* W2u = (float*)ws; ws += (size_t)NL * H * H * 4;
    float* b2u = (float*)ws; ws += (size_t)NL * H * 4;
    float* hg  = (float*)ws; ws += (size_t)NG * 2 * H * 4;

    // --- precompute: folded weights + CSR (+ sorted edge streams) ---
    fold_edge_weights<<<dim3(ED + 1, NL), H, 0, stream>>>(ee_W, ee_b, msgW1, msgb1, Wec, bec);
    fold_W2u<<<dim3(H + 1, NL), H, 0, stream>>>(msgW2, msgb2, updW, W2u, b2u);
    hipMemsetAsync(deg, 0, (size_t)NN * 4, stream);
    csr_count<<<(NE + 255) / 256, 256, 0, stream>>>(dst, deg);
    scan_deg<<<1, 1024, 0, stream>>>(deg, rowstart);
    hipMemsetAsync(deg, 0, (size_t)NN * 4, stream);
    csr_scatter<<<(NE + 255) / 256, 256, 0, stream>>>(src, dst, edge_feats, rowstart,
                                                      deg, srcs, dsts, efs);
    encode_pre<<<NN / NT, 128, 0, stream>>>(node_feats, ne_W, ne_b, msgW1, h, hs, hd, hidsum);

    // --- layers ---
    for (int l = 0; l < NL; ++l) {
        aggregate_edges<<<NE / EPB, 128, 0, stream>>>(srcs, dsts, efs, hs, hd,
                                                      Wec + (size_t)l * ED * H,
                                                      bec + (size_t)l * H, hidsum);
        update_pre<<<NN / NT, 128, 0, stream>>>(hidsum, rowstart,
                                                updW + (size_t)l * 2 * H * H,
                                                W2u + (size_t)l * H * H,
                                                b2u + (size_t)l * H,
                                                updb + (size_t)l * H,
                                                lng + (size_t)l * H, lnb + (size_t)l * H,
                                                msgW1 + (size_t)(l + 1) * 3 * H * H,
                                                h, hs, hd, hidsum,
                                                (l == NL - 1) ? 1 : 0);
    }

    pool<<<NG, 512, 0, stream>>>(h, batch, hg);
    readout<<<NG, H, 0, stream>>>(hg, roW1, rob1, roW2, rob2, roW3, rob3, (float*)d_out);
}

// Round 4
// 918.355 us; speedup vs baseline: 6.5958x; 1.5462x over previous
//
#include <hip/hip_runtime.h>
#include <hip/hip_fp16.h>
#include <math.h>

#define NN 100000
#define NE 500000
#define NG 128
#define ND 91
#define ED 20
#define H  128
#define NL 3
#define EPSF 1e-5f
#define NT 16           // nodes per block in scalar encode
#define EPB 32          // edges per block in aggregation
#define NB64 ((NN + 63) / 64)

typedef _Float16 f16;
typedef _Float16 f16x8 __attribute__((ext_vector_type(8)));
typedef float    f32x4 __attribute__((ext_vector_type(4)));

// ---------------------------------------------------------------------------
// Fold edge-feature path: Wec[l] = ee_W @ msg_W1[l][2H:3H,:]
//                         bec[l] = ee_b @ msg_W1[l][2H:3H,:] + msg_b1[l]
// ---------------------------------------------------------------------------
__global__ void fold_edge_weights(const float* __restrict__ eeW,
                                  const float* __restrict__ eeb,
                                  const float* __restrict__ msgW1,
                                  const float* __restrict__ msgb1,
                                  float* __restrict__ Wec,
                                  float* __restrict__ bec) {
    int l = blockIdx.y;
    int k = blockIdx.x;                        // 0..ED (ED => bias row)
    int c = threadIdx.x;
    const float* W1e = msgW1 + (size_t)l * 3 * H * H + (size_t)2 * H * H;
    if (k < ED) {
        float acc = 0.f;
        for (int m = 0; m < H; ++m) acc += eeW[k * H + m] * W1e[m * H + c];
        Wec[((size_t)l * ED + k) * H + c] = acc;
    } else {
        float acc = msgb1[l * H + c];
        for (int m = 0; m < H; ++m) acc += eeb[m] * W1e[m * H + c];
        bec[(size_t)l * H + c] = acc;
    }
}

// ---------------------------------------------------------------------------
// Fold msg_W2 into update weights: W2u[l] = msg_W2[l] @ updW[l][H:2H,:]
//                                  b2u[l] = msg_b2[l] @ updW[l][H:2H,:]
// ---------------------------------------------------------------------------
__global__ void fold_W2u(const float* __restrict__ msgW2,
                         const float* __restrict__ msgb2,
                         const float* __restrict__ updW,
                         float* __restrict__ W2u,
                         float* __restrict__ b2u) {
    int l = blockIdx.y;
    int k = blockIdx.x;                        // 0..H (H => bias row)
    int c = threadIdx.x;
    const float* Wbot = updW + (size_t)l * 2 * H * H + (size_t)H * H;
    if (k < H) {
        const float* w2row = msgW2 + (size_t)l * H * H + (size_t)k * H;
        float acc = 0.f;
        for (int m = 0; m < H; ++m) acc += w2row[m] * Wbot[m * H + c];
        W2u[((size_t)l * H + k) * H + c] = acc;
    } else {
        const float* b2 = msgb2 + (size_t)l * H;
        float acc = 0.f;
        for (int m = 0; m < H; ++m) acc += b2[m] * Wbot[m * H + c];
        b2u[(size_t)l * H + c] = acc;
    }
}

// ---------------------------------------------------------------------------
// Wt1[l][col][k] (f16, [H][2H]): k<128 -> updW_top[k][col], else W2u[k-128][col]
// grid (NL, H) x 256 ; thread = k
// ---------------------------------------------------------------------------
__global__ void make_Wt1(const float* __restrict__ updW,
                         const float* __restrict__ W2u,
                         f16* __restrict__ Wt1) {
    int l = blockIdx.x, c = blockIdx.y, k = threadIdx.x;   // k 0..255
    float v;
    if (k < H) v = updW[(size_t)l * 2 * H * H + (size_t)k * H + c];
    else       v = W2u[(size_t)l * H * H + (size_t)(k - H) * H + c];
    Wt1[((size_t)l * H + c) * 2 * H + k] = (f16)v;
}

// ---------------------------------------------------------------------------
// Wt2[l][oc][k] (f16, [2H][H]): msg_W1[l][(oc<128?0:H)+k][oc&127]
// grid (NL, 2H) x 128 ; thread = k
// ---------------------------------------------------------------------------
__global__ void make_Wt2(const float* __restrict__ msgW1,
                         f16* __restrict__ Wt2) {
    int l = blockIdx.x, oc = blockIdx.y, k = threadIdx.x;  // k 0..127
    const float* W1 = msgW1 + (size_t)l * 3 * H * H;
    float v = W1[(size_t)((oc < H ? 0 : H) + k) * H + (oc & (H - 1))];
    Wt2[((size_t)l * 2 * H + oc) * H + k] = (f16)v;
}

// ---------------------------------------------------------------------------
// CSR build over dst (+ reorder src/dst/edge_feats into CSR order)
// ---------------------------------------------------------------------------
__global__ void csr_count(const int* __restrict__ dst, int* __restrict__ deg) {
    int e = blockIdx.x * blockDim.x + threadIdx.x;
    if (e < NE) atomicAdd(&deg[dst[e]], 1);
}

__global__ void scan_deg(const int* __restrict__ deg, int* __restrict__ rowstart) {
    __shared__ int wsum[16];
    __shared__ int carry_s;
    int t = threadIdx.x, lane = t & 63, w = t >> 6;
    if (t == 0) carry_s = 0;
    __syncthreads();
    for (int base = 0; base < NN; base += 1024) {
        int i = base + t;
        int v = (i < NN) ? deg[i] : 0;
        int inc = v;
        #pragma unroll
        for (int off = 1; off < 64; off <<= 1) {
            int u = __shfl_up(inc, off, 64);
            if (lane >= off) inc += u;
        }
        if (lane == 63) wsum[w] = inc;
        __syncthreads();
        if (t == 0) {
            int run = carry_s;
            #pragma unroll
            for (int q = 0; q < 16; ++q) { int tmp = wsum[q]; wsum[q] = run; run += tmp; }
            carry_s = run;
        }
        __syncthreads();
        if (i < NN) rowstart[i] = wsum[w] + inc - v;
        __syncthreads();
    }
    if (t == 0) rowstart[NN] = NE;
}

__global__ void csr_scatter(const int* __restrict__ src,
                            const int* __restrict__ dst,
                            const float* __restrict__ ef,
                            const int* __restrict__ rowstart,
                            int* __restrict__ cursor,
                            int* __restrict__ srcs,
                            int* __restrict__ dsts,
                            float* __restrict__ efs) {
    int e = blockIdx.x * blockDim.x + threadIdx.x;
    if (e < NE) {
        int d = dst[e];
        int pos = atomicAdd(&cursor[d], 1);
        int j = rowstart[d] + pos;
        srcs[j] = src[e];
        dsts[j] = d;
        const float* efp = ef + (size_t)e * ED;
        float* out = efs + (size_t)j * ED;
        #pragma unroll
        for (int k = 0; k < ED; ++k) out[k] = efp[k];
    }
}

// ---------------------------------------------------------------------------
// h = node_feats @ ne_W + ne_b (scalar GEMV, NT nodes / 128 threads)
// ---------------------------------------------------------------------------
__global__ void __launch_bounds__(128)
encode_nodes(const float* __restrict__ nf,
             const float* __restrict__ neW, const float* __restrict__ neb,
             float* __restrict__ h) {
    int c = threadIdx.x;
    int n0 = blockIdx.x * NT;
    __shared__ float rows[NT][92];
    for (int i = c; i < NT * ND; i += 128) rows[i / ND][i % ND] = nf[(size_t)n0 * ND + i];
    __syncthreads();
    float bb = neb[c];
    float acc[NT];
    #pragma unroll
    for (int nt = 0; nt < NT; ++nt) acc[nt] = bb;
    for (int k0 = 0; k0 + 4 <= ND; k0 += 4) {
        float w0 = neW[(k0 + 0) * H + c];
        float w1 = neW[(k0 + 1) * H + c];
        float w2 = neW[(k0 + 2) * H + c];
        float w3 = neW[(k0 + 3) * H + c];
        #pragma unroll
        for (int nt = 0; nt < NT; ++nt) {
            float4 r = *(const float4*)&rows[nt][k0];
            acc[nt] += r.x * w0 + r.y * w1 + r.z * w2 + r.w * w3;
        }
    }
    for (int k = ND & ~3; k < ND; ++k) {
        float w = neW[k * H + c];
        #pragma unroll
        for (int nt = 0; nt < NT; ++nt) acc[nt] += rows[nt][k] * w;
    }
    #pragma unroll
    for (int nt = 0; nt < NT; ++nt) h[(size_t)(n0 + nt) * H + c] = acc[nt];
}

// ---------------------------------------------------------------------------
// GEMM2 device fn: D[outcol 0..255][node 0..63] = Wt2l(256x128) x xlds(128x64)
// xlds holds h_new [64 rows][128 k] f16 with byte ^= ((row&7)<<4) swizzle.
// hs/hd get D packed 4 consecutive f16 cols per store.
// ---------------------------------------------------------------------------
__device__ __forceinline__ void gemm2_store(const f16* xlds,
                                            const f16* __restrict__ Wt2l,
                                            f16* __restrict__ hs,
                                            f16* __restrict__ hd,
                                            int n0, int wave, int lane) {
    int g = lane >> 4, r15 = lane & 15;
    f16x8 B2[4][4];
    #pragma unroll
    for (int nf = 0; nf < 4; ++nf) {
        int row = nf * 16 + r15;
        #pragma unroll
        for (int kc = 0; kc < 4; ++kc) {
            int byte = (row * 256 + kc * 64 + g * 16) ^ ((row & 7) << 4);
            B2[nf][kc] = *(const f16x8*)((const char*)xlds + byte);
        }
    }
    f16* outb = (wave < 2) ? hs : hd;
    int colw = (wave & 1) * 64;
    #pragma unroll
    for (int mf = 0; mf < 4; ++mf) {
        f16x8 A2[4];
        int oc = wave * 64 + mf * 16 + r15;
        #pragma unroll
        for (int kc = 0; kc < 4; ++kc)
            A2[kc] = *(const f16x8*)&Wt2l[(size_t)oc * H + kc * 32 + g * 8];
        #pragma unroll
        for (int nf = 0; nf < 4; ++nf) {
            f32x4 acc = {0.f, 0.f, 0.f, 0.f};
            #pragma unroll
            for (int kc = 0; kc < 4; ++kc)
                acc = __builtin_amdgcn_mfma_f32_16x16x32_f16(A2[kc], B2[nf][kc], acc, 0, 0, 0);
            int node = n0 + nf * 16 + r15;
            if (node < NN) {
                union { f16 q[4]; uint2 u; } pk;
                pk.q[0] = (f16)acc[0]; pk.q[1] = (f16)acc[1];
                pk.q[2] = (f16)acc[2]; pk.q[3] = (f16)acc[3];
                *(uint2*)&outb[(size_t)node * H + colw + mf * 16 + g * 4] = pk.u;
            }
        }
    }
}

// ---------------------------------------------------------------------------
// msg_pre: stage h tile -> swizzled f16 LDS, zero hidsum, run GEMM2 -> hs/hd
// ---------------------------------------------------------------------------
__global__ void __launch_bounds__(256)
msg_pre_mfma(const float* __restrict__ h,
             const f16* __restrict__ Wt2l,
             f16* __restrict__ hs, f16* __restrict__ hd,
             float* __restrict__ hidsum) {
    __shared__ f16 xlds[64 * 128];
    int t = threadIdx.x;
    int n0 = blockIdx.x * 64;
    for (int i = t; i < 64 * 64; i += 256) {       // f16 pairs
        int row = i >> 6, c2 = i & 63;
        float2 v = make_float2(0.f, 0.f);
        if (n0 + row < NN) {
            v = *(const float2*)&h[(size_t)(n0 + row) * H + c2 * 2];
            *(float2*)&hidsum[(size_t)(n0 + row) * H + c2 * 2] = make_float2(0.f, 0.f);
        }
        union { f16 q[2]; unsigned u; } pk;
        pk.q[0] = (f16)v.x; pk.q[1] = (f16)v.y;
        int byte = (row * 256 + c2 * 4) ^ ((row & 7) << 4);
        *(unsigned*)((char*)xlds + byte) = pk.u;
    }
    __syncthreads();
    gemm2_store(xlds, Wt2l, hs, hd, n0, t >> 6, t & 63);
}

// ---------------------------------------------------------------------------
// Edge-parallel segmented aggregation over CSR-sorted edges, EPB per block.
// ---------------------------------------------------------------------------
__global__ void __launch_bounds__(128)
aggregate_edges(const int* __restrict__ srcs,
                const int* __restrict__ dsts,
                const float* __restrict__ efs,
                const f16* __restrict__ hs,
                const f16* __restrict__ hd,
                const float* __restrict__ Wec_l,
                const float* __restrict__ bec_l,
                float* __restrict__ hidsum) {
    int c = threadIdx.x;
    size_t j0 = (size_t)blockIdx.x * EPB;
    __shared__ float efs_lds[EPB][ED];
    __shared__ int sd[2 * EPB];
    const float* efsrc = efs + j0 * ED;
    for (int i = c; i < EPB * ED; i += 128) ((float*)efs_lds)[i] = efsrc[i];
    if (c < EPB) { sd[c] = srcs[j0 + c]; sd[EPB + c] = dsts[j0 + c]; }
    __syncthreads();
    float wec[ED];
    #pragma unroll
    for (int k = 0; k < ED; ++k) wec[k] = Wec_l[k * H + c];
    float becc = bec_l[c];
    float hv[EPB];
    #pragma unroll
    for (int jj = 0; jj < EPB; ++jj) {
        hv[jj] = (float)hs[(size_t)sd[jj] * H + c]
               + (float)hd[(size_t)sd[EPB + jj] * H + c];
    }
    int dcur = sd[EPB];
    float acc = 0.f;
    int nflush = 0;
    #pragma unroll
    for (int jj = 0; jj < EPB; ++jj) {
        int d = sd[EPB + jj];
        if (d != dcur) {
            if (nflush == 0) atomicAdd(&hidsum[(size_t)dcur * H + c], acc);
            else             hidsum[(size_t)dcur * H + c] = acc;
            dcur = d; acc = 0.f; ++nflush;
        }
        float v = hv[jj] + becc;
        #pragma unroll
        for (int k = 0; k < ED; ++k) v = fmaf(efs_lds[jj][k], wec[k], v);
        acc += fmaxf(v, 0.f);
    }
    atomicAdd(&hidsum[(size_t)dcur * H + c], acc);
}

// ---------------------------------------------------------------------------
// MFMA fused update:
//  GEMM1: pre = [h|hidsum](K=256) @ Wt1^T ; x = h + relu(pre + ub + deg*b2u)
//  LN in registers -> h ; (if !last) stage f16 LDS, zero hidsum, GEMM2 -> hs/hd
//  64 nodes per 256-thread block (4 waves x 16 rows)
// ---------------------------------------------------------------------------
__global__ void __launch_bounds__(256)
update_pre_mfma(float* __restrict__ h,
                float* __restrict__ hidsum,
                const int* __restrict__ degv,
                const f16* __restrict__ Wt1l,    // [H][2H]
                const float* __restrict__ b2u_l,
                const float* __restrict__ updbl,
                const float* __restrict__ lng_l,
                const float* __restrict__ lnb_l,
                const f16* __restrict__ Wt2next, // [2H][H]
                f16* __restrict__ hs, f16* __restrict__ hd,
                int last) {
    __shared__ f16 xlds[64 * 128];
    int t = threadIdx.x;
    int wave = t >> 6, lane = t & 63;
    int g = lane >> 4, r15 = lane & 15;
    int n0 = blockIdx.x * 64;

    // ---- A fragments: kc 0..3 from h, 4..7 from hidsum ----
    int arow = n0 + wave * 16 + r15;
    bool av = arow < NN;
    f16x8 A1[8];
    #pragma unroll
    for (int kc = 0; kc < 8; ++kc) {
        f16x8 a;
        if (av) {
            const float* sp = (kc < 4 ? h : hidsum) + (size_t)arow * H + (kc & 3) * 32 + g * 8;
            float4 v0 = *(const float4*)sp;
            float4 v1 = *(const float4*)(sp + 4);
            a[0] = (f16)v0.x; a[1] = (f16)v0.y; a[2] = (f16)v0.z; a[3] = (f16)v0.w;
            a[4] = (f16)v1.x; a[5] = (f16)v1.y; a[6] = (f16)v1.z; a[7] = (f16)v1.w;
        } else {
            #pragma unroll
            for (int i = 0; i < 8; ++i) a[i] = (f16)0.f;
        }
        A1[kc] = a;
    }

    // ---- GEMM1: acc1[cf] covers cols cf*16+r15, rows g*4+reg ----
    f32x4 acc1[8];
    #pragma unroll
    for (int cf = 0; cf < 8; ++cf) acc1[cf] = (f32x4){0.f, 0.f, 0.f, 0.f};
    #pragma unroll
    for (int cf = 0; cf < 8; ++cf) {
        const f16* bp = Wt1l + (size_t)(cf * 16 + r15) * 256;
        #pragma unroll
        for (int kc = 0; kc < 8; ++kc) {
            f16x8 b = *(const f16x8*)(bp + kc * 32 + g * 8);
            acc1[cf] = __builtin_amdgcn_mfma_f32_16x16x32_f16(A1[kc], b, acc1[cf], 0, 0, 0);
        }
    }

    // ---- epilogue: bias + deg*b2u + relu + residual ----
    int nodes[4]; bool nv[4]; float degf[4];
    #pragma unroll
    for (int r = 0; r < 4; ++r) {
        nodes[r] = n0 + wave * 16 + g * 4 + r;
        nv[r] = nodes[r] < NN;
        degf[r] = nv[r] ? (float)degv[nodes[r]] : 0.f;
    }
    float ubc[8], b2c[8], gl[8], bl[8];
    #pragma unroll
    for (int cf = 0; cf < 8; ++cf) {
        int col = cf * 16 + r15;
        ubc[cf] = updbl[col]; b2c[cf] = b2u_l[col];
        gl[cf] = lng_l[col];  bl[cf] = lnb_l[col];
    }
    float x[8][4];
    #pragma unroll
    for (int cf = 0; cf < 8; ++cf) {
        int col = cf * 16 + r15;
        #pragma unroll
        for (int r = 0; r < 4; ++r) {
            float hres = nv[r] ? h[(size_t)nodes[r] * H + col] : 0.f;
            x[cf][r] = hres + fmaxf(acc1[cf][r] + ubc[cf] + degf[r] * b2c[cf], 0.f);
        }
    }

    // ---- layernorm per row (16-lane group reduce) + store ----
    #pragma unroll
    for (int r = 0; r < 4; ++r) {
        float s1 = 0.f, s2 = 0.f;
        #pragma unroll
        for (int cf = 0; cf < 8; ++cf) { s1 += x[cf][r]; s2 += x[cf][r] * x[cf][r]; }
        #pragma unroll
        for (int off = 1; off <= 8; off <<= 1) {
            s1 += __shfl_xor(s1, off);
            s2 += __shfl_xor(s2, off);
        }
        float mu  = s1 * (1.0f / H);
        float var = s2 * (1.0f / H) - mu * mu;
        float inv = rsqrtf(var + EPSF);
        int lrow = wave * 16 + g * 4 + r;
        #pragma unroll
        for (int cf = 0; cf < 8; ++cf) {
            int col = cf * 16 + r15;
            float hn = (x[cf][r] - mu) * inv * gl[cf] + bl[cf];
            if (nv[r]) {
                h[(size_t)nodes[r] * H + col] = hn;
                if (!last) hidsum[(size_t)nodes[r] * H + col] = 0.f;
            } else hn = 0.f;
            if (!last) {
                int byte = (lrow * 256 + col * 2) ^ ((lrow & 7) << 4);
                *(f16*)((char*)xlds + byte) = (f16)hn;
            }
        }
    }
    if (last) return;
    __syncthreads();
    gemm2_store(xlds, Wt2next, hs, hd, n0, wave, lane);
}

// ---------------------------------------------------------------------------
// per-graph mean (denom = count+1) and max pooling; batch sorted.
// ---------------------------------------------------------------------------
__global__ void __launch_bounds__(512)
pool(const float* __restrict__ h,
     const int* __restrict__ batch,
     float* __restrict__ hg) {
    int g = blockIdx.x;
    int t = threadIdx.x;
    int c = t & 127, q = t >> 7;
    int lo = 0, hi = NN;
    while (lo < hi) { int mid = (lo + hi) >> 1; if (batch[mid] < g) lo = mid + 1; else hi = mid; }
    int start = lo;
    hi = NN;
    while (lo < hi) { int mid = (lo + hi) >> 1; if (batch[mid] < g + 1) lo = mid + 1; else hi = mid; }
    int end = lo;
    float s = 0.f, mx = -INFINITY;
    for (int n = start + q; n < end; n += 4) {
        float v = h[(size_t)n * H + c];
        s += v;
        mx = fmaxf(mx, v);
    }
    __shared__ float shs[4][H];
    __shared__ float shm[4][H];
    shs[q][c] = s; shm[q][c] = mx;
    __syncthreads();
    if (q == 0) {
        float S = shs[0][c] + shs[1][c] + shs[2][c] + shs[3][c];
        float M = fmaxf(fmaxf(shm[0][c], shm[1][c]), fmaxf(shm[2][c], shm[3][c]));
        float denom = (float)(end - start) + 1.0f;
        hg[(size_t)g * 2 * H + c]     = S / denom;
        hg[(size_t)g * 2 * H + H + c] = M;
    }
}

// ---------------------------------------------------------------------------
// readout MLP
// ---------------------------------------------------------------------------
__global__ void __launch_bounds__(128)
readout(const float* __restrict__ hg,
        const float* __restrict__ W1, const float* __restrict__ b1,
        const float* __restrict__ W2, const float* __restrict__ b2,
        const float* __restrict__ W3, const float* __restrict__ b3,
        float* __restrict__ out) {
    int g = blockIdx.x, t = threadIdx.x;
    __shared__ float xin[2 * H];
    __shared__ float x1[H];
    __shared__ float x2[H / 2];
    xin[t]     = hg[(size_t)g * 2 * H + t];
    xin[H + t] = hg[(size_t)g * 2 * H + H + t];
    __syncthreads();
    float acc = b1[t];
    for (int k = 0; k < 2 * H; ++k) acc += xin[k] * W1[k * H + t];
    x1[t] = fmaxf(acc, 0.f);
    __syncthreads();
    if (t < 64) {
        float a2 = b2[t];
        for (int k = 0; k < H; ++k) a2 += x1[k] * W2[k * 64 + t];
        x2[t] = fmaxf(a2, 0.f);
    }
    __syncthreads();
    if (t < 64) {
        float v = x2[t] * W3[t];
        #pragma unroll
        for (int off = 32; off >= 1; off >>= 1) v += __shfl_xor(v, off, 64);
        if (t == 0) out[g] = v + b3[0];
    }
}

// ---------------------------------------------------------------------------
extern "C" void kernel_launch(void* const* d_in, const int* in_sizes, int n_in,
                              void* d_out, int out_size, void* d_ws, size_t ws_size,
                              hipStream_t stream) {
    const float* node_feats = (const float*)d_in[0];
    const int*   edge_index = (const int*)d_in[1];
    const float* edge_feats = (const float*)d_in[2];
    const int*   batch      = (const int*)d_in[3];
    const float* ne_W  = (const float*)d_in[4];
    const float* ne_b  = (const float*)d_in[5];
    const float* ee_W  = (const float*)d_in[6];
    const float* ee_b  = (const float*)d_in[7];
    const float* msgW1 = (const float*)d_in[8];
    const float* msgb1 = (const float*)d_in[9];
    const float* msgW2 = (const float*)d_in[10];
    const float* msgb2 = (const float*)d_in[11];
    const float* updW  = (const float*)d_in[12];
    const float* updb  = (const float*)d_in[13];
    const float* lng   = (const float*)d_in[14];
    const float* lnb   = (const float*)d_in[15];
    const float* roW1  = (const float*)d_in[16];
    const float* rob1  = (const float*)d_in[17];
    const float* roW2  = (const float*)d_in[18];
    const float* rob2  = (const float*)d_in[19];
    const float* roW3  = (const float*)d_in[20];
    const float* rob3  = (const float*)d_in[21];

    const int* src = edge_index;            // row 0
    const int* dst = edge_index + NE;       // row 1

    char* ws = (char*)d_ws;
    float* h      = (float*)ws; ws += (size_t)NN * H * 4;
    float* hidsum = (float*)ws; ws += (size_t)NN * H * 4;
    f16*   hs     = (f16*)ws;   ws += (size_t)NN * H * 2;
    f16*   hd     = (f16*)ws;   ws += (size_t)NN * H * 2;
    float* efs    = (float*)ws; ws += (size_t)NE * ED * 4;
    int* srcs     = (int*)ws; ws += (size_t)NE * 4;
    int* dsts     = (int*)ws; ws += (size_t)NE * 4;
    int* rowstart = (int*)ws; ws += (size_t)(NN + 4) * 4;
    int* deg      = (int*)ws; ws += (size_t)NN * 4;     // reused as cursor; ends = degree
    float* Wec = (float*)ws; ws += (size_t)NL * ED * H * 4;
    float* bec = (float*)ws; ws += (size_t)NL * H * 4;
    float* W2u = (float*)ws; ws += (size_t)NL * H * H * 4;
    float* b2u = (float*)ws; ws += (size_t)NL * H * 4;
    f16* Wt1 = (f16*)ws; ws += (size_t)NL * H * 2 * H * 2;
    f16* Wt2 = (f16*)ws; ws += (size_t)NL * 2 * H * H * 2;
    float* hg  = (float*)ws; ws += (size_t)NG * 2 * H * 4;

    // --- precompute: folded weights + transposed f16 weights + CSR ---
    fold_edge_weights<<<dim3(ED + 1, NL), H, 0, stream>>>(ee_W, ee_b, msgW1, msgb1, Wec, bec);
    fold_W2u<<<dim3(H + 1, NL), H, 0, stream>>>(msgW2, msgb2, updW, W2u, b2u);
    make_Wt1<<<dim3(NL, H), 256, 0, stream>>>(updW, W2u, Wt1);
    make_Wt2<<<dim3(NL, 2 * H), 128, 0, stream>>>(msgW1, Wt2);

    hipMemsetAsync(deg, 0, (size_t)NN * 4, stream);
    csr_count<<<(NE + 255) / 256, 256, 0, stream>>>(dst, deg);
    scan_deg<<<1, 1024, 0, stream>>>(deg, rowstart);
    hipMemsetAsync(deg, 0, (size_t)NN * 4, stream);
    csr_scatter<<<(NE + 255) / 256, 256, 0, stream>>>(src, dst, edge_feats, rowstart,
                                                      deg, srcs, dsts, efs);

    encode_nodes<<<NN / NT, 128, 0, stream>>>(node_feats, ne_W, ne_b, h);
    msg_pre_mfma<<<NB64, 256, 0, stream>>>(h, Wt2, hs, hd, hidsum);

    // --- layers ---
    for (int l = 0; l < NL; ++l) {
        aggregate_edges<<<NE / EPB, 128, 0, stream>>>(srcs, dsts, efs, hs, hd,
                                                      Wec + (size_t)l * ED * H,
                                                      bec + (size_t)l * H, hidsum);
        int nl = (l + 1 < NL) ? (l + 1) : 0;   // safe index; unused when last
        update_pre_mfma<<<NB64, 256, 0, stream>>>(h, hidsum, deg,
                                                  Wt1 + (size_t)l * H * 2 * H,
                                                  b2u + (size_t)l * H,
                                                  updb + (size_t)l * H,
                                                  lng + (size_t)l * H, lnb + (size_t)l * H,
                                                  Wt2 + (size_t)nl * 2 * H * H,
                                                  hs, hd, (l == NL - 1) ? 1 : 0);
    }

    pool<<<NG, 512, 0, stream>>>(h, batch, hg);
    readout<<<NG, H, 0, stream>>>(hg, roW1, rob1, roW2, rob2, roW3, rob3, (float*)d_out);
}

// Round 6
// 791.615 us; speedup vs baseline: 7.6518x; 1.1601x over previous
//
#include <hip/hip_runtime.h>
#include <hip/hip_fp16.h>
#include <math.h>

#define NN 100000
#define NE 500000
#define NG 128
#define ND 91
#define ED 20
#define H  128
#define NL 3
#define EPSF 1e-5f
#define NT 16           // nodes per block in scalar encode
#define EPB 32          // edges per block in aggregation
#define NB64 ((NN + 63) / 64)
#define NSC ((NN + 1023) / 1024)

typedef _Float16 f16;
typedef _Float16 f16x8 __attribute__((ext_vector_type(8)));
typedef float    f32x4 __attribute__((ext_vector_type(4)));

// ---------------------------------------------------------------------------
// Fold edge-feature path: Wec[l] = ee_W @ msg_W1[l][2H:3H,:]
//                         bec[l] = ee_b @ msg_W1[l][2H:3H,:] + msg_b1[l]
// ---------------------------------------------------------------------------
__global__ void fold_edge_weights(const float* __restrict__ eeW,
                                  const float* __restrict__ eeb,
                                  const float* __restrict__ msgW1,
                                  const float* __restrict__ msgb1,
                                  float* __restrict__ Wec,
                                  float* __restrict__ bec) {
    int l = blockIdx.y;
    int k = blockIdx.x;                        // 0..ED (ED => bias row)
    int c = threadIdx.x;
    const float* W1e = msgW1 + (size_t)l * 3 * H * H + (size_t)2 * H * H;
    if (k < ED) {
        float acc = 0.f;
        for (int m = 0; m < H; ++m) acc += eeW[k * H + m] * W1e[m * H + c];
        Wec[((size_t)l * ED + k) * H + c] = acc;
    } else {
        float acc = msgb1[l * H + c];
        for (int m = 0; m < H; ++m) acc += eeb[m] * W1e[m * H + c];
        bec[(size_t)l * H + c] = acc;
    }
}

// ---------------------------------------------------------------------------
// Fold msg_W2 into update weights: W2u[l] = msg_W2[l] @ updW[l][H:2H,:]
//                                  b2u[l] = msg_b2[l] @ updW[l][H:2H,:]
// ---------------------------------------------------------------------------
__global__ void fold_W2u(const float* __restrict__ msgW2,
                         const float* __restrict__ msgb2,
                         const float* __restrict__ updW,
                         float* __restrict__ W2u,
                         float* __restrict__ b2u) {
    int l = blockIdx.y;
    int k = blockIdx.x;                        // 0..H (H => bias row)
    int c = threadIdx.x;
    const float* Wbot = updW + (size_t)l * 2 * H * H + (size_t)H * H;
    if (k < H) {
        const float* w2row = msgW2 + (size_t)l * H * H + (size_t)k * H;
        float acc = 0.f;
        for (int m = 0; m < H; ++m) acc += w2row[m] * Wbot[m * H + c];
        W2u[((size_t)l * H + k) * H + c] = acc;
    } else {
        const float* b2 = msgb2 + (size_t)l * H;
        float acc = 0.f;
        for (int m = 0; m < H; ++m) acc += b2[m] * Wbot[m * H + c];
        b2u[(size_t)l * H + c] = acc;
    }
}

// ---------------------------------------------------------------------------
// Wt1[l][col][k] (f16, [H][2H]): k<128 -> updW_top[k][col], else W2u[k-128][col]
// ---------------------------------------------------------------------------
__global__ void make_Wt1(const float* __restrict__ updW,
                         const float* __restrict__ W2u,
                         f16* __restrict__ Wt1) {
    int l = blockIdx.x, c = blockIdx.y, k = threadIdx.x;   // k 0..255
    float v;
    if (k < H) v = updW[(size_t)l * 2 * H * H + (size_t)k * H + c];
    else       v = W2u[(size_t)l * H * H + (size_t)(k - H) * H + c];
    Wt1[((size_t)l * H + c) * 2 * H + k] = (f16)v;
}

// ---------------------------------------------------------------------------
// Wt2[l][oc][k] (f16, [2H][H]): msg_W1[l][(oc<128?0:H)+k][oc&127]
// ---------------------------------------------------------------------------
__global__ void make_Wt2(const float* __restrict__ msgW1,
                         f16* __restrict__ Wt2) {
    int l = blockIdx.x, oc = blockIdx.y, k = threadIdx.x;  // k 0..127
    const float* W1 = msgW1 + (size_t)l * 3 * H * H;
    float v = W1[(size_t)((oc < H ? 0 : H) + k) * H + (oc & (H - 1))];
    Wt2[((size_t)l * 2 * H + oc) * H + k] = (f16)v;
}

// ---------------------------------------------------------------------------
// CSR build over dst
// ---------------------------------------------------------------------------
__global__ void csr_count(const int* __restrict__ dst, int* __restrict__ deg) {
    int e = blockIdx.x * blockDim.x + threadIdx.x;
    if (e < NE) atomicAdd(&deg[dst[e]], 1);
}

// 3-phase exclusive scan: p1 per-1024-block scan, p2 block-sum scan, p3 add
__global__ void scan_p1(const int* __restrict__ deg,
                        int* __restrict__ part, int* __restrict__ bsum) {
    __shared__ int ws[16];
    int t = threadIdx.x, lane = t & 63, w = t >> 6;
    int i = blockIdx.x * 1024 + t;
    int v = (i < NN) ? deg[i] : 0;
    int inc = v;
    #pragma unroll
    for (int off = 1; off < 64; off <<= 1) {
        int u = __shfl_up(inc, off, 64);
        if (lane >= off) inc += u;
    }
    if (lane == 63) ws[w] = inc;
    __syncthreads();
    if (t == 0) {
        int run = 0;
        #pragma unroll
        for (int q = 0; q < 16; ++q) { int tmp = ws[q]; ws[q] = run; run += tmp; }
        bsum[blockIdx.x] = run;
    }
    __syncthreads();
    if (i < NN) part[i] = ws[w] + inc - v;
}

__global__ void scan_p2(int* __restrict__ bsum) {
    if (threadIdx.x == 0) {
        int run = 0;
        for (int q = 0; q < NSC; ++q) { int tmp = bsum[q]; bsum[q] = run; run += tmp; }
    }
}

__global__ void scan_p3(const int* __restrict__ part, const int* __restrict__ bsum,
                        int* __restrict__ rowstart) {
    int i = blockIdx.x * 1024 + threadIdx.x;
    if (i < NN) rowstart[i] = part[i] + bsum[blockIdx.x];
    if (i == 0) rowstart[NN] = NE;
}

// zflag[n]=1 iff node needs hidsum zero-init (deg0 or its CSR range is not a
// strictly-interior single-block segment -> receives atomicAdd in aggregate)
__global__ void mark_zero(const int* __restrict__ rowstart,
                          unsigned char* __restrict__ zflag) {
    int n = blockIdx.x * 256 + threadIdx.x;
    if (n >= NN) return;
    int b = rowstart[n], e = rowstart[n + 1];
    bool interior = (b < e) && (b % EPB != 0) && (e % EPB != 0)
                    && ((b / EPB) == ((e - 1) / EPB));
    zflag[n] = interior ? 0 : 1;
}

__global__ void csr_scatter(const int* __restrict__ src,
                            const int* __restrict__ dst,
                            const float* __restrict__ ef,
                            const int* __restrict__ rowstart,
                            int* __restrict__ cursor,
                            int* __restrict__ srcs,
                            int* __restrict__ dsts,
                            f16* __restrict__ efs) {
    int e = blockIdx.x * blockDim.x + threadIdx.x;
    if (e < NE) {
        int d = dst[e];
        int pos = atomicAdd(&cursor[d], 1);
        int j = rowstart[d] + pos;
        srcs[j] = src[e];
        dsts[j] = d;
        const float* efp = ef + (size_t)e * ED;
        f16* out = efs + (size_t)j * ED;
        #pragma unroll
        for (int k = 0; k < ED; ++k) out[k] = (f16)efp[k];
    }
}

// ---------------------------------------------------------------------------
// hf = f16(node_feats @ ne_W + ne_b)  (scalar GEMV, NT nodes / 128 threads)
// ---------------------------------------------------------------------------
__global__ void __launch_bounds__(128)
encode_nodes(const float* __restrict__ nf,
             const float* __restrict__ neW, const float* __restrict__ neb,
             f16* __restrict__ hf) {
    int c = threadIdx.x;
    int n0 = blockIdx.x * NT;
    __shared__ float rows[NT][92];
    for (int i = c; i < NT * ND; i += 128) rows[i / ND][i % ND] = nf[(size_t)n0 * ND + i];
    __syncthreads();
    float bb = neb[c];
    float acc[NT];
    #pragma unroll
    for (int nt = 0; nt < NT; ++nt) acc[nt] = bb;
    for (int k0 = 0; k0 + 4 <= ND; k0 += 4) {
        float w0 = neW[(k0 + 0) * H + c];
        float w1 = neW[(k0 + 1) * H + c];
        float w2 = neW[(k0 + 2) * H + c];
        float w3 = neW[(k0 + 3) * H + c];
        #pragma unroll
        for (int nt = 0; nt < NT; ++nt) {
            float4 r = *(const float4*)&rows[nt][k0];
            acc[nt] += r.x * w0 + r.y * w1 + r.z * w2 + r.w * w3;
        }
    }
    for (int k = ND & ~3; k < ND; ++k) {
        float w = neW[k * H + c];
        #pragma unroll
        for (int nt = 0; nt < NT; ++nt) acc[nt] += rows[nt][k] * w;
    }
    #pragma unroll
    for (int nt = 0; nt < NT; ++nt) hf[(size_t)(n0 + nt) * H + c] = (f16)acc[nt];
}

// ---------------------------------------------------------------------------
// GEMM2 device fn: D[outcol 0..255][node 0..63] = Wt2l(256x128) x xlds(128x64)
// xlds holds h_new [64 rows][128 k] f16 with byte ^= ((row&7)<<4) swizzle.
// ---------------------------------------------------------------------------
__device__ __forceinline__ void gemm2_store(const f16* xlds,
                                            const f16* __restrict__ Wt2l,
                                            f16* __restrict__ hs,
                                            f16* __restrict__ hd,
                                            int n0, int wave, int lane) {
    int g = lane >> 4, r15 = lane & 15;
    f16x8 B2[4][4];
    #pragma unroll
    for (int nf = 0; nf < 4; ++nf) {
        int row = nf * 16 + r15;
        #pragma unroll
        for (int kc = 0; kc < 4; ++kc) {
            int byte = (row * 256 + kc * 64 + g * 16) ^ ((row & 7) << 4);
            B2[nf][kc] = *(const f16x8*)((const char*)xlds + byte);
        }
    }
    f16* outb = (wave < 2) ? hs : hd;
    int colw = (wave & 1) * 64;
    #pragma unroll
    for (int mf = 0; mf < 4; ++mf) {
        f16x8 A2[4];
        int oc = wave * 64 + mf * 16 + r15;
        #pragma unroll
        for (int kc = 0; kc < 4; ++kc)
            A2[kc] = *(const f16x8*)&Wt2l[(size_t)oc * H + kc * 32 + g * 8];
        #pragma unroll
        for (int nf = 0; nf < 4; ++nf) {
            f32x4 acc = {0.f, 0.f, 0.f, 0.f};
            #pragma unroll
            for (int kc = 0; kc < 4; ++kc)
                acc = __builtin_amdgcn_mfma_f32_16x16x32_f16(A2[kc], B2[nf][kc], acc, 0, 0, 0);
            int node = n0 + nf * 16 + r15;
            if (node < NN) {
                union { f16 q[4]; uint2 u; } pk;
                pk.q[0] = (f16)acc[0]; pk.q[1] = (f16)acc[1];
                pk.q[2] = (f16)acc[2]; pk.q[3] = (f16)acc[3];
                *(uint2*)&outb[(size_t)node * H + colw + mf * 16 + g * 4] = pk.u;
            }
        }
    }
}

// ---------------------------------------------------------------------------
// msg_pre: stage hf tile -> swizzled f16 LDS, zero flagged hidsum, GEMM2
// ---------------------------------------------------------------------------
__global__ void __launch_bounds__(256)
msg_pre_mfma(const f16* __restrict__ hf,
             const f16* __restrict__ Wt2l,
             const unsigned char* __restrict__ zflag,
             f16* __restrict__ hs, f16* __restrict__ hd,
             float* __restrict__ hidsum) {
    __shared__ f16 xlds[64 * 128];
    int t = threadIdx.x;
    int n0 = blockIdx.x * 64;
    for (int i = t; i < 64 * 32; i += 256) {       // 4-f16 chunks
        int row = i >> 5, c4 = i & 31;
        uint2 v = make_uint2(0u, 0u);
        int n = n0 + row;
        if (n < NN) {
            v = *(const uint2*)&hf[(size_t)n * H + c4 * 4];
            if (zflag[n]) *(float4*)&hidsum[(size_t)n * H + c4 * 4] =
                make_float4(0.f, 0.f, 0.f, 0.f);
        }
        int byte = (row * 256 + c4 * 8) ^ ((row & 7) << 4);
        *(uint2*)((char*)xlds + byte) = v;
    }
    __syncthreads();
    gemm2_store(xlds, Wt2l, hs, hd, n0, t >> 6, t & 63);
}

// ---------------------------------------------------------------------------
// Edge-parallel segmented aggregation over CSR-sorted edges, EPB per block.
// ---------------------------------------------------------------------------
__global__ void __launch_bounds__(128)
aggregate_edges(const int* __restrict__ srcs,
                const int* __restrict__ dsts,
                const f16* __restrict__ efs,
                const f16* __restrict__ hs,
                const f16* __restrict__ hd,
                const float* __restrict__ Wec_l,
                const float* __restrict__ bec_l,
                float* __restrict__ hidsum) {
    int c = threadIdx.x;
    size_t j0 = (size_t)blockIdx.x * EPB;
    __shared__ float efs_lds[EPB][ED];
    __shared__ int sd[2 * EPB];
    const f16* efsrc = efs + j0 * ED;
    for (int i = c; i < EPB * ED; i += 128) ((float*)efs_lds)[i] = (float)efsrc[i];
    if (c < EPB) { sd[c] = srcs[j0 + c]; sd[EPB + c] = dsts[j0 + c]; }
    __syncthreads();
    float wec[ED];
    #pragma unroll
    for (int k = 0; k < ED; ++k) wec[k] = Wec_l[k * H + c];
    float becc = bec_l[c];
    float hv[EPB];
    #pragma unroll
    for (int jj = 0; jj < EPB; ++jj) {
        hv[jj] = (float)hs[(size_t)sd[jj] * H + c]
               + (float)hd[(size_t)sd[EPB + jj] * H + c];
    }
    int dcur = sd[EPB];
    float acc = 0.f;
    int nflush = 0;
    #pragma unroll
    for (int jj = 0; jj < EPB; ++jj) {
        int d = sd[EPB + jj];
        if (d != dcur) {
            if (nflush == 0) atomicAdd(&hidsum[(size_t)dcur * H + c], acc);
            else             hidsum[(size_t)dcur * H + c] = acc;
            dcur = d; acc = 0.f; ++nflush;
        }
        float v = hv[jj] + becc;
        #pragma unroll
        for (int k = 0; k < ED; ++k) v = fmaf(efs_lds[jj][k], wec[k], v);
        acc += fmaxf(v, 0.f);
    }
    atomicAdd(&hidsum[(size_t)dcur * H + c], acc);
}

// ---------------------------------------------------------------------------
// MFMA fused update (64 nodes / 256 threads):
//  GEMM1: pre = [hf|hidsum](K=256) @ Wt1^T ; x = hf + relu(pre + ub + deg*b2u)
//  LN -> hf ; (if !last) zero flagged hidsum, stage f16 LDS, GEMM2 -> hs/hd
// ---------------------------------------------------------------------------
__global__ void __launch_bounds__(256)
update_pre_mfma(f16* __restrict__ hf,
                float* __restrict__ hidsum,
                const int* __restrict__ degv,
                const unsigned char* __restrict__ zflag,
                const f16* __restrict__ Wt1l,    // [H][2H]
                const float* __restrict__ b2u_l,
                const float* __restrict__ updbl,
                const float* __restrict__ lng_l,
                const float* __restrict__ lnb_l,
                const f16* __restrict__ Wt2next, // [2H][H]
                f16* __restrict__ hs, f16* __restrict__ hd,
                int last) {
    __shared__ f16 xlds[64 * 128];
    int t = threadIdx.x;
    int wave = t >> 6, lane = t & 63;
    int g = lane >> 4, r15 = lane & 15;
    int n0 = blockIdx.x * 64;

    // ---- A fragments: kc 0..3 from hf (direct f16x8), 4..7 from hidsum ----
    int arow = n0 + wave * 16 + r15;
    bool av = arow < NN;
    f16x8 zero8;
    for (int i = 0; i < 8; ++i) zero8[i] = (f16)0.f;
    f16x8 A1[8];
    #pragma unroll
    for (int kc = 0; kc < 4; ++kc) {
        A1[kc] = av ? *(const f16x8*)&hf[(size_t)arow * H + kc * 32 + g * 8] : zero8;
    }
    #pragma unroll
    for (int kc = 4; kc < 8; ++kc) {
        f16x8 a = zero8;
        if (av) {
            const float* sp = hidsum + (size_t)arow * H + (kc & 3) * 32 + g * 8;
            float4 v0 = *(const float4*)sp;
            float4 v1 = *(const float4*)(sp + 4);
            a[0] = (f16)v0.x; a[1] = (f16)v0.y; a[2] = (f16)v0.z; a[3] = (f16)v0.w;
            a[4] = (f16)v1.x; a[5] = (f16)v1.y; a[6] = (f16)v1.z; a[7] = (f16)v1.w;
        }
        A1[kc] = a;
    }

    // ---- GEMM1 ----
    f32x4 acc1[8];
    #pragma unroll
    for (int cf = 0; cf < 8; ++cf) acc1[cf] = (f32x4){0.f, 0.f, 0.f, 0.f};
    #pragma unroll
    for (int cf = 0; cf < 8; ++cf) {
        const f16* bp = Wt1l + (size_t)(cf * 16 + r15) * 256;
        #pragma unroll
        for (int kc = 0; kc < 8; ++kc) {
            f16x8 b = *(const f16x8*)(bp + kc * 32 + g * 8);
            acc1[cf] = __builtin_amdgcn_mfma_f32_16x16x32_f16(A1[kc], b, acc1[cf], 0, 0, 0);
        }
    }

    // ---- epilogue ----
    int nodes[4]; bool nv[4]; float degf[4]; bool zf[4];
    #pragma unroll
    for (int r = 0; r < 4; ++r) {
        nodes[r] = n0 + wave * 16 + g * 4 + r;
        nv[r] = nodes[r] < NN;
        degf[r] = nv[r] ? (float)degv[nodes[r]] : 0.f;
        zf[r] = nv[r] ? (zflag[nodes[r]] != 0) : false;
    }
    float ubc[8], b2c[8], gl[8], bl[8];
    #pragma unroll
    for (int cf = 0; cf < 8; ++cf) {
        int col = cf * 16 + r15;
        ubc[cf] = updbl[col]; b2c[cf] = b2u_l[col];
        gl[cf] = lng_l[col];  bl[cf] = lnb_l[col];
    }
    float x[8][4];
    #pragma unroll
    for (int cf = 0; cf < 8; ++cf) {
        int col = cf * 16 + r15;
        #pragma unroll
        for (int r = 0; r < 4; ++r) {
            float hres = nv[r] ? (float)hf[(size_t)nodes[r] * H + col] : 0.f;
            x[cf][r] = hres + fmaxf(acc1[cf][r] + ubc[cf] + degf[r] * b2c[cf], 0.f);
        }
    }

    // ---- layernorm per row + store ----
    #pragma unroll
    for (int r = 0; r < 4; ++r) {
        float s1 = 0.f, s2 = 0.f;
        #pragma unroll
        for (int cf = 0; cf < 8; ++cf) { s1 += x[cf][r]; s2 += x[cf][r] * x[cf][r]; }
        #pragma unroll
        for (int off = 1; off <= 8; off <<= 1) {
            s1 += __shfl_xor(s1, off);
            s2 += __shfl_xor(s2, off);
        }
        float mu  = s1 * (1.0f / H);
        float var = s2 * (1.0f / H) - mu * mu;
        float inv = rsqrtf(var + EPSF);
        int lrow = wave * 16 + g * 4 + r;
        #pragma unroll
        for (int cf = 0; cf < 8; ++cf) {
            int col = cf * 16 + r15;
            float hn = (x[cf][r] - mu) * inv * gl[cf] + bl[cf];
            if (nv[r]) {
                hf[(size_t)nodes[r] * H + col] = (f16)hn;
                if (!last && zf[r]) hidsum[(size_t)nodes[r] * H + col] = 0.f;
            } else hn = 0.f;
            if (!last) {
                int byte = (lrow * 256 + col * 2) ^ ((lrow & 7) << 4);
                *(f16*)((char*)xlds + byte) = (f16)hn;
            }
        }
    }
    if (last) return;
    __syncthreads();
    gemm2_store(xlds, Wt2next, hs, hd, n0, wave, lane);
}

// ---------------------------------------------------------------------------
// per-graph mean (denom = count+1) and max pooling; batch sorted.
// ---------------------------------------------------------------------------
__global__ void __launch_bounds__(512)
pool(const f16* __restrict__ hf,
     const int* __restrict__ batch,
     float* __restrict__ hg) {
    int g = blockIdx.x;
    int t = threadIdx.x;
    int c = t & 127, q = t >> 7;
    int lo = 0, hi = NN;
    while (lo < hi) { int mid = (lo + hi) >> 1; if (batch[mid] < g) lo = mid + 1; else hi = mid; }
    int start = lo;
    hi = NN;
    while (lo < hi) { int mid = (lo + hi) >> 1; if (batch[mid] < g + 1) lo = mid + 1; else hi = mid; }
    int end = lo;
    float s = 0.f, mx = -INFINITY;
    for (int n = start + q; n < end; n += 4) {
        float v = (float)hf[(size_t)n * H + c];
        s += v;
        mx = fmaxf(mx, v);
    }
    __shared__ float shs[4][H];
    __shared__ float shm[4][H];
    shs[q][c] = s; shm[q][c] = mx;
    __syncthreads();
    if (q == 0) {
        float S = shs[0][c] + shs[1][c] + shs[2][c] + shs[3][c];
        float M = fmaxf(fmaxf(shm[0][c], shm[1][c]), fmaxf(shm[2][c], shm[3][c]));
        float denom = (float)(end - start) + 1.0f;
        hg[(size_t)g * 2 * H + c]     = S / denom;
        hg[(size_t)g * 2 * H + H + c] = M;
    }
}

// ---------------------------------------------------------------------------
// readout MLP
// ---------------------------------------------------------------------------
__global__ void __launch_bounds__(128)
readout(const float* __restrict__ hg,
        const float* __restrict__ W1, const float* __restrict__ b1,
        const float* __restrict__ W2, const float* __restrict__ b2,
        const float* __restrict__ W3, const float* __restrict__ b3,
        float* __restrict__ out) {
    int g = blockIdx.x, t = threadIdx.x;
    __shared__ float xin[2 * H];
    __shared__ float x1[H];
    __shared__ float x2[H / 2];
    xin[t]     = hg[(size_t)g * 2 * H + t];
    xin[H + t] = hg[(size_t)g * 2 * H + H + t];
    __syncthreads();
    float acc = b1[t];
    for (int k = 0; k < 2 * H; ++k) acc += xin[k] * W1[k * H + t];
    x1[t] = fmaxf(acc, 0.f);
    __syncthreads();
    if (t < 64) {
        float a2 = b2[t];
        for (int k = 0; k < H; ++k) a2 += x1[k] * W2[k * 64 + t];
        x2[t] = fmaxf(a2, 0.f);
    }
    __syncthreads();
    if (t < 64) {
        float v = x2[t] * W3[t];
        #pragma unroll
        for (int off = 32; off >= 1; off >>= 1) v += __shfl_xor(v, off, 64);
        if (t == 0) out[g] = v + b3[0];
    }
}

// ---------------------------------------------------------------------------
extern "C" void kernel_launch(void* const* d_in, const int* in_sizes, int n_in,
                              void* d_out, int out_size, void* d_ws, size_t ws_size,
                              hipStream_t stream) {
    const float* node_feats = (const float*)d_in[0];
    const int*   edge_index = (const int*)d_in[1];
    const float* edge_feats = (const float*)d_in[2];
    const int*   batch      = (const int*)d_in[3];
    const float* ne_W  = (const float*)d_in[4];
    const float* ne_b  = (const float*)d_in[5];
    const float* ee_W  = (const float*)d_in[6];
    const float* ee_b  = (const float*)d_in[7];
    const float* msgW1 = (const float*)d_in[8];
    const float* msgb1 = (const float*)d_in[9];
    const float* msgW2 = (const float*)d_in[10];
    const float* msgb2 = (const float*)d_in[11];
    const float* updW  = (const float*)d_in[12];
    const float* updb  = (const float*)d_in[13];
    const float* lng   = (const float*)d_in[14];
    const float* lnb   = (const float*)d_in[15];
    const float* roW1  = (const float*)d_in[16];
    const float* rob1  = (const float*)d_in[17];
    const float* roW2  = (const float*)d_in[18];
    const float* rob2  = (const float*)d_in[19];
    const float* roW3  = (const float*)d_in[20];
    const float* rob3  = (const float*)d_in[21];

    const int* src = edge_index;            // row 0
    const int* dst = edge_index + NE;       // row 1

    char* ws = (char*)d_ws;
    f16*   hf     = (f16*)ws;   ws += (size_t)NN * H * 2;
    float* hidsum = (float*)ws; ws += (size_t)NN * H * 4;
    f16*   hs     = (f16*)ws;   ws += (size_t)NN * H * 2;
    f16*   hd     = (f16*)ws;   ws += (size_t)NN * H * 2;
    f16*   efs    = (f16*)ws;   ws += (size_t)NE * ED * 2;
    int* srcs     = (int*)ws; ws += (size_t)NE * 4;
    int* dsts     = (int*)ws; ws += (size_t)NE * 4;
    int* rowstart = (int*)ws; ws += (size_t)(NN + 4) * 4;
    int* deg      = (int*)ws; ws += (size_t)NN * 4;     // reused as cursor; ends = degree
    int* part     = (int*)ws; ws += (size_t)NN * 4;
    int* bsum     = (int*)ws; ws += (size_t)256 * 4;
    unsigned char* zflag = (unsigned char*)ws; ws += ((size_t)NN + 15) / 16 * 16;
    float* Wec = (float*)ws; ws += (size_t)NL * ED * H * 4;
    float* bec = (float*)ws; ws += (size_t)NL * H * 4;
    float* W2u = (float*)ws; ws += (size_t)NL * H * H * 4;
    float* b2u = (float*)ws; ws += (size_t)NL * H * 4;
    f16* Wt1 = (f16*)ws; ws += (size_t)NL * H * 2 * H * 2;
    f16* Wt2 = (f16*)ws; ws += (size_t)NL * 2 * H * H * 2;
    float* hg  = (float*)ws; ws += (size_t)NG * 2 * H * 4;

    // --- precompute: folded weights + transposed f16 weights + CSR ---
    fold_edge_weights<<<dim3(ED + 1, NL), H, 0, stream>>>(ee_W, ee_b, msgW1, msgb1, Wec, bec);
    fold_W2u<<<dim3(H + 1, NL), H, 0, stream>>>(msgW2, msgb2, updW, W2u, b2u);
    make_Wt1<<<dim3(NL, H), 256, 0, stream>>>(updW, W2u, Wt1);
    make_Wt2<<<dim3(NL, 2 * H), 128, 0, stream>>>(msgW1, Wt2);

    hipMemsetAsync(deg, 0, (size_t)NN * 4, stream);
    csr_count<<<(NE + 255) / 256, 256, 0, stream>>>(dst, deg);
    scan_p1<<<NSC, 1024, 0, stream>>>(deg, part, bsum);
    scan_p2<<<1, 64, 0, stream>>>(bsum);
    scan_p3<<<NSC, 1024, 0, stream>>>(part, bsum, rowstart);
    mark_zero<<<(NN + 255) / 256, 256, 0, stream>>>(rowstart, zflag);
    hipMemsetAsync(deg, 0, (size_t)NN * 4, stream);
    csr_scatter<<<(NE + 255) / 256, 256, 0, stream>>>(src, dst, edge_feats, rowstart,
                                                      deg, srcs, dsts, efs);

    encode_nodes<<<NN / NT, 128, 0, stream>>>(node_feats, ne_W, ne_b, hf);
    msg_pre_mfma<<<NB64, 256, 0, stream>>>(hf, Wt2, zflag, hs, hd, hidsum);

    // --- layers ---
    for (int l = 0; l < NL; ++l) {
        aggregate_edges<<<NE / EPB, 128, 0, stream>>>(srcs, dsts, efs, hs, hd,
                                                      Wec + (size_t)l * ED * H,
                                                      bec + (size_t)l * H, hidsum);
        int nl = (l + 1 < NL) ? (l + 1) : 0;   // safe index; unused when last
        update_pre_mfma<<<NB64, 256, 0, stream>>>(hf, hidsum, deg, zflag,
                                                  Wt1 + (size_t)l * H * 2 * H,
                                                  b2u + (size_t)l * H,
                                                  updb + (size_t)l * H,
                                                  lng + (size_t)l * H, lnb + (size_t)l * H,
                                                  Wt2 + (size_t)nl * 2 * H * H,
                                                  hs, hd, (l == NL - 1) ? 1 : 0);
    }

    pool<<<NG, 512, 0, stream>>>(hf, batch, hg);
    readout<<<NG, H, 0, stream>>>(hg, roW1, rob1, roW2, rob2, roW3, rob3, (float*)d_out);
}

// Round 7
// 743.348 us; speedup vs baseline: 8.1487x; 1.0649x over previous
//
#include <hip/hip_runtime.h>
#include <hip/hip_fp16.h>
#include <math.h>

#define NN 100000
#define NE 500000
#define NG 128
#define ND 91
#define ED 20
#define H  128
#define NL 3
#define EPSF 1e-5f
#define NT 16           // nodes per block in scalar encode
#define EPB 32          // edges per block in aggregation
#define NB64 ((NN + 63) / 64)
#define NSC ((NN + 1023) / 1024)

typedef _Float16 f16;
typedef _Float16 f16x8 __attribute__((ext_vector_type(8)));
typedef float    f32x4 __attribute__((ext_vector_type(4)));

// swizzled LDS byte offset for a [64][128] f16 tile (row stride 256 B)
__device__ __forceinline__ int swz(int row, int colbyte) {
    return (row * 256 + colbyte) ^ ((row & 7) << 4);
}

// ---------------------------------------------------------------------------
// Fold edge-feature path: Wec[l] = ee_W @ msg_W1[l][2H:3H,:]
//                         bec[l] = ee_b @ msg_W1[l][2H:3H,:] + msg_b1[l]
// ---------------------------------------------------------------------------
__global__ void fold_edge_weights(const float* __restrict__ eeW,
                                  const float* __restrict__ eeb,
                                  const float* __restrict__ msgW1,
                                  const float* __restrict__ msgb1,
                                  float* __restrict__ Wec,
                                  float* __restrict__ bec) {
    int l = blockIdx.y;
    int k = blockIdx.x;                        // 0..ED (ED => bias row)
    int c = threadIdx.x;
    const float* W1e = msgW1 + (size_t)l * 3 * H * H + (size_t)2 * H * H;
    if (k < ED) {
        float acc = 0.f;
        for (int m = 0; m < H; ++m) acc += eeW[k * H + m] * W1e[m * H + c];
        Wec[((size_t)l * ED + k) * H + c] = acc;
    } else {
        float acc = msgb1[l * H + c];
        for (int m = 0; m < H; ++m) acc += eeb[m] * W1e[m * H + c];
        bec[(size_t)l * H + c] = acc;
    }
}

// ---------------------------------------------------------------------------
// Fold msg_W2 into update weights: W2u[l] = msg_W2[l] @ updW[l][H:2H,:]
//                                  b2u[l] = msg_b2[l] @ updW[l][H:2H,:]
// ---------------------------------------------------------------------------
__global__ void fold_W2u(const float* __restrict__ msgW2,
                         const float* __restrict__ msgb2,
                         const float* __restrict__ updW,
                         float* __restrict__ W2u,
                         float* __restrict__ b2u) {
    int l = blockIdx.y;
    int k = blockIdx.x;                        // 0..H (H => bias row)
    int c = threadIdx.x;
    const float* Wbot = updW + (size_t)l * 2 * H * H + (size_t)H * H;
    if (k < H) {
        const float* w2row = msgW2 + (size_t)l * H * H + (size_t)k * H;
        float acc = 0.f;
        for (int m = 0; m < H; ++m) acc += w2row[m] * Wbot[m * H + c];
        W2u[((size_t)l * H + k) * H + c] = acc;
    } else {
        const float* b2 = msgb2 + (size_t)l * H;
        float acc = 0.f;
        for (int m = 0; m < H; ++m) acc += b2[m] * Wbot[m * H + c];
        b2u[(size_t)l * H + c] = acc;
    }
}

// ---------------------------------------------------------------------------
// Wt1[l][col][k] (f16, [H][2H]): k<128 -> updW_top[k][col], else W2u[k-128][col]
// ---------------------------------------------------------------------------
__global__ void make_Wt1(const float* __restrict__ updW,
                         const float* __restrict__ W2u,
                         f16* __restrict__ Wt1) {
    int l = blockIdx.x, c = blockIdx.y, k = threadIdx.x;   // k 0..255
    float v;
    if (k < H) v = updW[(size_t)l * 2 * H * H + (size_t)k * H + c];
    else       v = W2u[(size_t)l * H * H + (size_t)(k - H) * H + c];
    Wt1[((size_t)l * H + c) * 2 * H + k] = (f16)v;
}

// ---------------------------------------------------------------------------
// Wt2[l][oc][k] (f16, [2H][H]): msg_W1[l][(oc<128?0:H)+k][oc&127]
// ---------------------------------------------------------------------------
__global__ void make_Wt2(const float* __restrict__ msgW1,
                         f16* __restrict__ Wt2) {
    int l = blockIdx.x, oc = blockIdx.y, k = threadIdx.x;  // k 0..127
    const float* W1 = msgW1 + (size_t)l * 3 * H * H;
    float v = W1[(size_t)((oc < H ? 0 : H) + k) * H + (oc & (H - 1))];
    Wt2[((size_t)l * 2 * H + oc) * H + k] = (f16)v;
}

// ---------------------------------------------------------------------------
// CSR build over dst
// ---------------------------------------------------------------------------
__global__ void csr_count(const int* __restrict__ dst, int* __restrict__ deg) {
    int e = blockIdx.x * blockDim.x + threadIdx.x;
    if (e < NE) atomicAdd(&deg[dst[e]], 1);
}

// 3-phase exclusive scan: p1 per-1024-block scan, p2 block-sum scan, p3 add
__global__ void scan_p1(const int* __restrict__ deg,
                        int* __restrict__ part, int* __restrict__ bsum) {
    __shared__ int ws[16];
    int t = threadIdx.x, lane = t & 63, w = t >> 6;
    int i = blockIdx.x * 1024 + t;
    int v = (i < NN) ? deg[i] : 0;
    int inc = v;
    #pragma unroll
    for (int off = 1; off < 64; off <<= 1) {
        int u = __shfl_up(inc, off, 64);
        if (lane >= off) inc += u;
    }
    if (lane == 63) ws[w] = inc;
    __syncthreads();
    if (t == 0) {
        int run = 0;
        #pragma unroll
        for (int q = 0; q < 16; ++q) { int tmp = ws[q]; ws[q] = run; run += tmp; }
        bsum[blockIdx.x] = run;
    }
    __syncthreads();
    if (i < NN) part[i] = ws[w] + inc - v;
}

__global__ void scan_p2(int* __restrict__ bsum) {
    if (threadIdx.x == 0) {
        int run = 0;
        for (int q = 0; q < NSC; ++q) { int tmp = bsum[q]; bsum[q] = run; run += tmp; }
    }
}

__global__ void scan_p3(const int* __restrict__ part, const int* __restrict__ bsum,
                        int* __restrict__ rowstart) {
    int i = blockIdx.x * 1024 + threadIdx.x;
    if (i < NN) rowstart[i] = part[i] + bsum[blockIdx.x];
    if (i == 0) rowstart[NN] = NE;
}

// zflag[n]=1 iff node needs hidsum zero-init (deg0 or its CSR range is not a
// strictly-interior single-block segment -> receives atomicAdd in aggregate)
__global__ void mark_zero(const int* __restrict__ rowstart,
                          unsigned char* __restrict__ zflag) {
    int n = blockIdx.x * 256 + threadIdx.x;
    if (n >= NN) return;
    int b = rowstart[n], e = rowstart[n + 1];
    bool interior = (b < e) && (b % EPB != 0) && (e % EPB != 0)
                    && ((b / EPB) == ((e - 1) / EPB));
    zflag[n] = interior ? 0 : 1;
}

__global__ void csr_scatter(const int* __restrict__ src,
                            const int* __restrict__ dst,
                            const float* __restrict__ ef,
                            const int* __restrict__ rowstart,
                            int* __restrict__ cursor,
                            int* __restrict__ srcs,
                            int* __restrict__ dsts,
                            f16* __restrict__ efs) {
    int e = blockIdx.x * blockDim.x + threadIdx.x;
    if (e < NE) {
        int d = dst[e];
        int pos = atomicAdd(&cursor[d], 1);
        int j = rowstart[d] + pos;
        srcs[j] = src[e];
        dsts[j] = d;
        const float* efp = ef + (size_t)e * ED;
        f16* out = efs + (size_t)j * ED;
        #pragma unroll
        for (int k = 0; k < ED; ++k) out[k] = (f16)efp[k];
    }
}

// ---------------------------------------------------------------------------
// hf = f16(node_feats @ ne_W + ne_b)  (scalar GEMV, NT nodes / 128 threads)
// ---------------------------------------------------------------------------
__global__ void __launch_bounds__(128)
encode_nodes(const float* __restrict__ nf,
             const float* __restrict__ neW, const float* __restrict__ neb,
             f16* __restrict__ hf) {
    int c = threadIdx.x;
    int n0 = blockIdx.x * NT;
    __shared__ float rows[NT][92];
    for (int i = c; i < NT * ND; i += 128) rows[i / ND][i % ND] = nf[(size_t)n0 * ND + i];
    __syncthreads();
    float bb = neb[c];
    float acc[NT];
    #pragma unroll
    for (int nt = 0; nt < NT; ++nt) acc[nt] = bb;
    for (int k0 = 0; k0 + 4 <= ND; k0 += 4) {
        float w0 = neW[(k0 + 0) * H + c];
        float w1 = neW[(k0 + 1) * H + c];
        float w2 = neW[(k0 + 2) * H + c];
        float w3 = neW[(k0 + 3) * H + c];
        #pragma unroll
        for (int nt = 0; nt < NT; ++nt) {
            float4 r = *(const float4*)&rows[nt][k0];
            acc[nt] += r.x * w0 + r.y * w1 + r.z * w2 + r.w * w3;
        }
    }
    for (int k = ND & ~3; k < ND; ++k) {
        float w = neW[k * H + c];
        #pragma unroll
        for (int nt = 0; nt < NT; ++nt) acc[nt] += rows[nt][k] * w;
    }
    #pragma unroll
    for (int nt = 0; nt < NT; ++nt) hf[(size_t)(n0 + nt) * H + c] = (f16)acc[nt];
}

// ---------------------------------------------------------------------------
// GEMM2 device fn: D[outcol 0..255][node 0..63] = Wt2l(256x128) x xlds(128x64)
// xlds holds h_new [64 rows][128 k] f16 with swz() swizzle.
// ---------------------------------------------------------------------------
__device__ __forceinline__ void gemm2_store(const f16* xlds,
                                            const f16* __restrict__ Wt2l,
                                            f16* __restrict__ hs,
                                            f16* __restrict__ hd,
                                            int n0, int wave, int lane) {
    int g = lane >> 4, r15 = lane & 15;
    f16x8 B2[4][4];
    #pragma unroll
    for (int nf = 0; nf < 4; ++nf) {
        int row = nf * 16 + r15;
        #pragma unroll
        for (int kc = 0; kc < 4; ++kc)
            B2[nf][kc] = *(const f16x8*)((const char*)xlds + swz(row, kc * 64 + g * 16));
    }
    f16* outb = (wave < 2) ? hs : hd;
    int colw = (wave & 1) * 64;
    #pragma unroll
    for (int mf = 0; mf < 4; ++mf) {
        f16x8 A2[4];
        int oc = wave * 64 + mf * 16 + r15;
        #pragma unroll
        for (int kc = 0; kc < 4; ++kc)
            A2[kc] = *(const f16x8*)&Wt2l[(size_t)oc * H + kc * 32 + g * 8];
        #pragma unroll
        for (int nf = 0; nf < 4; ++nf) {
            f32x4 acc = {0.f, 0.f, 0.f, 0.f};
            #pragma unroll
            for (int kc = 0; kc < 4; ++kc)
                acc = __builtin_amdgcn_mfma_f32_16x16x32_f16(A2[kc], B2[nf][kc], acc, 0, 0, 0);
            int node = n0 + nf * 16 + r15;
            if (node < NN) {
                union { f16 q[4]; uint2 u; } pk;
                pk.q[0] = (f16)acc[0]; pk.q[1] = (f16)acc[1];
                pk.q[2] = (f16)acc[2]; pk.q[3] = (f16)acc[3];
                *(uint2*)&outb[(size_t)node * H + colw + mf * 16 + g * 4] = pk.u;
            }
        }
    }
}

// ---------------------------------------------------------------------------
// msg_pre: stage hf tile -> swizzled f16 LDS, zero flagged hidsum, GEMM2
// ---------------------------------------------------------------------------
__global__ void __launch_bounds__(256)
msg_pre_mfma(const f16* __restrict__ hf,
             const f16* __restrict__ Wt2l,
             const unsigned char* __restrict__ zflag,
             f16* __restrict__ hs, f16* __restrict__ hd,
             float* __restrict__ hidsum) {
    __shared__ f16 xlds[64 * 128];
    int t = threadIdx.x;
    int n0 = blockIdx.x * 64;
    for (int i = t; i < 64 * 32; i += 256) {       // 4-f16 chunks
        int row = i >> 5, c4 = i & 31;
        uint2 v = make_uint2(0u, 0u);
        int n = n0 + row;
        if (n < NN) {
            v = *(const uint2*)&hf[(size_t)n * H + c4 * 4];
            if (zflag[n]) *(float4*)&hidsum[(size_t)n * H + c4 * 4] =
                make_float4(0.f, 0.f, 0.f, 0.f);
        }
        *(uint2*)((char*)xlds + swz(row, c4 * 8)) = v;
    }
    __syncthreads();
    gemm2_store(xlds, Wt2l, hs, hd, n0, t >> 6, t & 63);
}

// ---------------------------------------------------------------------------
// Edge-parallel segmented aggregation over CSR-sorted edges, EPB per block.
// ---------------------------------------------------------------------------
__global__ void __launch_bounds__(128)
aggregate_edges(const int* __restrict__ srcs,
                const int* __restrict__ dsts,
                const f16* __restrict__ efs,
                const f16* __restrict__ hs,
                const f16* __restrict__ hd,
                const float* __restrict__ Wec_l,
                const float* __restrict__ bec_l,
                float* __restrict__ hidsum) {
    int c = threadIdx.x;
    size_t j0 = (size_t)blockIdx.x * EPB;
    __shared__ float efs_lds[EPB][ED];
    __shared__ int sd[2 * EPB];
    const f16* efsrc = efs + j0 * ED;
    for (int i = c; i < EPB * ED; i += 128) ((float*)efs_lds)[i] = (float)efsrc[i];
    if (c < EPB) { sd[c] = srcs[j0 + c]; sd[EPB + c] = dsts[j0 + c]; }
    __syncthreads();
    float wec[ED];
    #pragma unroll
    for (int k = 0; k < ED; ++k) wec[k] = Wec_l[k * H + c];
    float becc = bec_l[c];
    float hv[EPB];
    #pragma unroll
    for (int jj = 0; jj < EPB; ++jj) {
        hv[jj] = (float)hs[(size_t)sd[jj] * H + c]
               + (float)hd[(size_t)sd[EPB + jj] * H + c];
    }
    int dcur = sd[EPB];
    float acc = 0.f;
    int nflush = 0;
    #pragma unroll
    for (int jj = 0; jj < EPB; ++jj) {
        int d = sd[EPB + jj];
        if (d != dcur) {
            if (nflush == 0) atomicAdd(&hidsum[(size_t)dcur * H + c], acc);
            else             hidsum[(size_t)dcur * H + c] = acc;
            dcur = d; acc = 0.f; ++nflush;
        }
        float v = hv[jj] + becc;
        #pragma unroll
        for (int k = 0; k < ED; ++k) v = fmaf(efs_lds[jj][k], wec[k], v);
        acc += fmaxf(v, 0.f);
    }
    atomicAdd(&hidsum[(size_t)dcur * H + c], acc);
}

// ---------------------------------------------------------------------------
// MFMA fused update (64 nodes / 256 threads), LDS-routed:
//  P1: stage hf tile -> xlds (coalesced); A kc4..7 from hidsum (coalesced)
//  P2: A kc0..3 + residual from xlds ; GEMM1 ; epilogue+LN -> hn
//  P3: hn -> xlds ; barrier ; coalesced hf store (+flagged hidsum zero) ; GEMM2
// ---------------------------------------------------------------------------
__global__ void __launch_bounds__(256)
update_pre_mfma(f16* __restrict__ hf,
                float* __restrict__ hidsum,
                const int* __restrict__ degv,
                const unsigned char* __restrict__ zflag,
                const f16* __restrict__ Wt1l,    // [H][2H]
                const float* __restrict__ b2u_l,
                const float* __restrict__ updbl,
                const float* __restrict__ lng_l,
                const float* __restrict__ lnb_l,
                const f16* __restrict__ Wt2next, // [2H][H]
                f16* __restrict__ hs, f16* __restrict__ hd,
                int last) {
    __shared__ f16 xlds[64 * 128];
    int t = threadIdx.x;
    int wave = t >> 6, lane = t & 63;
    int g = lane >> 4, r15 = lane & 15;
    int n0 = blockIdx.x * 64;

    // ---- P1: coalesced stage of hf tile into swizzled LDS ----
    for (int i = t; i < 64 * 32; i += 256) {
        int row = i >> 5, c4 = i & 31;
        int n = n0 + row;
        uint2 v = make_uint2(0u, 0u);
        if (n < NN) v = *(const uint2*)&hf[(size_t)n * H + c4 * 4];
        *(uint2*)((char*)xlds + swz(row, c4 * 8)) = v;
    }

    // ---- A fragments kc4..7 from hidsum (coalesced global float4) ----
    int arow = n0 + wave * 16 + r15;
    bool av = arow < NN;
    f16x8 zero8;
    for (int i = 0; i < 8; ++i) zero8[i] = (f16)0.f;
    f16x8 A1[8];
    #pragma unroll
    for (int kc = 4; kc < 8; ++kc) {
        f16x8 a = zero8;
        if (av) {
            const float* sp = hidsum + (size_t)arow * H + (kc & 3) * 32 + g * 8;
            float4 v0 = *(const float4*)sp;
            float4 v1 = *(const float4*)(sp + 4);
            a[0] = (f16)v0.x; a[1] = (f16)v0.y; a[2] = (f16)v0.z; a[3] = (f16)v0.w;
            a[4] = (f16)v1.x; a[5] = (f16)v1.y; a[6] = (f16)v1.z; a[7] = (f16)v1.w;
        }
        A1[kc] = a;
    }
    __syncthreads();

    // ---- A fragments kc0..3 from xlds (own stripe) ----
    int lrow_a = wave * 16 + r15;
    #pragma unroll
    for (int kc = 0; kc < 4; ++kc)
        A1[kc] = *(const f16x8*)((const char*)xlds + swz(lrow_a, kc * 64 + g * 16));

    // ---- GEMM1 ----
    f32x4 acc1[8];
    #pragma unroll
    for (int cf = 0; cf < 8; ++cf) acc1[cf] = (f32x4){0.f, 0.f, 0.f, 0.f};
    #pragma unroll
    for (int cf = 0; cf < 8; ++cf) {
        const f16* bp = Wt1l + (size_t)(cf * 16 + r15) * 256;
        #pragma unroll
        for (int kc = 0; kc < 8; ++kc) {
            f16x8 b = *(const f16x8*)(bp + kc * 32 + g * 8);
            acc1[cf] = __builtin_amdgcn_mfma_f32_16x16x32_f16(A1[kc], b, acc1[cf], 0, 0, 0);
        }
    }

    // ---- epilogue: residual from xlds, bias/deg from global ----
    int nodes[4]; bool nv[4]; float degf[4];
    #pragma unroll
    for (int r = 0; r < 4; ++r) {
        nodes[r] = n0 + wave * 16 + g * 4 + r;
        nv[r] = nodes[r] < NN;
        degf[r] = nv[r] ? (float)degv[nodes[r]] : 0.f;
    }
    float ubc[8], b2c[8], gl[8], bl[8];
    #pragma unroll
    for (int cf = 0; cf < 8; ++cf) {
        int col = cf * 16 + r15;
        ubc[cf] = updbl[col]; b2c[cf] = b2u_l[col];
        gl[cf] = lng_l[col];  bl[cf] = lnb_l[col];
    }
    float x[8][4];
    #pragma unroll
    for (int cf = 0; cf < 8; ++cf) {
        int col = cf * 16 + r15;
        #pragma unroll
        for (int r = 0; r < 4; ++r) {
            int lrow = wave * 16 + g * 4 + r;
            float hres = (float)*(const f16*)((const char*)xlds + swz(lrow, col * 2));
            x[cf][r] = hres + fmaxf(acc1[cf][r] + ubc[cf] + degf[r] * b2c[cf], 0.f);
        }
    }

    // ---- layernorm per row, write hn into xlds (own stripe) ----
    #pragma unroll
    for (int r = 0; r < 4; ++r) {
        float s1 = 0.f, s2 = 0.f;
        #pragma unroll
        for (int cf = 0; cf < 8; ++cf) { s1 += x[cf][r]; s2 += x[cf][r] * x[cf][r]; }
        #pragma unroll
        for (int off = 1; off <= 8; off <<= 1) {
            s1 += __shfl_xor(s1, off);
            s2 += __shfl_xor(s2, off);
        }
        float mu  = s1 * (1.0f / H);
        float var = s2 * (1.0f / H) - mu * mu;
        float inv = rsqrtf(var + EPSF);
        int lrow = wave * 16 + g * 4 + r;
        #pragma unroll
        for (int cf = 0; cf < 8; ++cf) {
            int col = cf * 16 + r15;
            float hn = (x[cf][r] - mu) * inv * gl[cf] + bl[cf];
            *(f16*)((char*)xlds + swz(lrow, col * 2)) = (f16)hn;
        }
    }
    __syncthreads();

    // ---- coalesced hf write-back (+ flagged hidsum zero) ----
    for (int i = t; i < 64 * 32; i += 256) {
        int row = i >> 5, c4 = i & 31;
        int n = n0 + row;
        if (n < NN) {
            uint2 v = *(const uint2*)((const char*)xlds + swz(row, c4 * 8));
            *(uint2*)&hf[(size_t)n * H + c4 * 4] = v;
            if (!last && zflag[n])
                *(float4*)&hidsum[(size_t)n * H + c4 * 4] = make_float4(0.f, 0.f, 0.f, 0.f);
        }
    }
    if (last) return;
    gemm2_store(xlds, Wt2next, hs, hd, n0, wave, lane);
}

// ---------------------------------------------------------------------------
// per-graph mean (denom = count+1) and max pooling; batch sorted.
// ---------------------------------------------------------------------------
__global__ void __launch_bounds__(512)
pool(const f16* __restrict__ hf,
     const int* __restrict__ batch,
     float* __restrict__ hg) {
    int g = blockIdx.x;
    int t = threadIdx.x;
    int c = t & 127, q = t >> 7;
    int lo = 0, hi = NN;
    while (lo < hi) { int mid = (lo + hi) >> 1; if (batch[mid] < g) lo = mid + 1; else hi = mid; }
    int start = lo;
    hi = NN;
    while (lo < hi) { int mid = (lo + hi) >> 1; if (batch[mid] < g + 1) lo = mid + 1; else hi = mid; }
    int end = lo;
    float s = 0.f, mx = -INFINITY;
    for (int n = start + q; n < end; n += 4) {
        float v = (float)hf[(size_t)n * H + c];
        s += v;
        mx = fmaxf(mx, v);
    }
    __shared__ float shs[4][H];
    __shared__ float shm[4][H];
    shs[q][c] = s; shm[q][c] = mx;
    __syncthreads();
    if (q == 0) {
        float S = shs[0][c] + shs[1][c] + shs[2][c] + shs[3][c];
        float M = fmaxf(fmaxf(shm[0][c], shm[1][c]), fmaxf(shm[2][c], shm[3][c]));
        float denom = (float)(end - start) + 1.0f;
        hg[(size_t)g * 2 * H + c]     = S / denom;
        hg[(size_t)g * 2 * H + H + c] = M;
    }
}

// ---------------------------------------------------------------------------
// readout MLP
// ---------------------------------------------------------------------------
__global__ void __launch_bounds__(128)
readout(const float* __restrict__ hg,
        const float* __restrict__ W1, const float* __restrict__ b1,
        const float* __restrict__ W2, const float* __restrict__ b2,
        const float* __restrict__ W3, const float* __restrict__ b3,
        float* __restrict__ out) {
    int g = blockIdx.x, t = threadIdx.x;
    __shared__ float xin[2 * H];
    __shared__ float x1[H];
    __shared__ float x2[H / 2];
    xin[t]     = hg[(size_t)g * 2 * H + t];
    xin[H + t] = hg[(size_t)g * 2 * H + H + t];
    __syncthreads();
    float acc = b1[t];
    for (int k = 0; k < 2 * H; ++k) acc += xin[k] * W1[k * H + t];
    x1[t] = fmaxf(acc, 0.f);
    __syncthreads();
    if (t < 64) {
        float a2 = b2[t];
        for (int k = 0; k < H; ++k) a2 += x1[k] * W2[k * 64 + t];
        x2[t] = fmaxf(a2, 0.f);
    }
    __syncthreads();
    if (t < 64) {
        float v = x2[t] * W3[t];
        #pragma unroll
        for (int off = 32; off >= 1; off >>= 1) v += __shfl_xor(v, off, 64);
        if (t == 0) out[g] = v + b3[0];
    }
}

// ---------------------------------------------------------------------------
extern "C" void kernel_launch(void* const* d_in, const int* in_sizes, int n_in,
                              void* d_out, int out_size, void* d_ws, size_t ws_size,
                              hipStream_t stream) {
    const float* node_feats = (const float*)d_in[0];
    const int*   edge_index = (const int*)d_in[1];
    const float* edge_feats = (const float*)d_in[2];
    const int*   batch      = (const int*)d_in[3];
    const float* ne_W  = (const float*)d_in[4];
    const float* ne_b  = (const float*)d_in[5];
    const float* ee_W  = (const float*)d_in[6];
    const float* ee_b  = (const float*)d_in[7];
    const float* msgW1 = (const float*)d_in[8];
    const float* msgb1 = (const float*)d_in[9];
    const float* msgW2 = (const float*)d_in[10];
    const float* msgb2 = (const float*)d_in[11];
    const float* updW  = (const float*)d_in[12];
    const float* updb  = (const float*)d_in[13];
    const float* lng   = (const float*)d_in[14];
    const float* lnb   = (const float*)d_in[15];
    const float* roW1  = (const float*)d_in[16];
    const float* rob1  = (const float*)d_in[17];
    const float* roW2  = (const float*)d_in[18];
    const float* rob2  = (const float*)d_in[19];
    const float* roW3  = (const float*)d_in[20];
    const float* rob3  = (const float*)d_in[21];

    const int* src = edge_index;            // row 0
    const int* dst = edge_index + NE;       // row 1

    char* ws = (char*)d_ws;
    f16*   hf     = (f16*)ws;   ws += (size_t)NN * H * 2;
    float* hidsum = (float*)ws; ws += (size_t)NN * H * 4;
    f16*   hs     = (f16*)ws;   ws += (size_t)NN * H * 2;
    f16*   hd     = (f16*)ws;   ws += (size_t)NN * H * 2;
    f16*   efs    = (f16*)ws;   ws += (size_t)NE * ED * 2;
    int* srcs     = (int*)ws; ws += (size_t)NE * 4;
    int* dsts     = (int*)ws; ws += (size_t)NE * 4;
    int* rowstart = (int*)ws; ws += (size_t)(NN + 4) * 4;
    int* deg      = (int*)ws; ws += (size_t)NN * 4;     // reused as cursor; ends = degree
    int* part     = (int*)ws; ws += (size_t)NN * 4;
    int* bsum     = (int*)ws; ws += (size_t)256 * 4;
    unsigned char* zflag = (unsigned char*)ws; ws += ((size_t)NN + 15) / 16 * 16;
    float* Wec = (float*)ws; ws += (size_t)NL * ED * H * 4;
    float* bec = (float*)ws; ws += (size_t)NL * H * 4;
    float* W2u = (float*)ws; ws += (size_t)NL * H * H * 4;
    float* b2u = (float*)ws; ws += (size_t)NL * H * 4;
    f16* Wt1 = (f16*)ws; ws += (size_t)NL * H * 2 * H * 2;
    f16* Wt2 = (f16*)ws; ws += (size_t)NL * 2 * H * H * 2;
    float* hg  = (float*)ws; ws += (size_t)NG * 2 * H * 4;

    // --- precompute: folded weights + transposed f16 weights + CSR ---
    fold_edge_weights<<<dim3(ED + 1, NL), H, 0, stream>>>(ee_W, ee_b, msgW1, msgb1, Wec, bec);
    fold_W2u<<<dim3(H + 1, NL), H, 0, stream>>>(msgW2, msgb2, updW, W2u, b2u);
    make_Wt1<<<dim3(NL, H), 256, 0, stream>>>(updW, W2u, Wt1);
    make_Wt2<<<dim3(NL, 2 * H), 128, 0, stream>>>(msgW1, Wt2);

    hipMemsetAsync(deg, 0, (size_t)NN * 4, stream);
    csr_count<<<(NE + 255) / 256, 256, 0, stream>>>(dst, deg);
    scan_p1<<<NSC, 1024, 0, stream>>>(deg, part, bsum);
    scan_p2<<<1, 64, 0, stream>>>(bsum);
    scan_p3<<<NSC, 1024, 0, stream>>>(part, bsum, rowstart);
    mark_zero<<<(NN + 255) / 256, 256, 0, stream>>>(rowstart, zflag);
    hipMemsetAsync(deg, 0, (size_t)NN * 4, stream);
    csr_scatter<<<(NE + 255) / 256, 256, 0, stream>>>(src, dst, edge_feats, rowstart,
                                                      deg, srcs, dsts, efs);

    encode_nodes<<<NN / NT, 128, 0, stream>>>(node_feats, ne_W, ne_b, hf);
    msg_pre_mfma<<<NB64, 256, 0, stream>>>(hf, Wt2, zflag, hs, hd, hidsum);

    // --- layers ---
    for (int l = 0; l < NL; ++l) {
        aggregate_edges<<<NE / EPB, 128, 0, stream>>>(srcs, dsts, efs, hs, hd,
                                                      Wec + (size_t)l * ED * H,
                                                      bec + (size_t)l * H, hidsum);
        int nl = (l + 1 < NL) ? (l + 1) : 0;   // safe index; unused when last
        update_pre_mfma<<<NB64, 256, 0, stream>>>(hf, hidsum, deg, zflag,
                                                  Wt1 + (size_t)l * H * 2 * H,
                                                  b2u + (size_t)l * H,
                                                  updb + (size_t)l * H,
                                                  lng + (size_t)l * H, lnb + (size_t)l * H,
                                                  Wt2 + (size_t)nl * 2 * H * H,
                                                  hs, hd, (l == NL - 1) ? 1 : 0);
    }

    pool<<<NG, 512, 0, stream>>>(hf, batch, hg);
    readout<<<NG, H, 0, stream>>>(hg, roW1, rob1, roW2, rob2, roW3, rob3, (float*)d_out);
}

// Round 8
// 670.324 us; speedup vs baseline: 9.0364x; 1.1089x over previous
//
#include <hip/hip_runtime.h>
#include <hip/hip_fp16.h>
#include <math.h>

#define NN 100000
#define NE 500000
#define NG 128
#define ND 91
#define ED 20
#define H  128
#define NL 3
#define EPSF 1e-5f
#define NT 16           // nodes per block in scalar encode
#define EPB 32          // edges per block in aggregation
#define NB64 ((NN + 63) / 64)
#define NSC ((NN + 1023) / 1024)

typedef _Float16 f16;
typedef _Float16 f16x8 __attribute__((ext_vector_type(8)));
typedef float    f32x4 __attribute__((ext_vector_type(4)));

// swizzled LDS byte offset for a [64][128] f16 tile (row stride 256 B)
__device__ __forceinline__ int swz(int row, int colbyte) {
    return (row * 256 + colbyte) ^ ((row & 7) << 4);
}

// ---------------------------------------------------------------------------
// Fold edge-feature path: Wec[l] = ee_W @ msg_W1[l][2H:3H,:]
//                         bec[l] = ee_b @ msg_W1[l][2H:3H,:] + msg_b1[l]
// ---------------------------------------------------------------------------
__global__ void fold_edge_weights(const float* __restrict__ eeW,
                                  const float* __restrict__ eeb,
                                  const float* __restrict__ msgW1,
                                  const float* __restrict__ msgb1,
                                  float* __restrict__ Wec,
                                  float* __restrict__ bec) {
    int l = blockIdx.y;
    int k = blockIdx.x;                        // 0..ED (ED => bias row)
    int c = threadIdx.x;
    const float* W1e = msgW1 + (size_t)l * 3 * H * H + (size_t)2 * H * H;
    if (k < ED) {
        float acc = 0.f;
        for (int m = 0; m < H; ++m) acc += eeW[k * H + m] * W1e[m * H + c];
        Wec[((size_t)l * ED + k) * H + c] = acc;
    } else {
        float acc = msgb1[l * H + c];
        for (int m = 0; m < H; ++m) acc += eeb[m] * W1e[m * H + c];
        bec[(size_t)l * H + c] = acc;
    }
}

// ---------------------------------------------------------------------------
// Fold msg_W2 into update weights: W2u[l] = msg_W2[l] @ updW[l][H:2H,:]
//                                  b2u[l] = msg_b2[l] @ updW[l][H:2H,:]
// ---------------------------------------------------------------------------
__global__ void fold_W2u(const float* __restrict__ msgW2,
                         const float* __restrict__ msgb2,
                         const float* __restrict__ updW,
                         float* __restrict__ W2u,
                         float* __restrict__ b2u) {
    int l = blockIdx.y;
    int k = blockIdx.x;                        // 0..H (H => bias row)
    int c = threadIdx.x;
    const float* Wbot = updW + (size_t)l * 2 * H * H + (size_t)H * H;
    if (k < H) {
        const float* w2row = msgW2 + (size_t)l * H * H + (size_t)k * H;
        float acc = 0.f;
        for (int m = 0; m < H; ++m) acc += w2row[m] * Wbot[m * H + c];
        W2u[((size_t)l * H + k) * H + c] = acc;
    } else {
        const float* b2 = msgb2 + (size_t)l * H;
        float acc = 0.f;
        for (int m = 0; m < H; ++m) acc += b2[m] * Wbot[m * H + c];
        b2u[(size_t)l * H + c] = acc;
    }
}

// ---------------------------------------------------------------------------
// W1s: fragment-major pre-swizzled GEMM1 weights.
// frag = cf*8+kc (cf 0..7, kc 0..7); lane 0..63; j 0..7.
// value = B[col=cf*16+(lane&15)][k=kc*32+(lane>>4)*8+j],
// B[col][k] = k<H ? updW_top[k][col] : W2u[k-H][col]
// ---------------------------------------------------------------------------
__global__ void make_W1s(const float* __restrict__ updW,
                         const float* __restrict__ W2u,
                         f16* __restrict__ W1s) {
    int l = blockIdx.x, frag = blockIdx.y, lane = threadIdx.x;  // 64 threads
    int cf = frag >> 3, kc = frag & 7;
    int col = cf * 16 + (lane & 15);
    int k0 = kc * 32 + (lane >> 4) * 8;
    f16* out = W1s + ((size_t)l * 64 + frag) * 512 + lane * 8;
    for (int j = 0; j < 8; ++j) {
        int k = k0 + j;
        float v = (k < H) ? updW[(size_t)l * 2 * H * H + (size_t)k * H + col]
                          : W2u[(size_t)l * H * H + (size_t)(k - H) * H + col];
        out[j] = (f16)v;
    }
}

// ---------------------------------------------------------------------------
// W2s: fragment-major pre-swizzled GEMM2 weights.
// frag = (wave*4+mf)*4+kc (wave 0..3, mf 0..3, kc 0..3).
// value = A[oc=wave*64+mf*16+(lane&15)][k=kc*32+(lane>>4)*8+j],
// A[oc][k] = msg_W1[l][(oc<H?0:H)+k][oc&127]
// ---------------------------------------------------------------------------
__global__ void make_W2s(const float* __restrict__ msgW1,
                         f16* __restrict__ W2s) {
    int l = blockIdx.x, frag = blockIdx.y, lane = threadIdx.x;  // 64 threads
    int wave = frag >> 4, mf = (frag >> 2) & 3, kc = frag & 3;
    int oc = wave * 64 + mf * 16 + (lane & 15);
    int k0 = kc * 32 + (lane >> 4) * 8;
    const float* W1 = msgW1 + (size_t)l * 3 * H * H;
    f16* out = W2s + ((size_t)l * 64 + frag) * 512 + lane * 8;
    for (int j = 0; j < 8; ++j) {
        int k = k0 + j;
        float v = W1[(size_t)((oc < H ? 0 : H) + k) * H + (oc & (H - 1))];
        out[j] = (f16)v;
    }
}

// ---------------------------------------------------------------------------
// CSR build over dst
// ---------------------------------------------------------------------------
__global__ void csr_count(const int* __restrict__ dst, int* __restrict__ deg) {
    int e = blockIdx.x * blockDim.x + threadIdx.x;
    if (e < NE) atomicAdd(&deg[dst[e]], 1);
}

// 3-phase exclusive scan: p1 per-1024-block scan, p2 block-sum scan, p3 add
__global__ void scan_p1(const int* __restrict__ deg,
                        int* __restrict__ part, int* __restrict__ bsum) {
    __shared__ int ws[16];
    int t = threadIdx.x, lane = t & 63, w = t >> 6;
    int i = blockIdx.x * 1024 + t;
    int v = (i < NN) ? deg[i] : 0;
    int inc = v;
    #pragma unroll
    for (int off = 1; off < 64; off <<= 1) {
        int u = __shfl_up(inc, off, 64);
        if (lane >= off) inc += u;
    }
    if (lane == 63) ws[w] = inc;
    __syncthreads();
    if (t == 0) {
        int run = 0;
        #pragma unroll
        for (int q = 0; q < 16; ++q) { int tmp = ws[q]; ws[q] = run; run += tmp; }
        bsum[blockIdx.x] = run;
    }
    __syncthreads();
    if (i < NN) part[i] = ws[w] + inc - v;
}

__global__ void scan_p2(int* __restrict__ bsum) {
    if (threadIdx.x == 0) {
        int run = 0;
        for (int q = 0; q < NSC; ++q) { int tmp = bsum[q]; bsum[q] = run; run += tmp; }
    }
}

__global__ void scan_p3(const int* __restrict__ part, const int* __restrict__ bsum,
                        int* __restrict__ rowstart) {
    int i = blockIdx.x * 1024 + threadIdx.x;
    if (i < NN) rowstart[i] = part[i] + bsum[blockIdx.x];
    if (i == 0) rowstart[NN] = NE;
}

// zflag[n]=1 iff node needs hidsum zero-init (deg0 or receives atomics)
__global__ void mark_zero(const int* __restrict__ rowstart,
                          unsigned char* __restrict__ zflag) {
    int n = blockIdx.x * 256 + threadIdx.x;
    if (n >= NN) return;
    int b = rowstart[n], e = rowstart[n + 1];
    bool interior = (b < e) && (b % EPB != 0) && (e % EPB != 0)
                    && ((b / EPB) == ((e - 1) / EPB));
    zflag[n] = interior ? 0 : 1;
}

__global__ void csr_scatter(const int* __restrict__ src,
                            const int* __restrict__ dst,
                            const float* __restrict__ ef,
                            const int* __restrict__ rowstart,
                            int* __restrict__ cursor,
                            int* __restrict__ srcs,
                            int* __restrict__ dsts,
                            f16* __restrict__ efs) {
    int e = blockIdx.x * blockDim.x + threadIdx.x;
    if (e < NE) {
        int d = dst[e];
        int pos = atomicAdd(&cursor[d], 1);
        int j = rowstart[d] + pos;
        srcs[j] = src[e];
        dsts[j] = d;
        const float* efp = ef + (size_t)e * ED;
        f16* out = efs + (size_t)j * ED;
        #pragma unroll
        for (int k = 0; k < ED; ++k) out[k] = (f16)efp[k];
    }
}

// ---------------------------------------------------------------------------
// hf = f16(node_feats @ ne_W + ne_b)  (scalar GEMV, NT nodes / 128 threads)
// ---------------------------------------------------------------------------
__global__ void __launch_bounds__(128)
encode_nodes(const float* __restrict__ nf,
             const float* __restrict__ neW, const float* __restrict__ neb,
             f16* __restrict__ hf) {
    int c = threadIdx.x;
    int n0 = blockIdx.x * NT;
    __shared__ float rows[NT][92];
    for (int i = c; i < NT * ND; i += 128) rows[i / ND][i % ND] = nf[(size_t)n0 * ND + i];
    __syncthreads();
    float bb = neb[c];
    float acc[NT];
    #pragma unroll
    for (int nt = 0; nt < NT; ++nt) acc[nt] = bb;
    for (int k0 = 0; k0 + 4 <= ND; k0 += 4) {
        float w0 = neW[(k0 + 0) * H + c];
        float w1 = neW[(k0 + 1) * H + c];
        float w2 = neW[(k0 + 2) * H + c];
        float w3 = neW[(k0 + 3) * H + c];
        #pragma unroll
        for (int nt = 0; nt < NT; ++nt) {
            float4 r = *(const float4*)&rows[nt][k0];
            acc[nt] += r.x * w0 + r.y * w1 + r.z * w2 + r.w * w3;
        }
    }
    for (int k = ND & ~3; k < ND; ++k) {
        float w = neW[k * H + c];
        #pragma unroll
        for (int nt = 0; nt < NT; ++nt) acc[nt] += rows[nt][k] * w;
    }
    #pragma unroll
    for (int nt = 0; nt < NT; ++nt) hf[(size_t)(n0 + nt) * H + c] = (f16)acc[nt];
}

// ---------------------------------------------------------------------------
// GEMM2 device fn: D[outcol 0..255][node 0..63] = W2s(frag-major) x xlds
// ---------------------------------------------------------------------------
__device__ __forceinline__ void gemm2_store(const f16* xlds,
                                            const f16* __restrict__ W2s_l,
                                            f16* __restrict__ hs,
                                            f16* __restrict__ hd,
                                            int n0, int wave, int lane) {
    int g = lane >> 4, r15 = lane & 15;
    f16x8 B2[4][4];
    #pragma unroll
    for (int nf = 0; nf < 4; ++nf) {
        int row = nf * 16 + r15;
        #pragma unroll
        for (int kc = 0; kc < 4; ++kc)
            B2[nf][kc] = *(const f16x8*)((const char*)xlds + swz(row, kc * 64 + g * 16));
    }
    f16* outb = (wave < 2) ? hs : hd;
    int colw = (wave & 1) * 64;
    #pragma unroll
    for (int mf = 0; mf < 4; ++mf) {
        f16x8 A2[4];
        #pragma unroll
        for (int kc = 0; kc < 4; ++kc)
            A2[kc] = *(const f16x8*)&W2s_l[(size_t)(((wave * 4 + mf) * 4 + kc) * 64 + lane) * 8];
        #pragma unroll
        for (int nf = 0; nf < 4; ++nf) {
            f32x4 acc = {0.f, 0.f, 0.f, 0.f};
            #pragma unroll
            for (int kc = 0; kc < 4; ++kc)
                acc = __builtin_amdgcn_mfma_f32_16x16x32_f16(A2[kc], B2[nf][kc], acc, 0, 0, 0);
            int node = n0 + nf * 16 + r15;
            if (node < NN) {
                union { f16 q[4]; uint2 u; } pk;
                pk.q[0] = (f16)acc[0]; pk.q[1] = (f16)acc[1];
                pk.q[2] = (f16)acc[2]; pk.q[3] = (f16)acc[3];
                *(uint2*)&outb[(size_t)node * H + colw + mf * 16 + g * 4] = pk.u;
            }
        }
    }
}

// ---------------------------------------------------------------------------
// msg_pre: stage hf tile -> swizzled f16 LDS, zero flagged hidsum (f16), GEMM2
// ---------------------------------------------------------------------------
__global__ void __launch_bounds__(256)
msg_pre_mfma(const f16* __restrict__ hf,
             const f16* __restrict__ W2s_l,
             const unsigned char* __restrict__ zflag,
             f16* __restrict__ hs, f16* __restrict__ hd,
             f16* __restrict__ hidsum) {
    __shared__ f16 xlds[64 * 128];
    int t = threadIdx.x;
    int n0 = blockIdx.x * 64;
    for (int i = t; i < 64 * 32; i += 256) {       // 4-f16 chunks
        int row = i >> 5, c4 = i & 31;
        uint2 v = make_uint2(0u, 0u);
        int n = n0 + row;
        if (n < NN) {
            v = *(const uint2*)&hf[(size_t)n * H + c4 * 4];
            if (zflag[n]) *(uint2*)&hidsum[(size_t)n * H + c4 * 4] = make_uint2(0u, 0u);
        }
        *(uint2*)((char*)xlds + swz(row, c4 * 8)) = v;
    }
    __syncthreads();
    gemm2_store(xlds, W2s_l, hs, hd, n0, t >> 6, t & 63);
}

// ---------------------------------------------------------------------------
// flush helpers: pack (col c even, c+1) via shfl, store/atomic f16x2
// ---------------------------------------------------------------------------
__device__ __forceinline__ void flush_store(f16* __restrict__ hidsum,
                                            int d, int c, float acc) {
    float other = __shfl_xor(acc, 1);
    if ((c & 1) == 0) {
        union { f16 q[2]; unsigned u; } pk;
        pk.q[0] = (f16)acc; pk.q[1] = (f16)other;
        *(unsigned*)&hidsum[(size_t)d * H + c] = pk.u;
    }
}

__device__ __forceinline__ void flush_atomic(f16* __restrict__ hidsum,
                                             int d, int c, float acc) {
    float other = __shfl_xor(acc, 1);
    if ((c & 1) == 0) {
        unsigned* p = (unsigned*)&hidsum[(size_t)d * H + c];
        unsigned old = *p;
        while (true) {
            union { f16 q[2]; unsigned u; } cur, nw;
            cur.u = old;
            nw.q[0] = (f16)((float)cur.q[0] + acc);
            nw.q[1] = (f16)((float)cur.q[1] + other);
            unsigned prev = atomicCAS(p, old, nw.u);
            if (prev == old) break;
            old = prev;
        }
    }
}

// ---------------------------------------------------------------------------
// Edge-parallel segmented aggregation over CSR-sorted edges, EPB per block.
// hidsum is f16 now.
// ---------------------------------------------------------------------------
__global__ void __launch_bounds__(128)
aggregate_edges(const int* __restrict__ srcs,
                const int* __restrict__ dsts,
                const f16* __restrict__ efs,
                const f16* __restrict__ hs,
                const f16* __restrict__ hd,
                const float* __restrict__ Wec_l,
                const float* __restrict__ bec_l,
                f16* __restrict__ hidsum) {
    int c = threadIdx.x;
    size_t j0 = (size_t)blockIdx.x * EPB;
    __shared__ float efs_lds[EPB][ED];
    __shared__ int sd[2 * EPB];
    const f16* efsrc = efs + j0 * ED;
    for (int i = c; i < EPB * ED; i += 128) ((float*)efs_lds)[i] = (float)efsrc[i];
    if (c < EPB) { sd[c] = srcs[j0 + c]; sd[EPB + c] = dsts[j0 + c]; }
    __syncthreads();
    float wec[ED];
    #pragma unroll
    for (int k = 0; k < ED; ++k) wec[k] = Wec_l[k * H + c];
    float becc = bec_l[c];
    float hv[EPB];
    #pragma unroll
    for (int jj = 0; jj < EPB; ++jj) {
        hv[jj] = (float)hs[(size_t)sd[jj] * H + c]
               + (float)hd[(size_t)sd[EPB + jj] * H + c];
    }
    int dcur = sd[EPB];
    float acc = 0.f;
    int nflush = 0;
    #pragma unroll
    for (int jj = 0; jj < EPB; ++jj) {
        int d = sd[EPB + jj];
        if (d != dcur) {
            if (nflush == 0) flush_atomic(hidsum, dcur, c, acc);
            else             flush_store(hidsum, dcur, c, acc);
            dcur = d; acc = 0.f; ++nflush;
        }
        float v = hv[jj] + becc;
        #pragma unroll
        for (int k = 0; k < ED; ++k) v = fmaf(efs_lds[jj][k], wec[k], v);
        acc += fmaxf(v, 0.f);
    }
    flush_atomic(hidsum, dcur, c, acc);
}

// ---------------------------------------------------------------------------
// MFMA fused update (64 nodes / 256 threads), LDS-routed, frag-major weights.
// ---------------------------------------------------------------------------
__global__ void __launch_bounds__(256)
update_pre_mfma(f16* __restrict__ hf,
                f16* __restrict__ hidsum,
                const int* __restrict__ degv,
                const unsigned char* __restrict__ zflag,
                const f16* __restrict__ W1s_l,   // frag-major [64][64][8]
                const float* __restrict__ b2u_l,
                const float* __restrict__ updbl,
                const float* __restrict__ lng_l,
                const float* __restrict__ lnb_l,
                const f16* __restrict__ W2s_next,
                f16* __restrict__ hs, f16* __restrict__ hd,
                int last) {
    __shared__ f16 xlds[64 * 128];
    int t = threadIdx.x;
    int wave = t >> 6, lane = t & 63;
    int g = lane >> 4, r15 = lane & 15;
    int n0 = blockIdx.x * 64;

    // ---- P1: coalesced stage of hf tile into swizzled LDS ----
    for (int i = t; i < 64 * 32; i += 256) {
        int row = i >> 5, c4 = i & 31;
        int n = n0 + row;
        uint2 v = make_uint2(0u, 0u);
        if (n < NN) v = *(const uint2*)&hf[(size_t)n * H + c4 * 4];
        *(uint2*)((char*)xlds + swz(row, c4 * 8)) = v;
    }

    // ---- A fragments kc4..7 direct from f16 hidsum (coalesced f16x8) ----
    int arow = n0 + wave * 16 + r15;
    bool av = arow < NN;
    f16x8 zero8;
    for (int i = 0; i < 8; ++i) zero8[i] = (f16)0.f;
    f16x8 A1[8];
    #pragma unroll
    for (int kc = 4; kc < 8; ++kc) {
        A1[kc] = av ? *(const f16x8*)&hidsum[(size_t)arow * H + (kc & 3) * 32 + g * 8]
                    : zero8;
    }
    __syncthreads();

    // ---- A fragments kc0..3 from xlds ----
    int lrow_a = wave * 16 + r15;
    #pragma unroll
    for (int kc = 0; kc < 4; ++kc)
        A1[kc] = *(const f16x8*)((const char*)xlds + swz(lrow_a, kc * 64 + g * 16));

    // ---- GEMM1 (coalesced frag-major weight loads) ----
    f32x4 acc1[8];
    #pragma unroll
    for (int cf = 0; cf < 8; ++cf) acc1[cf] = (f32x4){0.f, 0.f, 0.f, 0.f};
    #pragma unroll
    for (int cf = 0; cf < 8; ++cf) {
        #pragma unroll
        for (int kc = 0; kc < 8; ++kc) {
            f16x8 b = *(const f16x8*)&W1s_l[(size_t)((cf * 8 + kc) * 64 + lane) * 8];
            acc1[cf] = __builtin_amdgcn_mfma_f32_16x16x32_f16(A1[kc], b, acc1[cf], 0, 0, 0);
        }
    }

    // ---- epilogue ----
    int nodes[4]; bool nv[4]; float degf[4];
    #pragma unroll
    for (int r = 0; r < 4; ++r) {
        nodes[r] = n0 + wave * 16 + g * 4 + r;
        nv[r] = nodes[r] < NN;
        degf[r] = nv[r] ? (float)degv[nodes[r]] : 0.f;
    }
    float ubc[8], b2c[8], gl[8], bl[8];
    #pragma unroll
    for (int cf = 0; cf < 8; ++cf) {
        int col = cf * 16 + r15;
        ubc[cf] = updbl[col]; b2c[cf] = b2u_l[col];
        gl[cf] = lng_l[col];  bl[cf] = lnb_l[col];
    }
    float x[8][4];
    #pragma unroll
    for (int cf = 0; cf < 8; ++cf) {
        int col = cf * 16 + r15;
        #pragma unroll
        for (int r = 0; r < 4; ++r) {
            int lrow = wave * 16 + g * 4 + r;
            float hres = (float)*(const f16*)((const char*)xlds + swz(lrow, col * 2));
            x[cf][r] = hres + fmaxf(acc1[cf][r] + ubc[cf] + degf[r] * b2c[cf], 0.f);
        }
    }

    // ---- layernorm per row, write hn into xlds ----
    #pragma unroll
    for (int r = 0; r < 4; ++r) {
        float s1 = 0.f, s2 = 0.f;
        #pragma unroll
        for (int cf = 0; cf < 8; ++cf) { s1 += x[cf][r]; s2 += x[cf][r] * x[cf][r]; }
        #pragma unroll
        for (int off = 1; off <= 8; off <<= 1) {
            s1 += __shfl_xor(s1, off);
            s2 += __shfl_xor(s2, off);
        }
        float mu  = s1 * (1.0f / H);
        float var = s2 * (1.0f / H) - mu * mu;
        float inv = rsqrtf(var + EPSF);
        int lrow = wave * 16 + g * 4 + r;
        #pragma unroll
        for (int cf = 0; cf < 8; ++cf) {
            int col = cf * 16 + r15;
            float hn = (x[cf][r] - mu) * inv * gl[cf] + bl[cf];
            *(f16*)((char*)xlds + swz(lrow, col * 2)) = (f16)hn;
        }
    }
    __syncthreads();

    // ---- coalesced hf write-back (+ flagged hidsum zero, f16) ----
    for (int i = t; i < 64 * 32; i += 256) {
        int row = i >> 5, c4 = i & 31;
        int n = n0 + row;
        if (n < NN) {
            uint2 v = *(const uint2*)((const char*)xlds + swz(row, c4 * 8));
            *(uint2*)&hf[(size_t)n * H + c4 * 4] = v;
            if (!last && zflag[n])
                *(uint2*)&hidsum[(size_t)n * H + c4 * 4] = make_uint2(0u, 0u);
        }
    }
    if (last) return;
    gemm2_store(xlds, W2s_next, hs, hd, n0, wave, lane);
}

// ---------------------------------------------------------------------------
// per-graph mean (denom = count+1) and max pooling; batch sorted.
// ---------------------------------------------------------------------------
__global__ void __launch_bounds__(512)
pool(const f16* __restrict__ hf,
     const int* __restrict__ batch,
     float* __restrict__ hg) {
    int g = blockIdx.x;
    int t = threadIdx.x;
    int c = t & 127, q = t >> 7;
    int lo = 0, hi = NN;
    while (lo < hi) { int mid = (lo + hi) >> 1; if (batch[mid] < g) lo = mid + 1; else hi = mid; }
    int start = lo;
    hi = NN;
    while (lo < hi) { int mid = (lo + hi) >> 1; if (batch[mid] < g + 1) lo = mid + 1; else hi = mid; }
    int end = lo;
    float s = 0.f, mx = -INFINITY;
    for (int n = start + q; n < end; n += 4) {
        float v = (float)hf[(size_t)n * H + c];
        s += v;
        mx = fmaxf(mx, v);
    }
    __shared__ float shs[4][H];
    __shared__ float shm[4][H];
    shs[q][c] = s; shm[q][c] = mx;
    __syncthreads();
    if (q == 0) {
        float S = shs[0][c] + shs[1][c] + shs[2][c] + shs[3][c];
        float M = fmaxf(fmaxf(shm[0][c], shm[1][c]), fmaxf(shm[2][c], shm[3][c]));
        float denom = (float)(end - start) + 1.0f;
        hg[(size_t)g * 2 * H + c]     = S / denom;
        hg[(size_t)g * 2 * H + H + c] = M;
    }
}

// ---------------------------------------------------------------------------
// readout MLP
// ---------------------------------------------------------------------------
__global__ void __launch_bounds__(128)
readout(const float* __restrict__ hg,
        const float* __restrict__ W1, const float* __restrict__ b1,
        const float* __restrict__ W2, const float* __restrict__ b2,
        const float* __restrict__ W3, const float* __restrict__ b3,
        float* __restrict__ out) {
    int g = blockIdx.x, t = threadIdx.x;
    __shared__ float xin[2 * H];
    __shared__ float x1[H];
    __shared__ float x2[H / 2];
    xin[t]     = hg[(size_t)g * 2 * H + t];
    xin[H + t] = hg[(size_t)g * 2 * H + H + t];
    __syncthreads();
    float acc = b1[t];
    for (int k = 0; k < 2 * H; ++k) acc += xin[k] * W1[k * H + t];
    x1[t] = fmaxf(acc, 0.f);
    __syncthreads();
    if (t < 64) {
        float a2 = b2[t];
        for (int k = 0; k < H; ++k) a2 += x1[k] * W2[k * 64 + t];
        x2[t] = fmaxf(a2, 0.f);
    }
    __syncthreads();
    if (t < 64) {
        float v = x2[t] * W3[t];
        #pragma unroll
        for (int off = 32; off >= 1; off >>= 1) v += __shfl_xor(v, off, 64);
        if (t == 0) out[g] = v + b3[0];
    }
}

// ---------------------------------------------------------------------------
extern "C" void kernel_launch(void* const* d_in, const int* in_sizes, int n_in,
                              void* d_out, int out_size, void* d_ws, size_t ws_size,
                              hipStream_t stream) {
    const float* node_feats = (const float*)d_in[0];
    const int*   edge_index = (const int*)d_in[1];
    const float* edge_feats = (const float*)d_in[2];
    const int*   batch      = (const int*)d_in[3];
    const float* ne_W  = (const float*)d_in[4];
    const float* ne_b  = (const float*)d_in[5];
    const float* ee_W  = (const float*)d_in[6];
    const float* ee_b  = (const float*)d_in[7];
    const float* msgW1 = (const float*)d_in[8];
    const float* msgb1 = (const float*)d_in[9];
    const float* msgW2 = (const float*)d_in[10];
    const float* msgb2 = (const float*)d_in[11];
    const float* updW  = (const float*)d_in[12];
    const float* updb  = (const float*)d_in[13];
    const float* lng   = (const float*)d_in[14];
    const float* lnb   = (const float*)d_in[15];
    const float* roW1  = (const float*)d_in[16];
    const float* rob1  = (const float*)d_in[17];
    const float* roW2  = (const float*)d_in[18];
    const float* rob2  = (const float*)d_in[19];
    const float* roW3  = (const float*)d_in[20];
    const float* rob3  = (const float*)d_in[21];

    const int* src = edge_index;            // row 0
    const int* dst = edge_index + NE;       // row 1

    char* ws = (char*)d_ws;
    f16*   hf     = (f16*)ws;   ws += (size_t)NN * H * 2;
    f16*   hidsum = (f16*)ws;   ws += (size_t)NN * H * 2;
    f16*   hs     = (f16*)ws;   ws += (size_t)NN * H * 2;
    f16*   hd     = (f16*)ws;   ws += (size_t)NN * H * 2;
    f16*   efs    = (f16*)ws;   ws += (size_t)NE * ED * 2;
    int* srcs     = (int*)ws; ws += (size_t)NE * 4;
    int* dsts     = (int*)ws; ws += (size_t)NE * 4;
    int* rowstart = (int*)ws; ws += (size_t)(NN + 4) * 4;
    int* deg      = (int*)ws; ws += (size_t)NN * 4;     // reused as cursor; ends = degree
    int* part     = (int*)ws; ws += (size_t)NN * 4;
    int* bsum     = (int*)ws; ws += (size_t)256 * 4;
    unsigned char* zflag = (unsigned char*)ws; ws += ((size_t)NN + 15) / 16 * 16;
    float* Wec = (float*)ws; ws += (size_t)NL * ED * H * 4;
    float* bec = (float*)ws; ws += (size_t)NL * H * 4;
    float* W2u = (float*)ws; ws += (size_t)NL * H * H * 4;
    float* b2u = (float*)ws; ws += (size_t)NL * H * 4;
    f16* W1s = (f16*)ws; ws += (size_t)NL * 64 * 512 * 2;
    f16* W2s = (f16*)ws; ws += (size_t)NL * 64 * 512 * 2;
    float* hg  = (float*)ws; ws += (size_t)NG * 2 * H * 4;

    // --- precompute: folded weights + frag-major f16 weights + CSR ---
    fold_edge_weights<<<dim3(ED + 1, NL), H, 0, stream>>>(ee_W, ee_b, msgW1, msgb1, Wec, bec);
    fold_W2u<<<dim3(H + 1, NL), H, 0, stream>>>(msgW2, msgb2, updW, W2u, b2u);
    make_W1s<<<dim3(NL, 64), 64, 0, stream>>>(updW, W2u, W1s);
    make_W2s<<<dim3(NL, 64), 64, 0, stream>>>(msgW1, W2s);

    hipMemsetAsync(deg, 0, (size_t)NN * 4, stream);
    csr_count<<<(NE + 255) / 256, 256, 0, stream>>>(dst, deg);
    scan_p1<<<NSC, 1024, 0, stream>>>(deg, part, bsum);
    scan_p2<<<1, 64, 0, stream>>>(bsum);
    scan_p3<<<NSC, 1024, 0, stream>>>(part, bsum, rowstart);
    mark_zero<<<(NN + 255) / 256, 256, 0, stream>>>(rowstart, zflag);
    hipMemsetAsync(deg, 0, (size_t)NN * 4, stream);
    csr_scatter<<<(NE + 255) / 256, 256, 0, stream>>>(src, dst, edge_feats, rowstart,
                                                      deg, srcs, dsts, efs);

    encode_nodes<<<NN / NT, 128, 0, stream>>>(node_feats, ne_W, ne_b, hf);
    msg_pre_mfma<<<NB64, 256, 0, stream>>>(hf, W2s, zflag, hs, hd, hidsum);

    // --- layers ---
    for (int l = 0; l < NL; ++l) {
        aggregate_edges<<<NE / EPB, 128, 0, stream>>>(srcs, dsts, efs, hs, hd,
                                                      Wec + (size_t)l * ED * H,
                                                      bec + (size_t)l * H, hidsum);
        int nl = (l + 1 < NL) ? (l + 1) : 0;   // safe index; unused when last
        update_pre_mfma<<<NB64, 256, 0, stream>>>(hf, hidsum, deg, zflag,
                                                  W1s + (size_t)l * 64 * 512,
                                                  b2u + (size_t)l * H,
                                                  updb + (size_t)l * H,
                                                  lng + (size_t)l * H, lnb + (size_t)l * H,
                                                  W2s + (size_t)nl * 64 * 512,
                                                  hs, hd, (l == NL - 1) ? 1 : 0);
    }

    pool<<<NG, 512, 0, stream>>>(hf, batch, hg);
    readout<<<NG, H, 0, stream>>>(hg, roW1, rob1, roW2, rob2, roW3, rob3, (float*)d_out);
}

// Round 9
// 607.004 us; speedup vs baseline: 9.9790x; 1.1043x over previous
//
#include <hip/hip_runtime.h>
#include <hip/hip_fp16.h>
#include <math.h>

#define NN 100000
#define NE 500000
#define NG 128
#define ND 91
#define ED 20
#define H  128
#define NL 3
#define EPSF 1e-5f
#define NT 16           // nodes per block in scalar encode
#define EPB 32          // edges per block in aggregation
#define NB64 ((NN + 63) / 64)
#define NSC ((NN + 1023) / 1024)

typedef _Float16 f16;
typedef _Float16 f16x2 __attribute__((ext_vector_type(2)));
typedef _Float16 f16x8 __attribute__((ext_vector_type(8)));
typedef float    f32x4 __attribute__((ext_vector_type(4)));

// swizzled LDS byte offset for a [64][128] f16 tile (row stride 256 B)
__device__ __forceinline__ int swz(int row, int colbyte) {
    return (row * 256 + colbyte) ^ ((row & 7) << 4);
}

// ---------------------------------------------------------------------------
// Fold edge-feature path: Wec[l] = ee_W @ msg_W1[l][2H:3H,:]
//                         bec[l] = ee_b @ msg_W1[l][2H:3H,:] + msg_b1[l]
// ---------------------------------------------------------------------------
__global__ void fold_edge_weights(const float* __restrict__ eeW,
                                  const float* __restrict__ eeb,
                                  const float* __restrict__ msgW1,
                                  const float* __restrict__ msgb1,
                                  float* __restrict__ Wec,
                                  float* __restrict__ bec) {
    int l = blockIdx.y;
    int k = blockIdx.x;                        // 0..ED (ED => bias row)
    int c = threadIdx.x;
    const float* W1e = msgW1 + (size_t)l * 3 * H * H + (size_t)2 * H * H;
    if (k < ED) {
        float acc = 0.f;
        for (int m = 0; m < H; ++m) acc += eeW[k * H + m] * W1e[m * H + c];
        Wec[((size_t)l * ED + k) * H + c] = acc;
    } else {
        float acc = msgb1[l * H + c];
        for (int m = 0; m < H; ++m) acc += eeb[m] * W1e[m * H + c];
        bec[(size_t)l * H + c] = acc;
    }
}

// pack Wec into f16 pairs: wecp[l][k2][c] = (Wec[2k2][c], Wec[2k2+1][c])
__global__ void pack_wec(const float* __restrict__ Wec,
                         f16x2* __restrict__ wecp) {
    int l = blockIdx.x, k2 = blockIdx.y, c = threadIdx.x;
    f16x2 v;
    v[0] = (f16)Wec[((size_t)l * ED + 2 * k2) * H + c];
    v[1] = (f16)Wec[((size_t)l * ED + 2 * k2 + 1) * H + c];
    wecp[((size_t)l * (ED / 2) + k2) * H + c] = v;
}

// ---------------------------------------------------------------------------
// Fold msg_W2 into update weights: W2u[l] = msg_W2[l] @ updW[l][H:2H,:]
//                                  b2u[l] = msg_b2[l] @ updW[l][H:2H,:]
// ---------------------------------------------------------------------------
__global__ void fold_W2u(const float* __restrict__ msgW2,
                         const float* __restrict__ msgb2,
                         const float* __restrict__ updW,
                         float* __restrict__ W2u,
                         float* __restrict__ b2u) {
    int l = blockIdx.y;
    int k = blockIdx.x;                        // 0..H (H => bias row)
    int c = threadIdx.x;
    const float* Wbot = updW + (size_t)l * 2 * H * H + (size_t)H * H;
    if (k < H) {
        const float* w2row = msgW2 + (size_t)l * H * H + (size_t)k * H;
        float acc = 0.f;
        for (int m = 0; m < H; ++m) acc += w2row[m] * Wbot[m * H + c];
        W2u[((size_t)l * H + k) * H + c] = acc;
    } else {
        const float* b2 = msgb2 + (size_t)l * H;
        float acc = 0.f;
        for (int m = 0; m < H; ++m) acc += b2[m] * Wbot[m * H + c];
        b2u[(size_t)l * H + c] = acc;
    }
}

// ---------------------------------------------------------------------------
// W1s: fragment-major pre-swizzled GEMM1 weights.
// ---------------------------------------------------------------------------
__global__ void make_W1s(const float* __restrict__ updW,
                         const float* __restrict__ W2u,
                         f16* __restrict__ W1s) {
    int l = blockIdx.x, frag = blockIdx.y, lane = threadIdx.x;  // 64 threads
    int cf = frag >> 3, kc = frag & 7;
    int col = cf * 16 + (lane & 15);
    int k0 = kc * 32 + (lane >> 4) * 8;
    f16* out = W1s + ((size_t)l * 64 + frag) * 512 + lane * 8;
    for (int j = 0; j < 8; ++j) {
        int k = k0 + j;
        float v = (k < H) ? updW[(size_t)l * 2 * H * H + (size_t)k * H + col]
                          : W2u[(size_t)l * H * H + (size_t)(k - H) * H + col];
        out[j] = (f16)v;
    }
}

// ---------------------------------------------------------------------------
// W2s: fragment-major pre-swizzled GEMM2 weights.
// ---------------------------------------------------------------------------
__global__ void make_W2s(const float* __restrict__ msgW1,
                         f16* __restrict__ W2s) {
    int l = blockIdx.x, frag = blockIdx.y, lane = threadIdx.x;  // 64 threads
    int wave = frag >> 4, mf = (frag >> 2) & 3, kc = frag & 3;
    int oc = wave * 64 + mf * 16 + (lane & 15);
    int k0 = kc * 32 + (lane >> 4) * 8;
    const float* W1 = msgW1 + (size_t)l * 3 * H * H;
    f16* out = W2s + ((size_t)l * 64 + frag) * 512 + lane * 8;
    for (int j = 0; j < 8; ++j) {
        int k = k0 + j;
        float v = W1[(size_t)((oc < H ? 0 : H) + k) * H + (oc & (H - 1))];
        out[j] = (f16)v;
    }
}

// ---------------------------------------------------------------------------
// CSR build over dst
// ---------------------------------------------------------------------------
__global__ void csr_count(const int* __restrict__ dst, int* __restrict__ deg) {
    int e = blockIdx.x * blockDim.x + threadIdx.x;
    if (e < NE) atomicAdd(&deg[dst[e]], 1);
}

__global__ void scan_p1(const int* __restrict__ deg,
                        int* __restrict__ part, int* __restrict__ bsum) {
    __shared__ int ws[16];
    int t = threadIdx.x, lane = t & 63, w = t >> 6;
    int i = blockIdx.x * 1024 + t;
    int v = (i < NN) ? deg[i] : 0;
    int inc = v;
    #pragma unroll
    for (int off = 1; off < 64; off <<= 1) {
        int u = __shfl_up(inc, off, 64);
        if (lane >= off) inc += u;
    }
    if (lane == 63) ws[w] = inc;
    __syncthreads();
    if (t == 0) {
        int run = 0;
        #pragma unroll
        for (int q = 0; q < 16; ++q) { int tmp = ws[q]; ws[q] = run; run += tmp; }
        bsum[blockIdx.x] = run;
    }
    __syncthreads();
    if (i < NN) part[i] = ws[w] + inc - v;
}

__global__ void scan_p2(int* __restrict__ bsum) {
    if (threadIdx.x == 0) {
        int run = 0;
        for (int q = 0; q < NSC; ++q) { int tmp = bsum[q]; bsum[q] = run; run += tmp; }
    }
}

__global__ void scan_p3(const int* __restrict__ part, const int* __restrict__ bsum,
                        int* __restrict__ rowstart) {
    int i = blockIdx.x * 1024 + threadIdx.x;
    if (i < NN) rowstart[i] = part[i] + bsum[blockIdx.x];
    if (i == 0) rowstart[NN] = NE;
}

// zflag[n]=1 iff node needs hidsum zero-init (deg0 or receives atomics)
__global__ void mark_zero(const int* __restrict__ rowstart,
                          unsigned char* __restrict__ zflag) {
    int n = blockIdx.x * 256 + threadIdx.x;
    if (n >= NN) return;
    int b = rowstart[n], e = rowstart[n + 1];
    bool interior = (b < e) && (b % EPB != 0) && (e % EPB != 0)
                    && ((b / EPB) == ((e - 1) / EPB));
    zflag[n] = interior ? 0 : 1;
}

__global__ void csr_scatter(const int* __restrict__ src,
                            const int* __restrict__ dst,
                            const float* __restrict__ ef,
                            const int* __restrict__ rowstart,
                            int* __restrict__ cursor,
                            int* __restrict__ srcs,
                            int* __restrict__ dsts,
                            f16* __restrict__ efs) {
    int e = blockIdx.x * blockDim.x + threadIdx.x;
    if (e < NE) {
        int d = dst[e];
        int pos = atomicAdd(&cursor[d], 1);
        int j = rowstart[d] + pos;
        srcs[j] = src[e];
        dsts[j] = d;
        const float* efp = ef + (size_t)e * ED;
        f16* out = efs + (size_t)j * ED;
        #pragma unroll
        for (int k = 0; k < ED; ++k) out[k] = (f16)efp[k];
    }
}

// ---------------------------------------------------------------------------
// hf = f16(node_feats @ ne_W + ne_b)  (scalar GEMV, NT nodes / 128 threads)
// ---------------------------------------------------------------------------
__global__ void __launch_bounds__(128)
encode_nodes(const float* __restrict__ nf,
             const float* __restrict__ neW, const float* __restrict__ neb,
             f16* __restrict__ hf) {
    int c = threadIdx.x;
    int n0 = blockIdx.x * NT;
    __shared__ float rows[NT][92];
    for (int i = c; i < NT * ND; i += 128) rows[i / ND][i % ND] = nf[(size_t)n0 * ND + i];
    __syncthreads();
    float bb = neb[c];
    float acc[NT];
    #pragma unroll
    for (int nt = 0; nt < NT; ++nt) acc[nt] = bb;
    for (int k0 = 0; k0 + 4 <= ND; k0 += 4) {
        float w0 = neW[(k0 + 0) * H + c];
        float w1 = neW[(k0 + 1) * H + c];
        float w2 = neW[(k0 + 2) * H + c];
        float w3 = neW[(k0 + 3) * H + c];
        #pragma unroll
        for (int nt = 0; nt < NT; ++nt) {
            float4 r = *(const float4*)&rows[nt][k0];
            acc[nt] += r.x * w0 + r.y * w1 + r.z * w2 + r.w * w3;
        }
    }
    for (int k = ND & ~3; k < ND; ++k) {
        float w = neW[k * H + c];
        #pragma unroll
        for (int nt = 0; nt < NT; ++nt) acc[nt] += rows[nt][k] * w;
    }
    #pragma unroll
    for (int nt = 0; nt < NT; ++nt) hf[(size_t)(n0 + nt) * H + c] = (f16)acc[nt];
}

// ---------------------------------------------------------------------------
// GEMM2 device fn: D[outcol 0..255][node 0..63] = W2s(frag-major) x xlds
// ---------------------------------------------------------------------------
__device__ __forceinline__ void gemm2_store(const f16* xlds,
                                            const f16* __restrict__ W2s_l,
                                            f16* __restrict__ hs,
                                            f16* __restrict__ hd,
                                            int n0, int wave, int lane) {
    int g = lane >> 4, r15 = lane & 15;
    f16x8 B2[4][4];
    #pragma unroll
    for (int nf = 0; nf < 4; ++nf) {
        int row = nf * 16 + r15;
        #pragma unroll
        for (int kc = 0; kc < 4; ++kc)
            B2[nf][kc] = *(const f16x8*)((const char*)xlds + swz(row, kc * 64 + g * 16));
    }
    f16* outb = (wave < 2) ? hs : hd;
    int colw = (wave & 1) * 64;
    #pragma unroll
    for (int mf = 0; mf < 4; ++mf) {
        f16x8 A2[4];
        #pragma unroll
        for (int kc = 0; kc < 4; ++kc)
            A2[kc] = *(const f16x8*)&W2s_l[(size_t)(((wave * 4 + mf) * 4 + kc) * 64 + lane) * 8];
        #pragma unroll
        for (int nf = 0; nf < 4; ++nf) {
            f32x4 acc = {0.f, 0.f, 0.f, 0.f};
            #pragma unroll
            for (int kc = 0; kc < 4; ++kc)
                acc = __builtin_amdgcn_mfma_f32_16x16x32_f16(A2[kc], B2[nf][kc], acc, 0, 0, 0);
            int node = n0 + nf * 16 + r15;
            if (node < NN) {
                union { f16 q[4]; uint2 u; } pk;
                pk.q[0] = (f16)acc[0]; pk.q[1] = (f16)acc[1];
                pk.q[2] = (f16)acc[2]; pk.q[3] = (f16)acc[3];
                *(uint2*)&outb[(size_t)node * H + colw + mf * 16 + g * 4] = pk.u;
            }
        }
    }
}

// ---------------------------------------------------------------------------
// msg_pre: stage hf tile -> swizzled f16 LDS, zero flagged hidsum (f16), GEMM2
// ---------------------------------------------------------------------------
__global__ void __launch_bounds__(256)
msg_pre_mfma(const f16* __restrict__ hf,
             const f16* __restrict__ W2s_l,
             const unsigned char* __restrict__ zflag,
             f16* __restrict__ hs, f16* __restrict__ hd,
             f16* __restrict__ hidsum) {
    __shared__ f16 xlds[64 * 128];
    int t = threadIdx.x;
    int n0 = blockIdx.x * 64;
    for (int i = t; i < 64 * 32; i += 256) {       // 4-f16 chunks
        int row = i >> 5, c4 = i & 31;
        uint2 v = make_uint2(0u, 0u);
        int n = n0 + row;
        if (n < NN) {
            v = *(const uint2*)&hf[(size_t)n * H + c4 * 4];
            if (zflag[n]) *(uint2*)&hidsum[(size_t)n * H + c4 * 4] = make_uint2(0u, 0u);
        }
        *(uint2*)((char*)xlds + swz(row, c4 * 8)) = v;
    }
    __syncthreads();
    gemm2_store(xlds, W2s_l, hs, hd, n0, t >> 6, t & 63);
}

// ---------------------------------------------------------------------------
// flush helpers: pack (col c even, c+1) via shfl, store/atomic f16x2
// ---------------------------------------------------------------------------
__device__ __forceinline__ void flush_store(f16* __restrict__ hidsum,
                                            int d, int c, float acc) {
    float other = __shfl_xor(acc, 1);
    if ((c & 1) == 0) {
        union { f16 q[2]; unsigned u; } pk;
        pk.q[0] = (f16)acc; pk.q[1] = (f16)other;
        *(unsigned*)&hidsum[(size_t)d * H + c] = pk.u;
    }
}

__device__ __forceinline__ void flush_atomic(f16* __restrict__ hidsum,
                                             int d, int c, float acc) {
    float other = __shfl_xor(acc, 1);
    if ((c & 1) == 0) {
        unsigned* p = (unsigned*)&hidsum[(size_t)d * H + c];
        unsigned old = *p;
        while (true) {
            union { f16 q[2]; unsigned u; } cur, nw;
            cur.u = old;
            nw.q[0] = (f16)((float)cur.q[0] + acc);
            nw.q[1] = (f16)((float)cur.q[1] + other);
            unsigned prev = atomicCAS(p, old, nw.u);
            if (prev == old) break;
            old = prev;
        }
    }
}

// ---------------------------------------------------------------------------
// Edge-parallel segmented aggregation over CSR-sorted edges, EPB per block.
// fdot2-based ef@Wec, raw f16 LDS staging.
// ---------------------------------------------------------------------------
__global__ void __launch_bounds__(128)
aggregate_edges(const int* __restrict__ srcs,
                const int* __restrict__ dsts,
                const f16* __restrict__ efs,
                const f16* __restrict__ hs,
                const f16* __restrict__ hd,
                const f16x2* __restrict__ wecp_l,
                const float* __restrict__ bec_l,
                f16* __restrict__ hidsum) {
    int c = threadIdx.x;
    size_t j0 = (size_t)blockIdx.x * EPB;
    __shared__ f16 efs_lds[EPB * ED];              // 1280 B raw
    __shared__ int sd[2 * EPB];
    {   // raw 16B-chunk copy: EPB*ED*2 = 1280 B = 80 uint4
        const uint4* srcp = (const uint4*)(efs + j0 * ED);
        uint4* dstp = (uint4*)efs_lds;
        if (c < 80) dstp[c] = srcp[c];
        if (c < EPB) { sd[c] = srcs[j0 + c]; sd[EPB + c] = dsts[j0 + c]; }
    }
    __syncthreads();
    f16x2 wp[ED / 2];
    #pragma unroll
    for (int k2 = 0; k2 < ED / 2; ++k2) wp[k2] = wecp_l[k2 * H + c];
    float becc = bec_l[c];
    float hv[EPB];
    #pragma unroll
    for (int jj = 0; jj < EPB; ++jj) {
        hv[jj] = (float)hs[(size_t)sd[jj] * H + c]
               + (float)hd[(size_t)sd[EPB + jj] * H + c];
    }
    int dcur = sd[EPB];
    float acc = 0.f;
    int nflush = 0;
    #pragma unroll
    for (int jj = 0; jj < EPB; ++jj) {
        int d = sd[EPB + jj];
        if (d != dcur) {
            if (nflush == 0) flush_atomic(hidsum, dcur, c, acc);
            else             flush_store(hidsum, dcur, c, acc);
            dcur = d; acc = 0.f; ++nflush;
        }
        float v = hv[jj] + becc;
        const f16x2* ef2 = (const f16x2*)&efs_lds[jj * ED];
        #pragma unroll
        for (int k2 = 0; k2 < ED / 2; ++k2)
            v = __builtin_amdgcn_fdot2(ef2[k2], wp[k2], v, false);
        acc += fmaxf(v, 0.f);
    }
    flush_atomic(hidsum, dcur, c, acc);
}

// ---------------------------------------------------------------------------
// MFMA fused update (64 nodes / 256 threads), LDS-routed, frag-major weights.
// ---------------------------------------------------------------------------
__global__ void __launch_bounds__(256)
update_pre_mfma(f16* __restrict__ hf,
                f16* __restrict__ hidsum,
                const int* __restrict__ degv,
                const unsigned char* __restrict__ zflag,
                const f16* __restrict__ W1s_l,   // frag-major [64][64][8]
                const float* __restrict__ b2u_l,
                const float* __restrict__ updbl,
                const float* __restrict__ lng_l,
                const float* __restrict__ lnb_l,
                const f16* __restrict__ W2s_next,
                f16* __restrict__ hs, f16* __restrict__ hd,
                int last) {
    __shared__ f16 xlds[64 * 128];
    int t = threadIdx.x;
    int wave = t >> 6, lane = t & 63;
    int g = lane >> 4, r15 = lane & 15;
    int n0 = blockIdx.x * 64;

    // ---- P1: coalesced stage of hf tile into swizzled LDS ----
    for (int i = t; i < 64 * 32; i += 256) {
        int row = i >> 5, c4 = i & 31;
        int n = n0 + row;
        uint2 v = make_uint2(0u, 0u);
        if (n < NN) v = *(const uint2*)&hf[(size_t)n * H + c4 * 4];
        *(uint2*)((char*)xlds + swz(row, c4 * 8)) = v;
    }

    // ---- A fragments kc4..7 direct from f16 hidsum (coalesced f16x8) ----
    int arow = n0 + wave * 16 + r15;
    bool av = arow < NN;
    f16x8 zero8;
    for (int i = 0; i < 8; ++i) zero8[i] = (f16)0.f;
    f16x8 A1[8];
    #pragma unroll
    for (int kc = 4; kc < 8; ++kc) {
        A1[kc] = av ? *(const f16x8*)&hidsum[(size_t)arow * H + (kc & 3) * 32 + g * 8]
                    : zero8;
    }
    __syncthreads();

    // ---- A fragments kc0..3 from xlds ----
    int lrow_a = wave * 16 + r15;
    #pragma unroll
    for (int kc = 0; kc < 4; ++kc)
        A1[kc] = *(const f16x8*)((const char*)xlds + swz(lrow_a, kc * 64 + g * 16));

    // ---- GEMM1 (coalesced frag-major weight loads) ----
    f32x4 acc1[8];
    #pragma unroll
    for (int cf = 0; cf < 8; ++cf) acc1[cf] = (f32x4){0.f, 0.f, 0.f, 0.f};
    #pragma unroll
    for (int cf = 0; cf < 8; ++cf) {
        #pragma unroll
        for (int kc = 0; kc < 8; ++kc) {
            f16x8 b = *(const f16x8*)&W1s_l[(size_t)((cf * 8 + kc) * 64 + lane) * 8];
            acc1[cf] = __builtin_amdgcn_mfma_f32_16x16x32_f16(A1[kc], b, acc1[cf], 0, 0, 0);
        }
    }

    // ---- epilogue ----
    int nodes[4]; bool nv[4]; float degf[4];
    #pragma unroll
    for (int r = 0; r < 4; ++r) {
        nodes[r] = n0 + wave * 16 + g * 4 + r;
        nv[r] = nodes[r] < NN;
        degf[r] = nv[r] ? (float)degv[nodes[r]] : 0.f;
    }
    float ubc[8], b2c[8], gl[8], bl[8];
    #pragma unroll
    for (int cf = 0; cf < 8; ++cf) {
        int col = cf * 16 + r15;
        ubc[cf] = updbl[col]; b2c[cf] = b2u_l[col];
        gl[cf] = lng_l[col];  bl[cf] = lnb_l[col];
    }
    float x[8][4];
    #pragma unroll
    for (int cf = 0; cf < 8; ++cf) {
        int col = cf * 16 + r15;
        #pragma unroll
        for (int r = 0; r < 4; ++r) {
            int lrow = wave * 16 + g * 4 + r;
            float hres = (float)*(const f16*)((const char*)xlds + swz(lrow, col * 2));
            x[cf][r] = hres + fmaxf(acc1[cf][r] + ubc[cf] + degf[r] * b2c[cf], 0.f);
        }
    }

    // ---- layernorm per row, write hn into xlds ----
    #pragma unroll
    for (int r = 0; r < 4; ++r) {
        float s1 = 0.f, s2 = 0.f;
        #pragma unroll
        for (int cf = 0; cf < 8; ++cf) { s1 += x[cf][r]; s2 += x[cf][r] * x[cf][r]; }
        #pragma unroll
        for (int off = 1; off <= 8; off <<= 1) {
            s1 += __shfl_xor(s1, off);
            s2 += __shfl_xor(s2, off);
        }
        float mu  = s1 * (1.0f / H);
        float var = s2 * (1.0f / H) - mu * mu;
        float inv = rsqrtf(var + EPSF);
        int lrow = wave * 16 + g * 4 + r;
        #pragma unroll
        for (int cf = 0; cf < 8; ++cf) {
            int col = cf * 16 + r15;
            float hn = (x[cf][r] - mu) * inv * gl[cf] + bl[cf];
            *(f16*)((char*)xlds + swz(lrow, col * 2)) = (f16)hn;
        }
    }
    __syncthreads();

    // ---- coalesced hf write-back (+ flagged hidsum zero, f16) ----
    for (int i = t; i < 64 * 32; i += 256) {
        int row = i >> 5, c4 = i & 31;
        int n = n0 + row;
        if (n < NN) {
            uint2 v = *(const uint2*)((const char*)xlds + swz(row, c4 * 8));
            *(uint2*)&hf[(size_t)n * H + c4 * 4] = v;
            if (!last && zflag[n])
                *(uint2*)&hidsum[(size_t)n * H + c4 * 4] = make_uint2(0u, 0u);
        }
    }
    if (last) return;
    gemm2_store(xlds, W2s_next, hs, hd, n0, wave, lane);
}

// ---------------------------------------------------------------------------
// per-graph mean (denom = count+1) and max pooling; batch sorted.
// ---------------------------------------------------------------------------
__global__ void __launch_bounds__(512)
pool(const f16* __restrict__ hf,
     const int* __restrict__ batch,
     float* __restrict__ hg) {
    int g = blockIdx.x;
    int t = threadIdx.x;
    int c = t & 127, q = t >> 7;
    int lo = 0, hi = NN;
    while (lo < hi) { int mid = (lo + hi) >> 1; if (batch[mid] < g) lo = mid + 1; else hi = mid; }
    int start = lo;
    hi = NN;
    while (lo < hi) { int mid = (lo + hi) >> 1; if (batch[mid] < g + 1) lo = mid + 1; else hi = mid; }
    int end = lo;
    float s = 0.f, mx = -INFINITY;
    for (int n = start + q; n < end; n += 4) {
        float v = (float)hf[(size_t)n * H + c];
        s += v;
        mx = fmaxf(mx, v);
    }
    __shared__ float shs[4][H];
    __shared__ float shm[4][H];
    shs[q][c] = s; shm[q][c] = mx;
    __syncthreads();
    if (q == 0) {
        float S = shs[0][c] + shs[1][c] + shs[2][c] + shs[3][c];
        float M = fmaxf(fmaxf(shm[0][c], shm[1][c]), fmaxf(shm[2][c], shm[3][c]));
        float denom = (float)(end - start) + 1.0f;
        hg[(size_t)g * 2 * H + c]     = S / denom;
        hg[(size_t)g * 2 * H + H + c] = M;
    }
}

// ---------------------------------------------------------------------------
// readout MLP
// ---------------------------------------------------------------------------
__global__ void __launch_bounds__(128)
readout(const float* __restrict__ hg,
        const float* __restrict__ W1, const float* __restrict__ b1,
        const float* __restrict__ W2, const float* __restrict__ b2,
        const float* __restrict__ W3, const float* __restrict__ b3,
        float* __restrict__ out) {
    int g = blockIdx.x, t = threadIdx.x;
    __shared__ float xin[2 * H];
    __shared__ float x1[H];
    __shared__ float x2[H / 2];
    xin[t]     = hg[(size_t)g * 2 * H + t];
    xin[H + t] = hg[(size_t)g * 2 * H + H + t];
    __syncthreads();
    float acc = b1[t];
    for (int k = 0; k < 2 * H; ++k) acc += xin[k] * W1[k * H + t];
    x1[t] = fmaxf(acc, 0.f);
    __syncthreads();
    if (t < 64) {
        float a2 = b2[t];
        for (int k = 0; k < H; ++k) a2 += x1[k] * W2[k * 64 + t];
        x2[t] = fmaxf(a2, 0.f);
    }
    __syncthreads();
    if (t < 64) {
        float v = x2[t] * W3[t];
        #pragma unroll
        for (int off = 32; off >= 1; off >>= 1) v += __shfl_xor(v, off, 64);
        if (t == 0) out[g] = v + b3[0];
    }
}

// ---------------------------------------------------------------------------
extern "C" void kernel_launch(void* const* d_in, const int* in_sizes, int n_in,
                              void* d_out, int out_size, void* d_ws, size_t ws_size,
                              hipStream_t stream) {
    const float* node_feats = (const float*)d_in[0];
    const int*   edge_index = (const int*)d_in[1];
    const float* edge_feats = (const float*)d_in[2];
    const int*   batch      = (const int*)d_in[3];
    const float* ne_W  = (const float*)d_in[4];
    const float* ne_b  = (const float*)d_in[5];
    const float* ee_W  = (const float*)d_in[6];
    const float* ee_b  = (const float*)d_in[7];
    const float* msgW1 = (const float*)d_in[8];
    const float* msgb1 = (const float*)d_in[9];
    const float* msgW2 = (const float*)d_in[10];
    const float* msgb2 = (const float*)d_in[11];
    const float* updW  = (const float*)d_in[12];
    const float* updb  = (const float*)d_in[13];
    const float* lng   = (const float*)d_in[14];
    const float* lnb   = (const float*)d_in[15];
    const float* roW1  = (const float*)d_in[16];
    const float* rob1  = (const float*)d_in[17];
    const float* roW2  = (const float*)d_in[18];
    const float* rob2  = (const float*)d_in[19];
    const float* roW3  = (const float*)d_in[20];
    const float* rob3  = (const float*)d_in[21];

    const int* src = edge_index;            // row 0
    const int* dst = edge_index + NE;       // row 1

    char* ws = (char*)d_ws;
    f16*   hf     = (f16*)ws;   ws += (size_t)NN * H * 2;
    f16*   hidsum = (f16*)ws;   ws += (size_t)NN * H * 2;
    f16*   hs     = (f16*)ws;   ws += (size_t)NN * H * 2;
    f16*   hd     = (f16*)ws;   ws += (size_t)NN * H * 2;
    f16*   efs    = (f16*)ws;   ws += (size_t)NE * ED * 2;
    int* srcs     = (int*)ws; ws += (size_t)NE * 4;
    int* dsts     = (int*)ws; ws += (size_t)NE * 4;
    int* rowstart = (int*)ws; ws += (size_t)(NN + 4) * 4;
    int* deg      = (int*)ws; ws += (size_t)NN * 4;     // reused as cursor; ends = degree
    int* part     = (int*)ws; ws += (size_t)NN * 4;
    int* bsum     = (int*)ws; ws += (size_t)256 * 4;
    unsigned char* zflag = (unsigned char*)ws; ws += ((size_t)NN + 15) / 16 * 16;
    float* Wec = (float*)ws; ws += (size_t)NL * ED * H * 4;
    float* bec = (float*)ws; ws += (size_t)NL * H * 4;
    f16x2* wecp = (f16x2*)ws; ws += (size_t)NL * (ED / 2) * H * 4;
    float* W2u = (float*)ws; ws += (size_t)NL * H * H * 4;
    float* b2u = (float*)ws; ws += (size_t)NL * H * 4;
    f16* W1s = (f16*)ws; ws += (size_t)NL * 64 * 512 * 2;
    f16* W2s = (f16*)ws; ws += (size_t)NL * 64 * 512 * 2;
    float* hg  = (float*)ws; ws += (size_t)NG * 2 * H * 4;

    // --- precompute: folded weights + packed/frag-major f16 weights + CSR ---
    fold_edge_weights<<<dim3(ED + 1, NL), H, 0, stream>>>(ee_W, ee_b, msgW1, msgb1, Wec, bec);
    pack_wec<<<dim3(NL, ED / 2), H, 0, stream>>>(Wec, wecp);
    fold_W2u<<<dim3(H + 1, NL), H, 0, stream>>>(msgW2, msgb2, updW, W2u, b2u);
    make_W1s<<<dim3(NL, 64), 64, 0, stream>>>(updW, W2u, W1s);
    make_W2s<<<dim3(NL, 64), 64, 0, stream>>>(msgW1, W2s);

    hipMemsetAsync(deg, 0, (size_t)NN * 4, stream);
    csr_count<<<(NE + 255) / 256, 256, 0, stream>>>(dst, deg);
    scan_p1<<<NSC, 1024, 0, stream>>>(deg, part, bsum);
    scan_p2<<<1, 64, 0, stream>>>(bsum);
    scan_p3<<<NSC, 1024, 0, stream>>>(part, bsum, rowstart);
    mark_zero<<<(NN + 255) / 256, 256, 0, stream>>>(rowstart, zflag);
    hipMemsetAsync(deg, 0, (size_t)NN * 4, stream);
    csr_scatter<<<(NE + 255) / 256, 256, 0, stream>>>(src, dst, edge_feats, rowstart,
                                                      deg, srcs, dsts, efs);

    encode_nodes<<<NN / NT, 128, 0, stream>>>(node_feats, ne_W, ne_b, hf);
    msg_pre_mfma<<<NB64, 256, 0, stream>>>(hf, W2s, zflag, hs, hd, hidsum);

    // --- layers ---
    for (int l = 0; l < NL; ++l) {
        aggregate_edges<<<NE / EPB, 128, 0, stream>>>(srcs, dsts, efs, hs, hd,
                                                      wecp + (size_t)l * (ED / 2) * H,
                                                      bec + (size_t)l * H, hidsum);
        int nl = (l + 1 < NL) ? (l + 1) : 0;   // safe index; unused when last
        update_pre_mfma<<<NB64, 256, 0, stream>>>(hf, hidsum, deg, zflag,
                                                  W1s + (size_t)l * 64 * 512,
                                                  b2u + (size_t)l * H,
                                                  updb + (size_t)l * H,
                                                  lng + (size_t)l * H, lnb + (size_t)l * H,
                                                  W2s + (size_t)nl * 64 * 512,
                                                  hs, hd, (l == NL - 1) ? 1 : 0);
    }

    pool<<<NG, 512, 0, stream>>>(hf, batch, hg);
    readout<<<NG, H, 0, stream>>>(hg, roW1, rob1, roW2, rob2, roW3, rob3, (float*)d_out);
}

// Round 10
// 568.455 us; speedup vs baseline: 10.6557x; 1.0678x over previous
//
#include <hip/hip_runtime.h>
#include <hip/hip_fp16.h>
#include <math.h>

#define NN 100000
#define NE 500000
#define NG 128
#define ND 91
#define ED 20
#define H  128
#define NL 3
#define EPSF 1e-5f
#define EPB 32          // edges per block in aggregation
#define NB64 ((NN + 63) / 64)
#define NSC ((NN + 1023) / 1024)

typedef _Float16 f16;
typedef _Float16 f16x2 __attribute__((ext_vector_type(2)));
typedef _Float16 f16x8 __attribute__((ext_vector_type(8)));
typedef float    f32x4 __attribute__((ext_vector_type(4)));

// swizzled LDS byte offset for a [64][128] f16 tile (row stride 256 B)
__device__ __forceinline__ int swz(int row, int colbyte) {
    return (row * 256 + colbyte) ^ ((row & 7) << 4);
}

// ---------------------------------------------------------------------------
// Fold edge-feature path: Wec[l] = ee_W @ msg_W1[l][2H:3H,:]
//                         bec[l] = ee_b @ msg_W1[l][2H:3H,:] + msg_b1[l]
// ---------------------------------------------------------------------------
__global__ void fold_edge_weights(const float* __restrict__ eeW,
                                  const float* __restrict__ eeb,
                                  const float* __restrict__ msgW1,
                                  const float* __restrict__ msgb1,
                                  float* __restrict__ Wec,
                                  float* __restrict__ bec) {
    int l = blockIdx.y;
    int k = blockIdx.x;                        // 0..ED (ED => bias row)
    int c = threadIdx.x;
    const float* W1e = msgW1 + (size_t)l * 3 * H * H + (size_t)2 * H * H;
    if (k < ED) {
        float acc = 0.f;
        for (int m = 0; m < H; ++m) acc += eeW[k * H + m] * W1e[m * H + c];
        Wec[((size_t)l * ED + k) * H + c] = acc;
    } else {
        float acc = msgb1[l * H + c];
        for (int m = 0; m < H; ++m) acc += eeb[m] * W1e[m * H + c];
        bec[(size_t)l * H + c] = acc;
    }
}

// pack Wec into f16 pairs: wecp[l][k2][c] = (Wec[2k2][c], Wec[2k2+1][c])
__global__ void pack_wec(const float* __restrict__ Wec,
                         f16x2* __restrict__ wecp) {
    int l = blockIdx.x, k2 = blockIdx.y, c = threadIdx.x;
    f16x2 v;
    v[0] = (f16)Wec[((size_t)l * ED + 2 * k2) * H + c];
    v[1] = (f16)Wec[((size_t)l * ED + 2 * k2 + 1) * H + c];
    wecp[((size_t)l * (ED / 2) + k2) * H + c] = v;
}

// ---------------------------------------------------------------------------
// Fold msg_W2 into update weights: W2u[l] = msg_W2[l] @ updW[l][H:2H,:]
//                                  b2u[l] = msg_b2[l] @ updW[l][H:2H,:]
// ---------------------------------------------------------------------------
__global__ void fold_W2u(const float* __restrict__ msgW2,
                         const float* __restrict__ msgb2,
                         const float* __restrict__ updW,
                         float* __restrict__ W2u,
                         float* __restrict__ b2u) {
    int l = blockIdx.y;
    int k = blockIdx.x;                        // 0..H (H => bias row)
    int c = threadIdx.x;
    const float* Wbot = updW + (size_t)l * 2 * H * H + (size_t)H * H;
    if (k < H) {
        const float* w2row = msgW2 + (size_t)l * H * H + (size_t)k * H;
        float acc = 0.f;
        for (int m = 0; m < H; ++m) acc += w2row[m] * Wbot[m * H + c];
        W2u[((size_t)l * H + k) * H + c] = acc;
    } else {
        const float* b2 = msgb2 + (size_t)l * H;
        float acc = 0.f;
        for (int m = 0; m < H; ++m) acc += b2[m] * Wbot[m * H + c];
        b2u[(size_t)l * H + c] = acc;
    }
}

// ---------------------------------------------------------------------------
// W1s: fragment-major pre-swizzled GEMM1 weights.
// ---------------------------------------------------------------------------
__global__ void make_W1s(const float* __restrict__ updW,
                         const float* __restrict__ W2u,
                         f16* __restrict__ W1s) {
    int l = blockIdx.x, frag = blockIdx.y, lane = threadIdx.x;  // 64 threads
    int cf = frag >> 3, kc = frag & 7;
    int col = cf * 16 + (lane & 15);
    int k0 = kc * 32 + (lane >> 4) * 8;
    f16* out = W1s + ((size_t)l * 64 + frag) * 512 + lane * 8;
    for (int j = 0; j < 8; ++j) {
        int k = k0 + j;
        float v = (k < H) ? updW[(size_t)l * 2 * H * H + (size_t)k * H + col]
                          : W2u[(size_t)l * H * H + (size_t)(k - H) * H + col];
        out[j] = (f16)v;
    }
}

// ---------------------------------------------------------------------------
// W2s: fragment-major pre-swizzled GEMM2 weights.
// ---------------------------------------------------------------------------
__global__ void make_W2s(const float* __restrict__ msgW1,
                         f16* __restrict__ W2s) {
    int l = blockIdx.x, frag = blockIdx.y, lane = threadIdx.x;  // 64 threads
    int wave = frag >> 4, mf = (frag >> 2) & 3, kc = frag & 3;
    int oc = wave * 64 + mf * 16 + (lane & 15);
    int k0 = kc * 32 + (lane >> 4) * 8;
    const float* W1 = msgW1 + (size_t)l * 3 * H * H;
    f16* out = W2s + ((size_t)l * 64 + frag) * 512 + lane * 8;
    for (int j = 0; j < 8; ++j) {
        int k = k0 + j;
        float v = W1[(size_t)((oc < H ? 0 : H) + k) * H + (oc & (H - 1))];
        out[j] = (f16)v;
    }
}

// ---------------------------------------------------------------------------
// Wenc: fragment-major encode weights. frag = cf*3+kc (kc 0..2, K padded 96)
// value = B[col=cf*16+(lane&15)][k=kc*32+(lane>>4)*8+j], B[col][k]=neW[k][col]
// ---------------------------------------------------------------------------
__global__ void make_Wenc(const float* __restrict__ neW,
                          f16* __restrict__ Wenc) {
    int frag = blockIdx.x, lane = threadIdx.x;  // 24 frags, 64 threads
    int cf = frag / 3, kc = frag % 3;
    int col = cf * 16 + (lane & 15);
    int k0 = kc * 32 + (lane >> 4) * 8;
    f16* out = Wenc + (size_t)frag * 512 + lane * 8;
    for (int j = 0; j < 8; ++j) {
        int k = k0 + j;
        out[j] = (k < ND) ? (f16)neW[(size_t)k * H + col] : (f16)0.f;
    }
}

// ---------------------------------------------------------------------------
// CSR build over dst
// ---------------------------------------------------------------------------
__global__ void csr_count(const int* __restrict__ dst, int* __restrict__ deg) {
    int e = blockIdx.x * blockDim.x + threadIdx.x;
    if (e < NE) atomicAdd(&deg[dst[e]], 1);
}

__global__ void scan_p1(const int* __restrict__ deg,
                        int* __restrict__ part, int* __restrict__ bsum) {
    __shared__ int ws[16];
    int t = threadIdx.x, lane = t & 63, w = t >> 6;
    int i = blockIdx.x * 1024 + t;
    int v = (i < NN) ? deg[i] : 0;
    int inc = v;
    #pragma unroll
    for (int off = 1; off < 64; off <<= 1) {
        int u = __shfl_up(inc, off, 64);
        if (lane >= off) inc += u;
    }
    if (lane == 63) ws[w] = inc;
    __syncthreads();
    if (t == 0) {
        int run = 0;
        #pragma unroll
        for (int q = 0; q < 16; ++q) { int tmp = ws[q]; ws[q] = run; run += tmp; }
        bsum[blockIdx.x] = run;
    }
    __syncthreads();
    if (i < NN) part[i] = ws[w] + inc - v;
}

__global__ void scan_p2(int* __restrict__ bsum) {
    if (threadIdx.x == 0) {
        int run = 0;
        for (int q = 0; q < NSC; ++q) { int tmp = bsum[q]; bsum[q] = run; run += tmp; }
    }
}

__global__ void scan_p3(const int* __restrict__ part, const int* __restrict__ bsum,
                        int* __restrict__ rowstart) {
    int i = blockIdx.x * 1024 + threadIdx.x;
    if (i < NN) rowstart[i] = part[i] + bsum[blockIdx.x];
    if (i == 0) rowstart[NN] = NE;
}

// zflag[n]=1 iff node needs hidsum zero-init (deg0 or receives atomics)
__global__ void mark_zero(const int* __restrict__ rowstart,
                          unsigned char* __restrict__ zflag) {
    int n = blockIdx.x * 256 + threadIdx.x;
    if (n >= NN) return;
    int b = rowstart[n], e = rowstart[n + 1];
    bool interior = (b < e) && (b % EPB != 0) && (e % EPB != 0)
                    && ((b / EPB) == ((e - 1) / EPB));
    zflag[n] = interior ? 0 : 1;
}

__global__ void csr_scatter(const int* __restrict__ src,
                            const int* __restrict__ dst,
                            const float* __restrict__ ef,
                            const int* __restrict__ rowstart,
                            int* __restrict__ cursor,
                            int* __restrict__ srcs,
                            int* __restrict__ dsts,
                            f16* __restrict__ efs) {
    int e = blockIdx.x * blockDim.x + threadIdx.x;
    if (e < NE) {
        int d = dst[e];
        int pos = atomicAdd(&cursor[d], 1);
        int j = rowstart[d] + pos;
        srcs[j] = src[e];
        dsts[j] = d;
        const float* efp = ef + (size_t)e * ED;
        f16* out = efs + (size_t)j * ED;
        #pragma unroll
        for (int k = 0; k < ED; ++k) out[k] = (f16)efp[k];
    }
}

// ---------------------------------------------------------------------------
// GEMM2 device fn: D[outcol 0..255][node 0..63] = W2s(frag-major) x xlds
// ---------------------------------------------------------------------------
__device__ __forceinline__ void gemm2_store(const f16* xlds,
                                            const f16* __restrict__ W2s_l,
                                            f16* __restrict__ hs,
                                            f16* __restrict__ hd,
                                            int n0, int wave, int lane) {
    int g = lane >> 4, r15 = lane & 15;
    f16x8 B2[4][4];
    #pragma unroll
    for (int nf = 0; nf < 4; ++nf) {
        int row = nf * 16 + r15;
        #pragma unroll
        for (int kc = 0; kc < 4; ++kc)
            B2[nf][kc] = *(const f16x8*)((const char*)xlds + swz(row, kc * 64 + g * 16));
    }
    f16* outb = (wave < 2) ? hs : hd;
    int colw = (wave & 1) * 64;
    #pragma unroll
    for (int mf = 0; mf < 4; ++mf) {
        f16x8 A2[4];
        #pragma unroll
        for (int kc = 0; kc < 4; ++kc)
            A2[kc] = *(const f16x8*)&W2s_l[(size_t)(((wave * 4 + mf) * 4 + kc) * 64 + lane) * 8];
        #pragma unroll
        for (int nf = 0; nf < 4; ++nf) {
            f32x4 acc = {0.f, 0.f, 0.f, 0.f};
            #pragma unroll
            for (int kc = 0; kc < 4; ++kc)
                acc = __builtin_amdgcn_mfma_f32_16x16x32_f16(A2[kc], B2[nf][kc], acc, 0, 0, 0);
            int node = n0 + nf * 16 + r15;
            if (node < NN) {
                union { f16 q[4]; uint2 u; } pk;
                pk.q[0] = (f16)acc[0]; pk.q[1] = (f16)acc[1];
                pk.q[2] = (f16)acc[2]; pk.q[3] = (f16)acc[3];
                *(uint2*)&outb[(size_t)node * H + colw + mf * 16 + g * 4] = pk.u;
            }
        }
    }
}

// ---------------------------------------------------------------------------
// Fused encode + msg_pre: nf tile -> f16 LDS (K pad 96) -> MFMA encode ->
// h -> hf (coalesced) ; zero flagged hidsum ; GEMM2 -> hs/hd (layer 0)
// ---------------------------------------------------------------------------
__global__ void __launch_bounds__(256)
encode_pre_mfma(const float* __restrict__ nf,
                const f16* __restrict__ Wenc,   // frag-major [24][64][8]
                const float* __restrict__ neb,
                const unsigned char* __restrict__ zflag,
                const f16* __restrict__ W2s_l0,
                f16* __restrict__ hf,
                f16* __restrict__ hs, f16* __restrict__ hd,
                f16* __restrict__ hidsum) {
    __shared__ f16 xlds[64 * 128];
    int t = threadIdx.x;
    int wave = t >> 6, lane = t & 63;
    int g = lane >> 4, r15 = lane & 15;
    int n0 = blockIdx.x * 64;

    // ---- stage nf tile f32->f16 into swizzled LDS; pad cols ND..127 = 0 ----
    for (int i = t; i < 64 * ND; i += 256) {
        int row = i / ND, col = i % ND;
        int n = n0 + row;
        float v = (n < NN) ? nf[(size_t)n * ND + col] : 0.f;
        *(f16*)((char*)xlds + swz(row, col * 2)) = (f16)v;
    }
    for (int i = t; i < 64 * (H - ND); i += 256) {
        int row = i / (H - ND), col = ND + i % (H - ND);
        *(f16*)((char*)xlds + swz(row, col * 2)) = (f16)0.f;
    }
    __syncthreads();

    // ---- A fragments kc 0..2 (K=96) ----
    int lrow_a = wave * 16 + r15;
    f16x8 A[3];
    #pragma unroll
    for (int kc = 0; kc < 3; ++kc)
        A[kc] = *(const f16x8*)((const char*)xlds + swz(lrow_a, kc * 64 + g * 16));

    // ---- encode GEMM ----
    f32x4 acc1[8];
    #pragma unroll
    for (int cf = 0; cf < 8; ++cf) acc1[cf] = (f32x4){0.f, 0.f, 0.f, 0.f};
    #pragma unroll
    for (int cf = 0; cf < 8; ++cf) {
        #pragma unroll
        for (int kc = 0; kc < 3; ++kc) {
            f16x8 b = *(const f16x8*)&Wenc[(size_t)((cf * 3 + kc) * 64 + lane) * 8];
            acc1[cf] = __builtin_amdgcn_mfma_f32_16x16x32_f16(A[kc], b, acc1[cf], 0, 0, 0);
        }
    }
    __syncthreads();                      // all A reads done before overwrite

    // ---- h = acc + neb -> xlds ----
    #pragma unroll
    for (int cf = 0; cf < 8; ++cf) {
        int col = cf * 16 + r15;
        float bb = neb[col];
        #pragma unroll
        for (int r = 0; r < 4; ++r) {
            int lrow = wave * 16 + g * 4 + r;
            *(f16*)((char*)xlds + swz(lrow, col * 2)) = (f16)(acc1[cf][r] + bb);
        }
    }
    __syncthreads();

    // ---- coalesced hf write + flagged hidsum zero ----
    for (int i = t; i < 64 * 32; i += 256) {
        int row = i >> 5, c4 = i & 31;
        int n = n0 + row;
        if (n < NN) {
            uint2 v = *(const uint2*)((const char*)xlds + swz(row, c4 * 8));
            *(uint2*)&hf[(size_t)n * H + c4 * 4] = v;
            if (zflag[n]) *(uint2*)&hidsum[(size_t)n * H + c4 * 4] = make_uint2(0u, 0u);
        }
    }
    gemm2_store(xlds, W2s_l0, hs, hd, n0, wave, lane);
}

// ---------------------------------------------------------------------------
// flush helpers: pack (col c even, c+1) via shfl, store/atomic f16x2
// ---------------------------------------------------------------------------
__device__ __forceinline__ void flush_store(f16* __restrict__ hidsum,
                                            int d, int c, float acc) {
    float other = __shfl_xor(acc, 1);
    if ((c & 1) == 0) {
        union { f16 q[2]; unsigned u; } pk;
        pk.q[0] = (f16)acc; pk.q[1] = (f16)other;
        *(unsigned*)&hidsum[(size_t)d * H + c] = pk.u;
    }
}

__device__ __forceinline__ void flush_atomic(f16* __restrict__ hidsum,
                                             int d, int c, float acc) {
    float other = __shfl_xor(acc, 1);
    if ((c & 1) == 0) {
        unsigned* p = (unsigned*)&hidsum[(size_t)d * H + c];
        unsigned old = *p;
        while (true) {
            union { f16 q[2]; unsigned u; } cur, nw;
            cur.u = old;
            nw.q[0] = (f16)((float)cur.q[0] + acc);
            nw.q[1] = (f16)((float)cur.q[1] + other);
            unsigned prev = atomicCAS(p, old, nw.u);
            if (prev == old) break;
            old = prev;
        }
    }
}

// ---------------------------------------------------------------------------
// Edge-parallel segmented aggregation over CSR-sorted edges, EPB per block.
// fdot2-based ef@Wec, raw f16 LDS staging.
// ---------------------------------------------------------------------------
__global__ void __launch_bounds__(128)
aggregate_edges(const int* __restrict__ srcs,
                const int* __restrict__ dsts,
                const f16* __restrict__ efs,
                const f16* __restrict__ hs,
                const f16* __restrict__ hd,
                const f16x2* __restrict__ wecp_l,
                const float* __restrict__ bec_l,
                f16* __restrict__ hidsum) {
    int c = threadIdx.x;
    size_t j0 = (size_t)blockIdx.x * EPB;
    __shared__ f16 efs_lds[EPB * ED];              // 1280 B raw
    __shared__ int sd[2 * EPB];
    {   // raw 16B-chunk copy: EPB*ED*2 = 1280 B = 80 uint4
        const uint4* srcp = (const uint4*)(efs + j0 * ED);
        uint4* dstp = (uint4*)efs_lds;
        if (c < 80) dstp[c] = srcp[c];
        if (c < EPB) { sd[c] = srcs[j0 + c]; sd[EPB + c] = dsts[j0 + c]; }
    }
    __syncthreads();
    f16x2 wp[ED / 2];
    #pragma unroll
    for (int k2 = 0; k2 < ED / 2; ++k2) wp[k2] = wecp_l[k2 * H + c];
    float becc = bec_l[c];
    float hv[EPB];
    #pragma unroll
    for (int jj = 0; jj < EPB; ++jj) {
        hv[jj] = (float)hs[(size_t)sd[jj] * H + c]
               + (float)hd[(size_t)sd[EPB + jj] * H + c];
    }
    int dcur = sd[EPB];
    float acc = 0.f;
    int nflush = 0;
    #pragma unroll
    for (int jj = 0; jj < EPB; ++jj) {
        int d = sd[EPB + jj];
        if (d != dcur) {
            if (nflush == 0) flush_atomic(hidsum, dcur, c, acc);
            else             flush_store(hidsum, dcur, c, acc);
            dcur = d; acc = 0.f; ++nflush;
        }
        float v = hv[jj] + becc;
        const f16x2* ef2 = (const f16x2*)&efs_lds[jj * ED];
        #pragma unroll
        for (int k2 = 0; k2 < ED / 2; ++k2)
            v = __builtin_amdgcn_fdot2(ef2[k2], wp[k2], v, false);
        acc += fmaxf(v, 0.f);
    }
    flush_atomic(hidsum, dcur, c, acc);
}

// ---------------------------------------------------------------------------
// MFMA fused update (64 nodes / 256 threads), LDS-routed, frag-major weights.
// ---------------------------------------------------------------------------
__global__ void __launch_bounds__(256)
update_pre_mfma(f16* __restrict__ hf,
                f16* __restrict__ hidsum,
                const int* __restrict__ degv,
                const unsigned char* __restrict__ zflag,
                const f16* __restrict__ W1s_l,   // frag-major [64][64][8]
                const float* __restrict__ b2u_l,
                const float* __restrict__ updbl,
                const float* __restrict__ lng_l,
                const float* __restrict__ lnb_l,
                const f16* __restrict__ W2s_next,
                f16* __restrict__ hs, f16* __restrict__ hd,
                int last) {
    __shared__ f16 xlds[64 * 128];
    int t = threadIdx.x;
    int wave = t >> 6, lane = t & 63;
    int g = lane >> 4, r15 = lane & 15;
    int n0 = blockIdx.x * 64;

    // ---- P1: coalesced stage of hf tile into swizzled LDS ----
    for (int i = t; i < 64 * 32; i += 256) {
        int row = i >> 5, c4 = i & 31;
        int n = n0 + row;
        uint2 v = make_uint2(0u, 0u);
        if (n < NN) v = *(const uint2*)&hf[(size_t)n * H + c4 * 4];
        *(uint2*)((char*)xlds + swz(row, c4 * 8)) = v;
    }

    // ---- A fragments kc4..7 direct from f16 hidsum (coalesced f16x8) ----
    int arow = n0 + wave * 16 + r15;
    bool av = arow < NN;
    f16x8 zero8;
    for (int i = 0; i < 8; ++i) zero8[i] = (f16)0.f;
    f16x8 A1[8];
    #pragma unroll
    for (int kc = 4; kc < 8; ++kc) {
        A1[kc] = av ? *(const f16x8*)&hidsum[(size_t)arow * H + (kc & 3) * 32 + g * 8]
                    : zero8;
    }
    __syncthreads();

    // ---- A fragments kc0..3 from xlds ----
    int lrow_a = wave * 16 + r15;
    #pragma unroll
    for (int kc = 0; kc < 4; ++kc)
        A1[kc] = *(const f16x8*)((const char*)xlds + swz(lrow_a, kc * 64 + g * 16));

    // ---- GEMM1 (coalesced frag-major weight loads) ----
    f32x4 acc1[8];
    #pragma unroll
    for (int cf = 0; cf < 8; ++cf) acc1[cf] = (f32x4){0.f, 0.f, 0.f, 0.f};
    #pragma unroll
    for (int cf = 0; cf < 8; ++cf) {
        #pragma unroll
        for (int kc = 0; kc < 8; ++kc) {
            f16x8 b = *(const f16x8*)&W1s_l[(size_t)((cf * 8 + kc) * 64 + lane) * 8];
            acc1[cf] = __builtin_amdgcn_mfma_f32_16x16x32_f16(A1[kc], b, acc1[cf], 0, 0, 0);
        }
    }

    // ---- epilogue ----
    int nodes[4]; bool nv[4]; float degf[4];
    #pragma unroll
    for (int r = 0; r < 4; ++r) {
        nodes[r] = n0 + wave * 16 + g * 4 + r;
        nv[r] = nodes[r] < NN;
        degf[r] = nv[r] ? (float)degv[nodes[r]] : 0.f;
    }
    float ubc[8], b2c[8], gl[8], bl[8];
    #pragma unroll
    for (int cf = 0; cf < 8; ++cf) {
        int col = cf * 16 + r15;
        ubc[cf] = updbl[col]; b2c[cf] = b2u_l[col];
        gl[cf] = lng_l[col];  bl[cf] = lnb_l[col];
    }
    float x[8][4];
    #pragma unroll
    for (int cf = 0; cf < 8; ++cf) {
        int col = cf * 16 + r15;
        #pragma unroll
        for (int r = 0; r < 4; ++r) {
            int lrow = wave * 16 + g * 4 + r;
            float hres = (float)*(const f16*)((const char*)xlds + swz(lrow, col * 2));
            x[cf][r] = hres + fmaxf(acc1[cf][r] + ubc[cf] + degf[r] * b2c[cf], 0.f);
        }
    }

    // ---- layernorm per row, write hn into xlds ----
    #pragma unroll
    for (int r = 0; r < 4; ++r) {
        float s1 = 0.f, s2 = 0.f;
        #pragma unroll
        for (int cf = 0; cf < 8; ++cf) { s1 += x[cf][r]; s2 += x[cf][r] * x[cf][r]; }
        #pragma unroll
        for (int off = 1; off <= 8; off <<= 1) {
            s1 += __shfl_xor(s1, off);
            s2 += __shfl_xor(s2, off);
        }
        float mu  = s1 * (1.0f / H);
        float var = s2 * (1.0f / H) - mu * mu;
        float inv = rsqrtf(var + EPSF);
        int lrow = wave * 16 + g * 4 + r;
        #pragma unroll
        for (int cf = 0; cf < 8; ++cf) {
            int col = cf * 16 + r15;
            float hn = (x[cf][r] - mu) * inv * gl[cf] + bl[cf];
            *(f16*)((char*)xlds + swz(lrow, col * 2)) = (f16)hn;
        }
    }
    __syncthreads();

    // ---- coalesced hf write-back (+ flagged hidsum zero, f16) ----
    for (int i = t; i < 64 * 32; i += 256) {
        int row = i >> 5, c4 = i & 31;
        int n = n0 + row;
        if (n < NN) {
            uint2 v = *(const uint2*)((const char*)xlds + swz(row, c4 * 8));
            *(uint2*)&hf[(size_t)n * H + c4 * 4] = v;
            if (!last && zflag[n])
                *(uint2*)&hidsum[(size_t)n * H + c4 * 4] = make_uint2(0u, 0u);
        }
    }
    if (last) return;
    gemm2_store(xlds, W2s_next, hs, hd, n0, wave, lane);
}

// ---------------------------------------------------------------------------
// per-graph mean (denom = count+1) and max pooling; batch sorted.
// ---------------------------------------------------------------------------
__global__ void __launch_bounds__(512)
pool(const f16* __restrict__ hf,
     const int* __restrict__ batch,
     float* __restrict__ hg) {
    int g = blockIdx.x;
    int t = threadIdx.x;
    int c = t & 127, q = t >> 7;
    int lo = 0, hi = NN;
    while (lo < hi) { int mid = (lo + hi) >> 1; if (batch[mid] < g) lo = mid + 1; else hi = mid; }
    int start = lo;
    hi = NN;
    while (lo < hi) { int mid = (lo + hi) >> 1; if (batch[mid] < g + 1) lo = mid + 1; else hi = mid; }
    int end = lo;
    float s = 0.f, mx = -INFINITY;
    for (int n = start + q; n < end; n += 4) {
        float v = (float)hf[(size_t)n * H + c];
        s += v;
        mx = fmaxf(mx, v);
    }
    __shared__ float shs[4][H];
    __shared__ float shm[4][H];
    shs[q][c] = s; shm[q][c] = mx;
    __syncthreads();
    if (q == 0) {
        float S = shs[0][c] + shs[1][c] + shs[2][c] + shs[3][c];
        float M = fmaxf(fmaxf(shm[0][c], shm[1][c]), fmaxf(shm[2][c], shm[3][c]));
        float denom = (float)(end - start) + 1.0f;
        hg[(size_t)g * 2 * H + c]     = S / denom;
        hg[(size_t)g * 2 * H + H + c] = M;
    }
}

// ---------------------------------------------------------------------------
// readout MLP
// ---------------------------------------------------------------------------
__global__ void __launch_bounds__(128)
readout(const float* __restrict__ hg,
        const float* __restrict__ W1, const float* __restrict__ b1,
        const float* __restrict__ W2, const float* __restrict__ b2,
        const float* __restrict__ W3, const float* __restrict__ b3,
        float* __restrict__ out) {
    int g = blockIdx.x, t = threadIdx.x;
    __shared__ float xin[2 * H];
    __shared__ float x1[H];
    __shared__ float x2[H / 2];
    xin[t]     = hg[(size_t)g * 2 * H + t];
    xin[H + t] = hg[(size_t)g * 2 * H + H + t];
    __syncthreads();
    float acc = b1[t];
    for (int k = 0; k < 2 * H; ++k) acc += xin[k] * W1[k * H + t];
    x1[t] = fmaxf(acc, 0.f);
    __syncthreads();
    if (t < 64) {
        float a2 = b2[t];
        for (int k = 0; k < H; ++k) a2 += x1[k] * W2[k * 64 + t];
        x2[t] = fmaxf(a2, 0.f);
    }
    __syncthreads();
    if (t < 64) {
        float v = x2[t] * W3[t];
        #pragma unroll
        for (int off = 32; off >= 1; off >>= 1) v += __shfl_xor(v, off, 64);
        if (t == 0) out[g] = v + b3[0];
    }
}

// ---------------------------------------------------------------------------
extern "C" void kernel_launch(void* const* d_in, const int* in_sizes, int n_in,
                              void* d_out, int out_size, void* d_ws, size_t ws_size,
                              hipStream_t stream) {
    const float* node_feats = (const float*)d_in[0];
    const int*   edge_index = (const int*)d_in[1];
    const float* edge_feats = (const float*)d_in[2];
    const int*   batch      = (const int*)d_in[3];
    const float* ne_W  = (const float*)d_in[4];
    const float* ne_b  = (const float*)d_in[5];
    const float* ee_W  = (const float*)d_in[6];
    const float* ee_b  = (const float*)d_in[7];
    const float* msgW1 = (const float*)d_in[8];
    const float* msgb1 = (const float*)d_in[9];
    const float* msgW2 = (const float*)d_in[10];
    const float* msgb2 = (const float*)d_in[11];
    const float* updW  = (const float*)d_in[12];
    const float* updb  = (const float*)d_in[13];
    const float* lng   = (const float*)d_in[14];
    const float* lnb   = (const float*)d_in[15];
    const float* roW1  = (const float*)d_in[16];
    const float* rob1  = (const float*)d_in[17];
    const float* roW2  = (const float*)d_in[18];
    const float* rob2  = (const float*)d_in[19];
    const float* roW3  = (const float*)d_in[20];
    const float* rob3  = (const float*)d_in[21];

    const int* src = edge_index;            // row 0
    const int* dst = edge_index + NE;       // row 1

    char* ws = (char*)d_ws;
    f16*   hf     = (f16*)ws;   ws += (size_t)NN * H * 2;
    f16*   hidsum = (f16*)ws;   ws += (size_t)NN * H * 2;
    f16*   hs     = (f16*)ws;   ws += (size_t)NN * H * 2;
    f16*   hd     = (f16*)ws;   ws += (size_t)NN * H * 2;
    f16*   efs    = (f16*)ws;   ws += (size_t)NE * ED * 2;
    int* srcs     = (int*)ws; ws += (size_t)NE * 4;
    int* dsts     = (int*)ws; ws += (size_t)NE * 4;
    int* rowstart = (int*)ws; ws += (size_t)(NN + 4) * 4;
    int* deg      = (int*)ws; ws += (size_t)NN * 4;     // reused as cursor; ends = degree
    int* part     = (int*)ws; ws += (size_t)NN * 4;
    int* bsum     = (int*)ws; ws += (size_t)256 * 4;
    unsigned char* zflag = (unsigned char*)ws; ws += ((size_t)NN + 15) / 16 * 16;
    float* Wec = (float*)ws; ws += (size_t)NL * ED * H * 4;
    float* bec = (float*)ws; ws += (size_t)NL * H * 4;
    f16x2* wecp = (f16x2*)ws; ws += (size_t)NL * (ED / 2) * H * 4;
    float* W2u = (float*)ws; ws += (size_t)NL * H * H * 4;
    float* b2u = (float*)ws; ws += (size_t)NL * H * 4;
    f16* W1s = (f16*)ws; ws += (size_t)NL * 64 * 512 * 2;
    f16* W2s = (f16*)ws; ws += (size_t)NL * 64 * 512 * 2;
    f16* Wenc = (f16*)ws; ws += (size_t)24 * 512 * 2;
    float* hg  = (float*)ws; ws += (size_t)NG * 2 * H * 4;

    // --- precompute: folded weights + packed/frag-major f16 weights + CSR ---
    fold_edge_weights<<<dim3(ED + 1, NL), H, 0, stream>>>(ee_W, ee_b, msgW1, msgb1, Wec, bec);
    pack_wec<<<dim3(NL, ED / 2), H, 0, stream>>>(Wec, wecp);
    fold_W2u<<<dim3(H + 1, NL), H, 0, stream>>>(msgW2, msgb2, updW, W2u, b2u);
    make_W1s<<<dim3(NL, 64), 64, 0, stream>>>(updW, W2u, W1s);
    make_W2s<<<dim3(NL, 64), 64, 0, stream>>>(msgW1, W2s);
    make_Wenc<<<24, 64, 0, stream>>>(ne_W, Wenc);

    hipMemsetAsync(deg, 0, (size_t)NN * 4, stream);
    csr_count<<<(NE + 255) / 256, 256, 0, stream>>>(dst, deg);
    scan_p1<<<NSC, 1024, 0, stream>>>(deg, part, bsum);
    scan_p2<<<1, 64, 0, stream>>>(bsum);
    scan_p3<<<NSC, 1024, 0, stream>>>(part, bsum, rowstart);
    mark_zero<<<(NN + 255) / 256, 256, 0, stream>>>(rowstart, zflag);
    hipMemsetAsync(deg, 0, (size_t)NN * 4, stream);
    csr_scatter<<<(NE + 255) / 256, 256, 0, stream>>>(src, dst, edge_feats, rowstart,
                                                      deg, srcs, dsts, efs);

    encode_pre_mfma<<<NB64, 256, 0, stream>>>(node_feats, Wenc, ne_b, zflag,
                                              W2s, hf, hs, hd, hidsum);

    // --- layers ---
    for (int l = 0; l < NL; ++l) {
        aggregate_edges<<<NE / EPB, 128, 0, stream>>>(srcs, dsts, efs, hs, hd,
                                                      wecp + (size_t)l * (ED / 2) * H,
                                                      bec + (size_t)l * H, hidsum);
        int nl = (l + 1 < NL) ? (l + 1) : 0;   // safe index; unused when last
        update_pre_mfma<<<NB64, 256, 0, stream>>>(hf, hidsum, deg, zflag,
                                                  W1s + (size_t)l * 64 * 512,
                                                  b2u + (size_t)l * H,
                                                  updb + (size_t)l * H,
                                                  lng + (size_t)l * H, lnb + (size_t)l * H,
                                                  W2s + (size_t)nl * 64 * 512,
                                                  hs, hd, (l == NL - 1) ? 1 : 0);
    }

    pool<<<NG, 512, 0, stream>>>(hf, batch, hg);
    readout<<<NG, H, 0, stream>>>(hg, roW1, rob1, roW2, rob2, roW3, rob3, (float*)d_out);
}